// Round 7
// baseline (1810.715 us; speedup 1.0000x reference)
//
#include <hip/hip_runtime.h>
#include <math.h>

#define BB 32
#define NN 4096
#define NPp 256
#define NSs 64
#define KC 20

__device__ __forceinline__ float fma4(const float4 w, const float4 v, float a){
  a = fmaf(w.x, v.x, a); a = fmaf(w.y, v.y, a);
  a = fmaf(w.z, v.z, a); a = fmaf(w.w, v.w, a); return a;
}
__device__ __forceinline__ float4 fma4s(const float4 w, float s, float4 a){
  a.x = fmaf(w.x, s, a.x); a.y = fmaf(w.y, s, a.y);
  a.z = fmaf(w.z, s, a.z); a.w = fmaf(w.w, s, a.w); return a;
}
__device__ __forceinline__ float4 max4(float4 a, float4 b){
  a.x = fmaxf(a.x, b.x); a.y = fmaxf(a.y, b.y);
  a.z = fmaxf(a.z, b.z); a.w = fmaxf(a.w, b.w); return a;
}
__device__ __forceinline__ float4 add4(float4 a, float4 b){
  a.x += b.x; a.y += b.y; a.z += b.z; a.w += b.w; return a;
}

template<int C>
__device__ __forceinline__ int dpp_i(int x){
  return __builtin_amdgcn_update_dpp(x, x, C, 0xf, 0xf, false);
}

// ---------------- unified weight prep (all transposes/splits in one kernel) ----------------
__global__ void k_wprep(const float* __restrict__ t0, const float* __restrict__ t1,
                        const float* __restrict__ d0, const float* __restrict__ d1,
                        const float* __restrict__ d2,
                        float* __restrict__ waT0, float* __restrict__ wbT0,
                        float* __restrict__ wt_t1,
                        float* __restrict__ waD0, float* __restrict__ wbD0,
                        float* __restrict__ waD1, float* __restrict__ wbD1,
                        float* __restrict__ waD2, float* __restrict__ wbD2){
  int i = blockIdx.x*256 + threadIdx.x;
  if (i < 8384){                       // t_ec_w0: [64][262] -> A/B [131][64]
    int m = i >> 6;
    int c = i & 63;
    float bb = t0[(size_t)c*262 + m];
    float dd = t0[(size_t)c*262 + 131 + m];
    waT0[i] = __fsub_rn(bb, dd); wbT0[i] = dd;
    return;
  }
  i -= 8384;
  if (i < 8192){                       // t_ec_w1: [128][64] -> [64][128]
    int m = i >> 7, c = i & 127;
    wt_t1[i] = t1[(size_t)c*64 + m];
    return;
  }
  i -= 8192;
  if (i < 16768){                      // dg_ec_w0: [128][262] -> A/B [131][128]
    int m = i >> 7, c = i & 127;
    float bb = d0[(size_t)c*262 + m];
    float dd = d0[(size_t)c*262 + 131 + m];
    waD0[i] = __fsub_rn(bb, dd); wbD0[i] = dd;
    return;
  }
  i -= 16768;
  if (i < 32768){                      // dg_ec_w1: [256][256] -> A/B [128][256]
    int m = i >> 8, c = i & 255;
    float bb = d1[(size_t)c*256 + m];
    float dd = d1[(size_t)c*256 + 128 + m];
    waD1[i] = __fsub_rn(bb, dd); wbD1[i] = dd;
    return;
  }
  i -= 32768;
  if (i < 131072){                     // dg_ec_w2: [512][512] -> A/B [256][512]
    int m = i >> 9, c = i & 511;
    float bb = d2[(size_t)c*512 + m];
    float dd = d2[(size_t)c*512 + 256 + m];
    waD2[i] = __fsub_rn(bb, dd); wbD2[i] = dd;
  }
}

// ---------------- transpose + point norms ----------------
__global__ void k_prep(const float* __restrict__ pts, float* __restrict__ xyz, float* __restrict__ xnrm){
  int i = blockIdx.x*256 + threadIdx.x;
  if (i >= BB*NN) return;
  int b = i >> 12, n = i & (NN-1);
  float X = pts[(b*3+0)*NN + n];
  float Y = pts[(b*3+1)*NN + n];
  float Z = pts[(b*3+2)*NN + n];
  xyz[i*3+0]=X; xyz[i*3+1]=Y; xyz[i*3+2]=Z;
  xnrm[i] = __fadd_rn(__fadd_rn(__fmul_rn(X,X), __fmul_rn(Y,Y)), __fmul_rn(Z,Z));
}

// ---------------- farthest point sampling: registers + DPP reduce, 1 barrier/iter ----------------
__global__ __launch_bounds__(256) void k_fps(const float* __restrict__ xyz, float* __restrict__ new_xyz){
  __shared__ float part[2][4][8];
  int b = blockIdx.x, t = threadIdx.x;
  int w = t >> 6;
  float px[16], py[16], pz[16], dist[16];
#pragma unroll
  for (int q = 0; q < 16; ++q){
    const float* p = xyz + ((size_t)b*NN + q*256 + t)*3;
    px[q] = p[0]; py[q] = p[1]; pz[q] = p[2];
    dist[q] = __builtin_inff();
  }
  const float* p0 = xyz + (size_t)b*NN*3;
  float Px = p0[0], Py = p0[1], Pz = p0[2];
  for (int it = 0; it < NPp; ++it){
    if (t == 0){
      float* o = new_xyz + ((size_t)b*NPp + it)*3;
      o[0] = Px; o[1] = Py; o[2] = Pz;
    }
    float bv = -1.0f, bx = 0.f, by = 0.f, bz = 0.f; int bj = 0;
#pragma unroll
    for (int q = 0; q < 16; ++q){
      float dx = __fsub_rn(px[q], Px);
      float dy = __fsub_rn(py[q], Py);
      float dz = __fsub_rn(pz[q], Pz);
      float dd = __fadd_rn(__fadd_rn(__fmul_rn(dx,dx), __fmul_rn(dy,dy)), __fmul_rn(dz,dz));
      float dm = fminf(dist[q], dd);
      dist[q] = dm;
      if (dm > bv){ bv = dm; bj = q*256 + t; bx = px[q]; by = py[q]; bz = pz[q]; }
    }
#define FPS_STAGE(C) { \
    float ov = __int_as_float(dpp_i<C>(__float_as_int(bv))); \
    int   oj = dpp_i<C>(bj); \
    float ox = __int_as_float(dpp_i<C>(__float_as_int(bx))); \
    float oy = __int_as_float(dpp_i<C>(__float_as_int(by))); \
    float oz = __int_as_float(dpp_i<C>(__float_as_int(bz))); \
    bool tk = (ov > bv) || (ov == bv && oj < bj); \
    bv = tk ? ov : bv; bj = tk ? oj : bj; \
    bx = tk ? ox : bx; by = tk ? oy : by; bz = tk ? oz : bz; }
    FPS_STAGE(0x111) FPS_STAGE(0x112) FPS_STAGE(0x114) FPS_STAGE(0x118)
    FPS_STAGE(0x142) FPS_STAGE(0x143)
#undef FPS_STAGE
    int par = it & 1;
    if ((t & 63) == 63){
      float* pp = part[par][w];
      pp[0] = bv; ((int*)pp)[1] = bj; pp[2] = bx; pp[3] = by; pp[4] = bz;
    }
    __syncthreads();
    const float* q0 = part[par][0];
    float fv = q0[0]; int fj = ((const int*)q0)[1];
    float fx = q0[2], fy = q0[3], fz = q0[4];
#pragma unroll
    for (int ww = 1; ww < 4; ++ww){
      const float* pp = part[par][ww];
      float ov = pp[0]; int oj = ((const int*)pp)[1];
      if (ov > fv || (ov == fv && oj < fj)){ fv = ov; fj = oj; fx = pp[2]; fy = pp[3]; fz = pp[4]; }
    }
    Px = fx; Py = fy; Pz = fz;
  }
}

// ---------------- ball query + SA convs + maxpool (h1 in registers, DPP max-reduce) ----------------
__global__ __launch_bounds__(64) void k_sa(const float* __restrict__ xyz, const float* __restrict__ xnrm,
    const float* __restrict__ new_xyz, const float* __restrict__ w0, const float* __restrict__ w1,
    const float* __restrict__ w2, float* __restrict__ feat, float* __restrict__ x131){
  __shared__ int gix[64];
  int bi = blockIdx.x, lane = threadIdx.x;
  int b = bi >> 8;
  const float* q = new_xyz + (size_t)bi*3;
  float qx=q[0], qy=q[1], qz=q[2];
  float nq = __fadd_rn(__fadd_rn(__fmul_rn(qx,qx), __fmul_rn(qy,qy)), __fmul_rn(qz,qz));
  int cnt = 0;
  for (int base = 0; base < NN && cnt < NSs; base += 256){
#pragma unroll
    for (int u = 0; u < 4; ++u){
      int j = base + u*64 + lane;
      const float* p = xyz + ((size_t)b*NN + j)*3;
      float dot = __fadd_rn(__fadd_rn(__fmul_rn(qx,p[0]), __fmul_rn(qy,p[1])), __fmul_rn(qz,p[2]));
      float d2 = __fsub_rn(__fadd_rn(nq, xnrm[b*NN + j]), __fmul_rn(2.0f, dot));
      bool inb = d2 < 0.04f;
      unsigned long long m = __ballot(inb);
      int pos = cnt + (int)__popcll(m & ((1ull << lane) - 1ull));
      if (inb && pos < NSs) gix[pos] = j;
      cnt += (int)__popcll(m);
    }
  }
  __syncthreads();
  int g0 = gix[0];
  if (lane >= cnt) gix[lane] = g0;
  __syncthreads();
  // lane = sample; both conv layers in registers
  float h1[64];
  {
    int gj = gix[lane];
    const float* p = xyz + ((size_t)b*NN + gj)*3;
    float px = p[0]-qx, py = p[1]-qy, pz = p[2]-qz;
    float h0[64];
#pragma unroll
    for (int c = 0; c < 64; ++c){
      float a = fmaf(w0[c*3+2], pz, fmaf(w0[c*3+1], py, w0[c*3]*px));
      h0[c] = fmaxf(a, 0.0f);
    }
    for (int c = 0; c < 64; ++c){
      const float4* wr = (const float4*)(w1 + c*64);
      float a = 0.0f;
#pragma unroll
      for (int qq = 0; qq < 16; ++qq){
        float4 w = wr[qq];
        a = fmaf(w.x, h0[4*qq+0], a);
        a = fmaf(w.y, h0[4*qq+1], a);
        a = fmaf(w.z, h0[4*qq+2], a);
        a = fmaf(w.w, h0[4*qq+3], a);
      }
      h1[c] = fmaxf(a, 0.0f);
    }
  }
  // third conv: per-lane dot for each out channel, wave max-reduce via DPP, keep own channel
  float m0 = 0.0f, m1 = 0.0f;
#pragma unroll 2
  for (int c = 0; c < 128; ++c){
    const float4* wr = (const float4*)(w2 + (size_t)c*64);
    float a = 0.0f;
#pragma unroll
    for (int qq = 0; qq < 16; ++qq){
      float4 w = wr[qq];
      a = fmaf(w.x, h1[4*qq+0], a);
      a = fmaf(w.y, h1[4*qq+1], a);
      a = fmaf(w.z, h1[4*qq+2], a);
      a = fmaf(w.w, h1[4*qq+3], a);
    }
    a = fmaxf(a, 0.0f);
#define SA_MAX(C) { float o = __int_as_float(dpp_i<C>(__float_as_int(a))); a = fmaxf(a, o); }
    SA_MAX(0x111) SA_MAX(0x112) SA_MAX(0x114) SA_MAX(0x118) SA_MAX(0x142) SA_MAX(0x143)
#undef SA_MAX
    float r = __int_as_float(__builtin_amdgcn_readlane(__float_as_int(a), 63));
    if (c < 64){ if (lane == c) m0 = r; }
    else       { if (lane == c - 64) m1 = r; }
  }
  feat[(size_t)bi*128 + lane]      = m0;
  feat[(size_t)bi*128 + 64 + lane] = m1;
  x131[(size_t)bi*132 + lane]      = m0;
  x131[(size_t)bi*132 + 64 + lane] = m1;
  if (lane < 3) x131[(size_t)bi*132 + 128 + lane] = (lane==0)?qx:((lane==1)?qy:qz);
}

// ---------------- feature norms (from xT, coalesced) ----------------
template<int CIN>
__global__ void k_norm2(const float* __restrict__ xT, float* __restrict__ nrm){
  int p = blockIdx.x*64 + threadIdx.x;
  if (p >= BB*NPp) return;
  int b = p >> 8, col = p & 255;
  const float* base = xT + (size_t)b*CIN*256 + col;
  float a = 0.0f;
  for (int m = 0; m < CIN; ++m){
    float v = base[m*256];
    a = __fadd_rn(a, __fmul_rn(v, v));
  }
  nrm[p] = a;
}

// ---------------- kNN, 8 centroids/block, LDS-staged xT chunks ----------------
template<int CIN>
__global__ __launch_bounds__(512) void k_knn3(const float* __restrict__ xT,
    const float* __restrict__ nrm, int* __restrict__ idxo){
  __shared__ __align__(16) float sch[16*256];
  __shared__ __align__(16) float ds[8*256];
  int bi = blockIdx.x, t = threadIdx.x;
  int w = t >> 6, lane = t & 63;
  int b = bi >> 5;
  int coli = (bi & 31)*8 + w;
  const float* xb = xT + (size_t)b*CIN*256;
  float d0=0.f, d1=0.f, d2=0.f, d3=0.f;
  for (int m0 = 0; m0 < CIN; m0 += 16){
    int mc = (CIN - m0 < 16) ? (CIN - m0) : 16;
    for (int i = t; i < mc*64; i += 512){
      int mm = i >> 6, c4 = i & 63;
      *(float4*)(sch + mm*256 + c4*4) = *(const float4*)(xb + (size_t)(m0+mm)*256 + c4*4);
    }
    __syncthreads();
    for (int mm = 0; mm < mc; ++mm){
      float xm = sch[mm*256 + coli];
      float4 v = *(const float4*)(sch + mm*256 + 4*lane);
      d0 = fmaf(v.x, xm, d0); d1 = fmaf(v.y, xm, d1);
      d2 = fmaf(v.z, xm, d2); d3 = fmaf(v.w, xm, d3);
    }
    __syncthreads();
  }
  float ni = nrm[b*256 + coli];
  {
    int j0 = 4*lane;
    float4 dv;
    dv.x = __fsub_rn(__fadd_rn(ni, nrm[b*256 + j0+0]), __fmul_rn(2.0f, d0));
    dv.y = __fsub_rn(__fadd_rn(ni, nrm[b*256 + j0+1]), __fmul_rn(2.0f, d1));
    dv.z = __fsub_rn(__fadd_rn(ni, nrm[b*256 + j0+2]), __fmul_rn(2.0f, d2));
    dv.w = __fsub_rn(__fadd_rn(ni, nrm[b*256 + j0+3]), __fmul_rn(2.0f, d3));
    *(float4*)(ds + w*256 + j0) = dv;
  }
  __syncthreads();
  for (int r = 0; r < KC; ++r){
    float bv = 3.4e38f; int bj = NPp;
    float4 dv = *(const float4*)(ds + w*256 + 4*lane);
#pragma unroll
    for (int q = 0; q < 4; ++q){
      float v = (q==0)?dv.x:((q==1)?dv.y:((q==2)?dv.z:dv.w));
      int j = 4*lane + q;
      if (v < bv){ bv = v; bj = j; }
    }
#pragma unroll
    for (int off = 32; off >= 1; off >>= 1){
      float ov = __shfl_xor(bv, off, 64);
      int   oj = __shfl_xor(bj, off, 64);
      if (ov < bv || (ov == bv && oj < bj)){ bv = ov; bj = oj; }
    }
    if (lane == 0){ idxo[((size_t)b*256 + coli)*KC + r] = bj; ds[w*256 + bj] = 3.0e38f; }
    __syncthreads();
  }
}

// ---------------- per-point dual GEMM + fused xT transpose ----------------
template<int CIN, int COUT, int T>
__global__ __launch_bounds__(T) void k_gab(const float* __restrict__ x, int xstride,
    const float* __restrict__ wA, const float* __restrict__ wB,
    float* __restrict__ A, float* __restrict__ B, float* __restrict__ xT){
  constexpr int PC  = CIN + 1;
  constexpr int G   = COUT/4;
  constexpr int RS  = T/G;
  constexpr int RPT = 16/RS;
  __shared__ float xsh[16*PC];
  int bi = blockIdx.x, t = threadIdx.x;
  int g = t % G, rs = t / G;
  int i0 = bi*16;
  for (int i = t; i < 16*CIN; i += T){
    int r = i / CIN, m = i - r*CIN;
    xsh[r*PC + m] = x[(size_t)(i0+r)*xstride + m];
  }
  __syncthreads();
  {
    int bb = i0 >> 8, col0 = i0 & 255;
    float* xTb = xT + (size_t)bb*CIN*256 + col0;
    for (int i = t; i < 16*CIN; i += T){
      int m = i >> 4, r = i & 15;
      xTb[m*256 + r] = xsh[r*PC + m];
    }
  }
  float4 accA[RPT], accB[RPT];
#pragma unroll
  for (int rr = 0; rr < RPT; ++rr){
    accA[rr] = make_float4(0.f,0.f,0.f,0.f);
    accB[rr] = make_float4(0.f,0.f,0.f,0.f);
  }
  for (int m = 0; m < CIN; ++m){
    float4 wa = *(const float4*)(wA + (size_t)m*COUT + 4*g);
    float4 wb = *(const float4*)(wB + (size_t)m*COUT + 4*g);
#pragma unroll
    for (int rr = 0; rr < RPT; ++rr){
      float xv = xsh[(rs + rr*RS)*PC + m];
      accA[rr] = fma4s(wa, xv, accA[rr]);
      accB[rr] = fma4s(wb, xv, accB[rr]);
    }
  }
#pragma unroll
  for (int rr = 0; rr < RPT; ++rr){
    int r = i0 + rs + rr*RS;
    *(float4*)(A + (size_t)r*COUT + 4*g) = accA[rr];
    *(float4*)(B + (size_t)r*COUT + 4*g) = accB[rr];
  }
}

// ---------------- edge epilogue: out[i][c] = max_k relu(A[i][c] + B[j_ik][c]) ----------------
template<int COUT>
__global__ __launch_bounds__(256) void k_emax(const float* __restrict__ A, const float* __restrict__ Bm,
    const int* __restrict__ idx, float* __restrict__ out){
  constexpr int GT = COUT/4;
  constexpr int NC = 256/GT;
  __shared__ int js[NC*KC];
  int bi = blockIdx.x, t = threadIdx.x;
  int li = t / GT, c4 = (t % GT)*4;
  int ci = bi*NC + li;
  int rb = (ci >> 8) << 8;
  if (t < NC*KC) js[t] = idx[(size_t)bi*NC*KC + t];
  __syncthreads();
  float4 a = *(const float4*)(A + (size_t)ci*COUT + c4);
  float4 p = make_float4(0.f,0.f,0.f,0.f);
#pragma unroll
  for (int k = 0; k < KC; ++k){
    int j = js[li*KC + k];
    float4 b = *(const float4*)(Bm + (size_t)(rb + j)*COUT + c4);
    p = max4(p, add4(a, b));
  }
  *(float4*)(out + (size_t)ci*COUT + c4) = p;
}

// ---------------- T-Net edge: h0 = relu(A0+B0) then 64->128 conv + k-maxpool ----------------
__global__ __launch_bounds__(128) void k_tedge3(const float* __restrict__ A0, const float* __restrict__ B0,
    const int* __restrict__ idx, const float* __restrict__ wt1, float* __restrict__ out){
  __shared__ __align__(16) float h0s[20*68];
  __shared__ __align__(16) float smax[4*128];
  __shared__ int js[KC];
  int bi = blockIdx.x, t = threadIdx.x;
  int cg = t & 31, kg = t >> 5, k0 = kg*5;
  int rb = (bi >> 8) << 8;
  if (t < KC) js[t] = idx[(size_t)bi*KC + t];
  __syncthreads();
  for (int i = t; i < 20*64; i += 128){
    int k = i >> 6, c = i & 63;
    float v = A0[(size_t)bi*64 + c] + B0[(size_t)(rb + js[k])*64 + c];
    h0s[k*68 + c] = fmaxf(v, 0.0f);
  }
  __syncthreads();
  float4 b2[5];
#pragma unroll
  for (int kk = 0; kk < 5; ++kk) b2[kk] = make_float4(0.f,0.f,0.f,0.f);
  for (int m4 = 0; m4 < 16; ++m4){
    float4 e[5];
#pragma unroll
    for (int kk = 0; kk < 5; ++kk) e[kk] = *(const float4*)(h0s + (k0+kk)*68 + 4*m4);
#pragma unroll
    for (int mm = 0; mm < 4; ++mm){
      float4 w = *(const float4*)(wt1 + (4*m4+mm)*128 + 4*cg);
#pragma unroll
      for (int kk = 0; kk < 5; ++kk){
        float ev = (mm==0)?e[kk].x:((mm==1)?e[kk].y:((mm==2)?e[kk].z:e[kk].w));
        b2[kk] = fma4s(w, ev, b2[kk]);
      }
    }
  }
  float4 p = make_float4(0.f,0.f,0.f,0.f);
#pragma unroll
  for (int kk = 0; kk < 5; ++kk) p = max4(p, b2[kk]);
  *(float4*)(smax + kg*128 + 4*cg) = p;
  __syncthreads();
  if (kg == 0){
    float4 r = *(const float4*)(smax + 4*cg);
#pragma unroll
    for (int g = 1; g < 4; ++g) r = max4(r, *(const float4*)(smax + g*128 + 4*cg));
    *(float4*)(out + (size_t)bi*128 + 4*cg) = r;
  }
}

// ---------------- T-Net 128->1024 + pool over points ----------------
__global__ __launch_bounds__(128) void k_tpool(const float* __restrict__ h, const float* __restrict__ W,
    float* __restrict__ g1024){
  int b = blockIdx.x, t = threadIdx.x;
  int c = blockIdx.y*128 + t;
  float4 w[32];
#pragma unroll
  for (int qq = 0; qq < 32; ++qq) w[qq] = *(const float4*)(W + (size_t)c*128 + 4*qq);
  const float* hb = h + (size_t)b*NPp*128;
  float mx = 0.0f;
  for (int i = 0; i < NPp; ++i){
    const float4* hr = (const float4*)(hb + (size_t)i*128);
    float a = 0.0f;
#pragma unroll
    for (int qq = 0; qq < 32; ++qq) a = fma4(w[qq], hr[qq], a);
    mx = fmaxf(mx, a);
  }
  g1024[(size_t)b*1024 + c] = mx;
}

// ---------------- T-Net MLP + 3x3 transform applied to new_xyz ----------------
__global__ __launch_bounds__(256) void k_trest(const float* __restrict__ g1024,
    const float* __restrict__ Wg0, const float* __restrict__ Wg1,
    const float* __restrict__ Wl, const float* __restrict__ bl,
    const float* __restrict__ new_xyz, float* __restrict__ x131){
  __shared__ __align__(16) float g1[1024];
  __shared__ __align__(16) float g5[512];
  __shared__ __align__(16) float g2[256];
  __shared__ float tm[12];
  int b = blockIdx.x, t = threadIdx.x;
  for (int m = t; m < 1024; m += 256) g1[m] = g1024[(size_t)b*1024 + m];
  __syncthreads();
#pragma unroll
  for (int cc = 0; cc < 2; ++cc){
    int c = t + cc*256;
    const float4* wr = (const float4*)(Wg0 + (size_t)c*1024);
    const float4* gv = (const float4*)g1;
    float a = 0.0f;
    for (int qq = 0; qq < 256; ++qq) a = fma4(wr[qq], gv[qq], a);
    g5[c] = fmaxf(a, 0.0f);
  }
  __syncthreads();
  {
    const float4* wr = (const float4*)(Wg1 + (size_t)t*512);
    const float4* gv = (const float4*)g5;
    float a = 0.0f;
    for (int qq = 0; qq < 128; ++qq) a = fma4(wr[qq], gv[qq], a);
    g2[t] = fmaxf(a, 0.0f);
  }
  __syncthreads();
  if (t < 9){
    const float4* wr = (const float4*)(Wl + (size_t)t*256);
    const float4* gv = (const float4*)g2;
    float a = 0.0f;
#pragma unroll
    for (int qq = 0; qq < 64; ++qq) a = fma4(wr[qq], gv[qq], a);
    a += bl[t];
    if (t == 0 || t == 4 || t == 8) a += 1.0f;
    tm[t] = a;
  }
  __syncthreads();
  {
    const float* nx = new_xyz + ((size_t)b*NPp + t)*3;
    float X = nx[0], Y = nx[1], Z = nx[2];
#pragma unroll
    for (int i = 0; i < 3; ++i){
      float v = __fadd_rn(__fadd_rn(__fmul_rn(tm[i*3+0], X), __fmul_rn(tm[i*3+1], Y)), __fmul_rn(tm[i*3+2], Z));
      x131[((size_t)b*NPp + t)*132 + 128 + i] = v;
    }
  }
}

// ---------------- 896->128 conv + global max pool (atomicMax; poison is negative int) ----------------
__global__ __launch_bounds__(128) void k_dgl(const float* __restrict__ f1, const float* __restrict__ f2,
    const float* __restrict__ f3, const float* __restrict__ W, float* __restrict__ g128){
  int b = blockIdx.x, t = threadIdx.x;
  int i0 = blockIdx.y * 16;
  const float* wr = W + (size_t)t*896;
  float acc[16];
#pragma unroll
  for (int ii = 0; ii < 16; ++ii) acc[ii] = 0.0f;
  for (int q = 0; q < 32; ++q){
    float4 w = *(const float4*)(wr + 4*q);
#pragma unroll
    for (int ii = 0; ii < 16; ++ii){
      float4 v = *(const float4*)(f1 + ((size_t)b*NPp + i0 + ii)*128 + 4*q);
      acc[ii] = fma4(w, v, acc[ii]);
    }
  }
  for (int q = 0; q < 64; ++q){
    float4 w = *(const float4*)(wr + 128 + 4*q);
#pragma unroll
    for (int ii = 0; ii < 16; ++ii){
      float4 v = *(const float4*)(f2 + ((size_t)b*NPp + i0 + ii)*256 + 4*q);
      acc[ii] = fma4(w, v, acc[ii]);
    }
  }
  for (int q = 0; q < 128; ++q){
    float4 w = *(const float4*)(wr + 384 + 4*q);
#pragma unroll
    for (int ii = 0; ii < 16; ++ii){
      float4 v = *(const float4*)(f3 + ((size_t)b*NPp + i0 + ii)*512 + 4*q);
      acc[ii] = fma4(w, v, acc[ii]);
    }
  }
#pragma unroll
  for (int ii = 0; ii < 16; ++ii){
    float v = fmaxf(acc[ii], 0.0f);
    atomicMax((int*)(g128 + (size_t)b*128 + t), __float_as_int(v));
  }
}

// ---------------- classifier head ----------------
__global__ __launch_bounds__(256) void k_final(const float* __restrict__ g128,
    const float* __restrict__ W0, const float* __restrict__ W1,
    const float* __restrict__ Wc, const float* __restrict__ bc, float* __restrict__ out){
  __shared__ __align__(16) float g0[128];
  __shared__ __align__(16) float g5[512];
  __shared__ __align__(16) float g2[256];
  int b = blockIdx.x, t = threadIdx.x;
  if (t < 128) g0[t] = g128[(size_t)b*128 + t];
  __syncthreads();
#pragma unroll
  for (int cc = 0; cc < 2; ++cc){
    int c = t + cc*256;
    const float4* wr = (const float4*)(W0 + (size_t)c*128);
    const float4* gv = (const float4*)g0;
    float a = 0.0f;
#pragma unroll
    for (int qq = 0; qq < 32; ++qq) a = fma4(wr[qq], gv[qq], a);
    g5[c] = fmaxf(a, 0.0f);
  }
  __syncthreads();
  {
    const float4* wr = (const float4*)(W1 + (size_t)t*512);
    const float4* gv = (const float4*)g5;
    float a = 0.0f;
    for (int qq = 0; qq < 128; ++qq) a = fma4(wr[qq], gv[qq], a);
    g2[t] = fmaxf(a, 0.0f);
  }
  __syncthreads();
  if (t < 40){
    const float4* wr = (const float4*)(Wc + (size_t)t*256);
    const float4* gv = (const float4*)g2;
    float a = 0.0f;
#pragma unroll
    for (int qq = 0; qq < 64; ++qq) a = fma4(wr[qq], gv[qq], a);
    out[(size_t)b*40 + t] = a + bc[t];
  }
}

extern "C" void kernel_launch(void* const* d_in, const int* in_sizes, int n_in,
                              void* d_out, int out_size, void* d_ws, size_t ws_size,
                              hipStream_t stream){
  (void)in_sizes; (void)n_in; (void)out_size; (void)ws_size;
  const float* points     = (const float*)d_in[0];
  const float* sa_w0      = (const float*)d_in[1];
  const float* sa_w1      = (const float*)d_in[2];
  const float* sa_w2      = (const float*)d_in[3];
  const float* t_ec_w0    = (const float*)d_in[4];
  const float* t_ec_w1    = (const float*)d_in[5];
  const float* t_local_w  = (const float*)d_in[6];
  const float* t_g_w0     = (const float*)d_in[7];
  const float* t_g_w1     = (const float*)d_in[8];
  const float* t_lin_w    = (const float*)d_in[9];
  const float* t_lin_b    = (const float*)d_in[10];
  const float* dg_ec_w0   = (const float*)d_in[11];
  const float* dg_ec_w1   = (const float*)d_in[12];
  const float* dg_ec_w2   = (const float*)d_in[13];
  const float* dg_local_w = (const float*)d_in[14];
  const float* dg_g_w0    = (const float*)d_in[15];
  const float* dg_g_w1    = (const float*)d_in[16];
  const float* cls_w      = (const float*)d_in[17];
  const float* cls_b      = (const float*)d_in[18];
  float* out = (float*)d_out;

  float* ws     = (float*)d_ws;
  float* xyz    = ws;                    // 393216
  float* xnrm   = xyz    + 393216;       // 131072
  float* nxyz   = xnrm   + 131072;       // 24576
  float* feat   = nxyz   + 24576;        // 1048576
  float* x131   = feat   + 1048576;      // 1081344
  float* nrm    = x131   + 1081344;      // 8192
  int*   idx    = (int*)(nrm + 8192);    // 163840
  float* ht     = (float*)(idx + 163840);// 1048576 (reused as f1)
  float* g1024v = ht     + 1048576;      // 32768
  float* f2     = g1024v + 32768;        // 2097152
  float* f3     = f2     + 2097152;      // 4194304
  float* g128v  = f3     + 4194304;      // 4096
  float* wt_t1  = g128v  + 4096;         // 8192   (64x128)
  float* waT0   = wt_t1  + 8192;         // 8384   (131x64)
  float* wbT0   = waT0   + 8384;         // 8384
  float* waD0   = wbT0   + 8384;         // 16768  (131x128)
  float* wbD0   = waD0   + 16768;        // 16768
  float* waD1   = wbD0   + 16768;        // 32768  (128x256)
  float* wbD1   = waD1   + 32768;        // 32768
  float* waD2   = wbD1   + 32768;        // 131072 (256x512)
  float* wbD2   = waD2   + 131072;       // 131072
  float* Ab     = wbD2   + 131072;       // 4194304
  float* Bb     = Ab     + 4194304;      // 4194304
  float* f1 = ht;
  float* xT = f3;                        // alias: xT lives in f3 until k_emax<512> writes f3

  k_prep<<<512, 256, 0, stream>>>(points, xyz, xnrm);
  k_wprep<<<771, 256, 0, stream>>>(t_ec_w0, t_ec_w1, dg_ec_w0, dg_ec_w1, dg_ec_w2,
                                   waT0, wbT0, wt_t1, waD0, wbD0, waD1, wbD1, waD2, wbD2);
  k_fps<<<BB, 256, 0, stream>>>(xyz, nxyz);
  k_sa<<<BB*NPp, 64, 0, stream>>>(xyz, xnrm, nxyz, sa_w0, sa_w1, sa_w2, feat, x131);

  // T-Net branch (x = [feat, new_xyz])
  k_gab<131,64,256><<<512, 256, 0, stream>>>(x131, 132, waT0, wbT0, Ab, Bb, xT);
  k_norm2<131><<<128, 64, 0, stream>>>(xT, nrm);
  k_knn3<131><<<1024, 512, 0, stream>>>(xT, nrm, idx);
  k_tedge3<<<BB*NPp, 128, 0, stream>>>(Ab, Bb, idx, wt_t1, ht);
  k_tpool<<<dim3(BB, 8), 128, 0, stream>>>(ht, t_local_w, g1024v);
  k_trest<<<BB, 256, 0, stream>>>(g1024v, t_g_w0, t_g_w1, t_lin_w, t_lin_b, nxyz, x131);

  // DGCNN layer 1 (x = [feat, xyz_t], 131 dims)
  k_gab<131,128,512><<<512, 512, 0, stream>>>(x131, 132, waD0, wbD0, Ab, Bb, xT);
  k_norm2<131><<<128, 64, 0, stream>>>(xT, nrm);
  k_knn3<131><<<1024, 512, 0, stream>>>(xT, nrm, idx);
  k_emax<128><<<1024, 256, 0, stream>>>(Ab, Bb, idx, f1);
  // layer 2
  k_gab<128,256,512><<<512, 512, 0, stream>>>(f1, 128, waD1, wbD1, Ab, Bb, xT);
  k_norm2<128><<<128, 64, 0, stream>>>(xT, nrm);
  k_knn3<128><<<1024, 512, 0, stream>>>(xT, nrm, idx);
  k_emax<256><<<2048, 256, 0, stream>>>(Ab, Bb, idx, f2);
  // layer 3
  k_gab<256,512,512><<<512, 512, 0, stream>>>(f2, 256, waD2, wbD2, Ab, Bb, xT);
  k_norm2<256><<<128, 64, 0, stream>>>(xT, nrm);
  k_knn3<256><<<1024, 512, 0, stream>>>(xT, nrm, idx);
  k_emax<512><<<4096, 256, 0, stream>>>(Ab, Bb, idx, f3);

  // local conv + global pool + head
  k_dgl<<<dim3(BB, 16), 128, 0, stream>>>(f1, f2, f3, dg_local_w, g128v);
  k_final<<<BB, 256, 0, stream>>>(g128v, dg_g_w0, dg_g_w1, cls_w, cls_b, out);
}

// Round 8
// 1750.913 us; speedup vs baseline: 1.0342x; 1.0342x over previous
//
#include <hip/hip_runtime.h>
#include <math.h>

#define BB 32
#define NN 4096
#define NPp 256
#define NSs 64
#define KC 20

__device__ __forceinline__ float fma4(const float4 w, const float4 v, float a){
  a = fmaf(w.x, v.x, a); a = fmaf(w.y, v.y, a);
  a = fmaf(w.z, v.z, a); a = fmaf(w.w, v.w, a); return a;
}
__device__ __forceinline__ float4 fma4s(const float4 w, float s, float4 a){
  a.x = fmaf(w.x, s, a.x); a.y = fmaf(w.y, s, a.y);
  a.z = fmaf(w.z, s, a.z); a.w = fmaf(w.w, s, a.w); return a;
}
__device__ __forceinline__ float4 max4(float4 a, float4 b){
  a.x = fmaxf(a.x, b.x); a.y = fmaxf(a.y, b.y);
  a.z = fmaxf(a.z, b.z); a.w = fmaxf(a.w, b.w); return a;
}
__device__ __forceinline__ float4 add4(float4 a, float4 b){
  a.x += b.x; a.y += b.y; a.z += b.z; a.w += b.w; return a;
}

template<int C>
__device__ __forceinline__ int dpp_i(int x){
  return __builtin_amdgcn_update_dpp(x, x, C, 0xf, 0xf, false);
}

// ---------------- unified weight prep (all transposes/splits in one kernel) ----------------
__global__ void k_wprep(const float* __restrict__ t0, const float* __restrict__ t1,
                        const float* __restrict__ d0, const float* __restrict__ d1,
                        const float* __restrict__ d2,
                        float* __restrict__ waT0, float* __restrict__ wbT0,
                        float* __restrict__ wt_t1,
                        float* __restrict__ waD0, float* __restrict__ wbD0,
                        float* __restrict__ waD1, float* __restrict__ wbD1,
                        float* __restrict__ waD2, float* __restrict__ wbD2){
  int i = blockIdx.x*256 + threadIdx.x;
  if (i < 8384){                       // t_ec_w0: [64][262] -> A/B [131][64]
    int m = i >> 6;
    int c = i & 63;
    float bb = t0[(size_t)c*262 + m];
    float dd = t0[(size_t)c*262 + 131 + m];
    waT0[i] = __fsub_rn(bb, dd); wbT0[i] = dd;
    return;
  }
  i -= 8384;
  if (i < 8192){                       // t_ec_w1: [128][64] -> [64][128]
    int m = i >> 7, c = i & 127;
    wt_t1[i] = t1[(size_t)c*64 + m];
    return;
  }
  i -= 8192;
  if (i < 16768){                      // dg_ec_w0: [128][262] -> A/B [131][128]
    int m = i >> 7, c = i & 127;
    float bb = d0[(size_t)c*262 + m];
    float dd = d0[(size_t)c*262 + 131 + m];
    waD0[i] = __fsub_rn(bb, dd); wbD0[i] = dd;
    return;
  }
  i -= 16768;
  if (i < 32768){                      // dg_ec_w1: [256][256] -> A/B [128][256]
    int m = i >> 8, c = i & 255;
    float bb = d1[(size_t)c*256 + m];
    float dd = d1[(size_t)c*256 + 128 + m];
    waD1[i] = __fsub_rn(bb, dd); wbD1[i] = dd;
    return;
  }
  i -= 32768;
  if (i < 131072){                     // dg_ec_w2: [512][512] -> A/B [256][512]
    int m = i >> 9, c = i & 511;
    float bb = d2[(size_t)c*512 + m];
    float dd = d2[(size_t)c*512 + 256 + m];
    waD2[i] = __fsub_rn(bb, dd); wbD2[i] = dd;
  }
}

// ---------------- transpose + point norms ----------------
__global__ void k_prep(const float* __restrict__ pts, float* __restrict__ xyz, float* __restrict__ xnrm){
  int i = blockIdx.x*256 + threadIdx.x;
  if (i >= BB*NN) return;
  int b = i >> 12, n = i & (NN-1);
  float X = pts[(b*3+0)*NN + n];
  float Y = pts[(b*3+1)*NN + n];
  float Z = pts[(b*3+2)*NN + n];
  xyz[i*3+0]=X; xyz[i*3+1]=Y; xyz[i*3+2]=Z;
  xnrm[i] = __fadd_rn(__fadd_rn(__fmul_rn(X,X), __fmul_rn(Y,Y)), __fmul_rn(Z,Z));
}

// ---------------- farthest point sampling: registers + DPP reduce, 1 barrier/iter ----------------
__global__ __launch_bounds__(256) void k_fps(const float* __restrict__ xyz, float* __restrict__ new_xyz){
  __shared__ float part[2][4][8];
  int b = blockIdx.x, t = threadIdx.x;
  int w = t >> 6;
  float px[16], py[16], pz[16], dist[16];
#pragma unroll
  for (int q = 0; q < 16; ++q){
    const float* p = xyz + ((size_t)b*NN + q*256 + t)*3;
    px[q] = p[0]; py[q] = p[1]; pz[q] = p[2];
    dist[q] = __builtin_inff();
  }
  const float* p0 = xyz + (size_t)b*NN*3;
  float Px = p0[0], Py = p0[1], Pz = p0[2];
  for (int it = 0; it < NPp; ++it){
    if (t == 0){
      float* o = new_xyz + ((size_t)b*NPp + it)*3;
      o[0] = Px; o[1] = Py; o[2] = Pz;
    }
    float bv = -1.0f, bx = 0.f, by = 0.f, bz = 0.f; int bj = 0;
#pragma unroll
    for (int q = 0; q < 16; ++q){
      float dx = __fsub_rn(px[q], Px);
      float dy = __fsub_rn(py[q], Py);
      float dz = __fsub_rn(pz[q], Pz);
      float dd = __fadd_rn(__fadd_rn(__fmul_rn(dx,dx), __fmul_rn(dy,dy)), __fmul_rn(dz,dz));
      float dm = fminf(dist[q], dd);
      dist[q] = dm;
      if (dm > bv){ bv = dm; bj = q*256 + t; bx = px[q]; by = py[q]; bz = pz[q]; }
    }
#define FPS_STAGE(C) { \
    float ov = __int_as_float(dpp_i<C>(__float_as_int(bv))); \
    int   oj = dpp_i<C>(bj); \
    float ox = __int_as_float(dpp_i<C>(__float_as_int(bx))); \
    float oy = __int_as_float(dpp_i<C>(__float_as_int(by))); \
    float oz = __int_as_float(dpp_i<C>(__float_as_int(bz))); \
    bool tk = (ov > bv) || (ov == bv && oj < bj); \
    bv = tk ? ov : bv; bj = tk ? oj : bj; \
    bx = tk ? ox : bx; by = tk ? oy : by; bz = tk ? oz : bz; }
    FPS_STAGE(0x111) FPS_STAGE(0x112) FPS_STAGE(0x114) FPS_STAGE(0x118)
    FPS_STAGE(0x142) FPS_STAGE(0x143)
#undef FPS_STAGE
    int par = it & 1;
    if ((t & 63) == 63){
      float* pp = part[par][w];
      pp[0] = bv; ((int*)pp)[1] = bj; pp[2] = bx; pp[3] = by; pp[4] = bz;
    }
    __syncthreads();
    const float* q0 = part[par][0];
    float fv = q0[0]; int fj = ((const int*)q0)[1];
    float fx = q0[2], fy = q0[3], fz = q0[4];
#pragma unroll
    for (int ww = 1; ww < 4; ++ww){
      const float* pp = part[par][ww];
      float ov = pp[0]; int oj = ((const int*)pp)[1];
      if (ov > fv || (ov == fv && oj < fj)){ fv = ov; fj = oj; fx = pp[2]; fy = pp[3]; fz = pp[4]; }
    }
    Px = fx; Py = fy; Pz = fz;
  }
}

// ---------------- ball query + SA convs + maxpool (regs, tiled mid-layer, no spill) ----------------
__global__ __launch_bounds__(64, 1) void k_sa(const float* __restrict__ xyz, const float* __restrict__ xnrm,
    const float* __restrict__ new_xyz, const float* __restrict__ w0, const float* __restrict__ w1,
    const float* __restrict__ w2, float* __restrict__ feat, float* __restrict__ x131){
  __shared__ int gix[64];
  int bi = blockIdx.x, lane = threadIdx.x;
  int b = bi >> 8;
  const float* q = new_xyz + (size_t)bi*3;
  float qx=q[0], qy=q[1], qz=q[2];
  float nq = __fadd_rn(__fadd_rn(__fmul_rn(qx,qx), __fmul_rn(qy,qy)), __fmul_rn(qz,qz));
  int cnt = 0;
  for (int base = 0; base < NN && cnt < NSs; base += 256){
#pragma unroll
    for (int u = 0; u < 4; ++u){
      int j = base + u*64 + lane;
      const float* p = xyz + ((size_t)b*NN + j)*3;
      float dot = __fadd_rn(__fadd_rn(__fmul_rn(qx,p[0]), __fmul_rn(qy,p[1])), __fmul_rn(qz,p[2]));
      float d2 = __fsub_rn(__fadd_rn(nq, xnrm[b*NN + j]), __fmul_rn(2.0f, dot));
      bool inb = d2 < 0.04f;
      unsigned long long m = __ballot(inb);
      int pos = cnt + (int)__popcll(m & ((1ull << lane) - 1ull));
      if (inb && pos < NSs) gix[pos] = j;
      cnt += (int)__popcll(m);
    }
  }
  __syncthreads();
  int g0 = gix[0];
  if (lane >= cnt) gix[lane] = g0;
  __syncthreads();
  // lane = sample; mid layer tiled in 2 halves to cap register pressure (~110 VGPR peak)
  float h1[64];
  {
    int gj = gix[lane];
    const float* p = xyz + ((size_t)b*NN + gj)*3;
    float px = p[0]-qx, py = p[1]-qy, pz = p[2]-qz;
#pragma unroll
    for (int c = 0; c < 64; ++c) h1[c] = 0.0f;
#pragma unroll
    for (int half = 0; half < 2; ++half){
      float h0h[32];
#pragma unroll
      for (int mm = 0; mm < 32; ++mm){
        int c = half*32 + mm;
        float a = fmaf(w0[c*3+2], pz, fmaf(w0[c*3+1], py, w0[c*3]*px));
        h0h[mm] = fmaxf(a, 0.0f);
      }
      for (int c = 0; c < 64; ++c){
        const float4* wr = (const float4*)(w1 + c*64 + half*32);
        float a = h1[c];
#pragma unroll
        for (int qq = 0; qq < 8; ++qq){
          float4 w = wr[qq];
          a = fmaf(w.x, h0h[4*qq+0], a);
          a = fmaf(w.y, h0h[4*qq+1], a);
          a = fmaf(w.z, h0h[4*qq+2], a);
          a = fmaf(w.w, h0h[4*qq+3], a);
        }
        h1[c] = a;
      }
    }
#pragma unroll
    for (int c = 0; c < 64; ++c) h1[c] = fmaxf(h1[c], 0.0f);
  }
  // third conv: per-lane dot for each out channel, wave max-reduce via DPP, keep own channel
  float m0 = 0.0f, m1 = 0.0f;
#pragma unroll 2
  for (int c = 0; c < 128; ++c){
    const float4* wr = (const float4*)(w2 + (size_t)c*64);
    float a = 0.0f;
#pragma unroll
    for (int qq = 0; qq < 16; ++qq){
      float4 w = wr[qq];
      a = fmaf(w.x, h1[4*qq+0], a);
      a = fmaf(w.y, h1[4*qq+1], a);
      a = fmaf(w.z, h1[4*qq+2], a);
      a = fmaf(w.w, h1[4*qq+3], a);
    }
    a = fmaxf(a, 0.0f);
#define SA_MAX(C) { float o = __int_as_float(dpp_i<C>(__float_as_int(a))); a = fmaxf(a, o); }
    SA_MAX(0x111) SA_MAX(0x112) SA_MAX(0x114) SA_MAX(0x118) SA_MAX(0x142) SA_MAX(0x143)
#undef SA_MAX
    float r = __int_as_float(__builtin_amdgcn_readlane(__float_as_int(a), 63));
    if (c < 64){ if (lane == c) m0 = r; }
    else       { if (lane == c - 64) m1 = r; }
  }
  feat[(size_t)bi*128 + lane]      = m0;
  feat[(size_t)bi*128 + 64 + lane] = m1;
  x131[(size_t)bi*132 + lane]      = m0;
  x131[(size_t)bi*132 + 64 + lane] = m1;
  if (lane < 3) x131[(size_t)bi*132 + 128 + lane] = (lane==0)?qx:((lane==1)?qy:qz);
}

// ---------------- feature norms (from xT, coalesced) ----------------
template<int CIN>
__global__ void k_norm2(const float* __restrict__ xT, float* __restrict__ nrm){
  int p = blockIdx.x*64 + threadIdx.x;
  if (p >= BB*NPp) return;
  int b = p >> 8, col = p & 255;
  const float* base = xT + (size_t)b*CIN*256 + col;
  float a = 0.0f;
  for (int m = 0; m < CIN; ++m){
    float v = base[m*256];
    a = __fadd_rn(a, __fmul_rn(v, v));
  }
  nrm[p] = a;
}

// ---------------- kNN, 8 centroids/block, LDS-staged xT chunks ----------------
template<int CIN>
__global__ __launch_bounds__(512) void k_knn3(const float* __restrict__ xT,
    const float* __restrict__ nrm, int* __restrict__ idxo){
  __shared__ __align__(16) float sch[16*256];
  __shared__ __align__(16) float ds[8*256];
  int bi = blockIdx.x, t = threadIdx.x;
  int w = t >> 6, lane = t & 63;
  int b = bi >> 5;
  int coli = (bi & 31)*8 + w;
  const float* xb = xT + (size_t)b*CIN*256;
  float d0=0.f, d1=0.f, d2=0.f, d3=0.f;
  for (int m0 = 0; m0 < CIN; m0 += 16){
    int mc = (CIN - m0 < 16) ? (CIN - m0) : 16;
    for (int i = t; i < mc*64; i += 512){
      int mm = i >> 6, c4 = i & 63;
      *(float4*)(sch + mm*256 + c4*4) = *(const float4*)(xb + (size_t)(m0+mm)*256 + c4*4);
    }
    __syncthreads();
    for (int mm = 0; mm < mc; ++mm){
      float xm = sch[mm*256 + coli];
      float4 v = *(const float4*)(sch + mm*256 + 4*lane);
      d0 = fmaf(v.x, xm, d0); d1 = fmaf(v.y, xm, d1);
      d2 = fmaf(v.z, xm, d2); d3 = fmaf(v.w, xm, d3);
    }
    __syncthreads();
  }
  float ni = nrm[b*256 + coli];
  {
    int j0 = 4*lane;
    float4 dv;
    dv.x = __fsub_rn(__fadd_rn(ni, nrm[b*256 + j0+0]), __fmul_rn(2.0f, d0));
    dv.y = __fsub_rn(__fadd_rn(ni, nrm[b*256 + j0+1]), __fmul_rn(2.0f, d1));
    dv.z = __fsub_rn(__fadd_rn(ni, nrm[b*256 + j0+2]), __fmul_rn(2.0f, d2));
    dv.w = __fsub_rn(__fadd_rn(ni, nrm[b*256 + j0+3]), __fmul_rn(2.0f, d3));
    *(float4*)(ds + w*256 + j0) = dv;
  }
  __syncthreads();
  for (int r = 0; r < KC; ++r){
    float bv = 3.4e38f; int bj = NPp;
    float4 dv = *(const float4*)(ds + w*256 + 4*lane);
#pragma unroll
    for (int q = 0; q < 4; ++q){
      float v = (q==0)?dv.x:((q==1)?dv.y:((q==2)?dv.z:dv.w));
      int j = 4*lane + q;
      if (v < bv){ bv = v; bj = j; }
    }
#pragma unroll
    for (int off = 32; off >= 1; off >>= 1){
      float ov = __shfl_xor(bv, off, 64);
      int   oj = __shfl_xor(bj, off, 64);
      if (ov < bv || (ov == bv && oj < bj)){ bv = ov; bj = oj; }
    }
    if (lane == 0){ idxo[((size_t)b*256 + coli)*KC + r] = bj; ds[w*256 + bj] = 3.0e38f; }
    __syncthreads();
  }
}

// ---------------- per-point dual GEMM + fused xT transpose ----------------
template<int CIN, int COUT, int T>
__global__ __launch_bounds__(T) void k_gab(const float* __restrict__ x, int xstride,
    const float* __restrict__ wA, const float* __restrict__ wB,
    float* __restrict__ A, float* __restrict__ B, float* __restrict__ xT){
  constexpr int PC  = CIN + 1;
  constexpr int G   = COUT/4;
  constexpr int RS  = T/G;
  constexpr int RPT = 16/RS;
  __shared__ float xsh[16*PC];
  int bi = blockIdx.x, t = threadIdx.x;
  int g = t % G, rs = t / G;
  int i0 = bi*16;
  for (int i = t; i < 16*CIN; i += T){
    int r = i / CIN, m = i - r*CIN;
    xsh[r*PC + m] = x[(size_t)(i0+r)*xstride + m];
  }
  __syncthreads();
  {
    int bb = i0 >> 8, col0 = i0 & 255;
    float* xTb = xT + (size_t)bb*CIN*256 + col0;
    for (int i = t; i < 16*CIN; i += T){
      int m = i >> 4, r = i & 15;
      xTb[m*256 + r] = xsh[r*PC + m];
    }
  }
  float4 accA[RPT], accB[RPT];
#pragma unroll
  for (int rr = 0; rr < RPT; ++rr){
    accA[rr] = make_float4(0.f,0.f,0.f,0.f);
    accB[rr] = make_float4(0.f,0.f,0.f,0.f);
  }
  for (int m = 0; m < CIN; ++m){
    float4 wa = *(const float4*)(wA + (size_t)m*COUT + 4*g);
    float4 wb = *(const float4*)(wB + (size_t)m*COUT + 4*g);
#pragma unroll
    for (int rr = 0; rr < RPT; ++rr){
      float xv = xsh[(rs + rr*RS)*PC + m];
      accA[rr] = fma4s(wa, xv, accA[rr]);
      accB[rr] = fma4s(wb, xv, accB[rr]);
    }
  }
#pragma unroll
  for (int rr = 0; rr < RPT; ++rr){
    int r = i0 + rs + rr*RS;
    *(float4*)(A + (size_t)r*COUT + 4*g) = accA[rr];
    *(float4*)(B + (size_t)r*COUT + 4*g) = accB[rr];
  }
}

// ---------------- edge epilogue: out[i][c] = max_k relu(A[i][c] + B[j_ik][c]) ----------------
template<int COUT>
__global__ __launch_bounds__(256) void k_emax(const float* __restrict__ A, const float* __restrict__ Bm,
    const int* __restrict__ idx, float* __restrict__ out){
  constexpr int GT = COUT/4;
  constexpr int NC = 256/GT;
  __shared__ int js[NC*KC];
  int bi = blockIdx.x, t = threadIdx.x;
  int li = t / GT, c4 = (t % GT)*4;
  int ci = bi*NC + li;
  int rb = (ci >> 8) << 8;
  if (t < NC*KC) js[t] = idx[(size_t)bi*NC*KC + t];
  __syncthreads();
  float4 a = *(const float4*)(A + (size_t)ci*COUT + c4);
  float4 p = make_float4(0.f,0.f,0.f,0.f);
#pragma unroll
  for (int k = 0; k < KC; ++k){
    int j = js[li*KC + k];
    float4 b = *(const float4*)(Bm + (size_t)(rb + j)*COUT + c4);
    p = max4(p, add4(a, b));
  }
  *(float4*)(out + (size_t)ci*COUT + c4) = p;
}

// ---------------- T-Net edge: h0 = relu(A0+B0) then 64->128 conv + k-maxpool ----------------
__global__ __launch_bounds__(128) void k_tedge3(const float* __restrict__ A0, const float* __restrict__ B0,
    const int* __restrict__ idx, const float* __restrict__ wt1, float* __restrict__ out){
  __shared__ __align__(16) float h0s[20*68];
  __shared__ __align__(16) float smax[4*128];
  __shared__ int js[KC];
  int bi = blockIdx.x, t = threadIdx.x;
  int cg = t & 31, kg = t >> 5, k0 = kg*5;
  int rb = (bi >> 8) << 8;
  if (t < KC) js[t] = idx[(size_t)bi*KC + t];
  __syncthreads();
  for (int i = t; i < 20*64; i += 128){
    int k = i >> 6, c = i & 63;
    float v = A0[(size_t)bi*64 + c] + B0[(size_t)(rb + js[k])*64 + c];
    h0s[k*68 + c] = fmaxf(v, 0.0f);
  }
  __syncthreads();
  float4 b2[5];
#pragma unroll
  for (int kk = 0; kk < 5; ++kk) b2[kk] = make_float4(0.f,0.f,0.f,0.f);
  for (int m4 = 0; m4 < 16; ++m4){
    float4 e[5];
#pragma unroll
    for (int kk = 0; kk < 5; ++kk) e[kk] = *(const float4*)(h0s + (k0+kk)*68 + 4*m4);
#pragma unroll
    for (int mm = 0; mm < 4; ++mm){
      float4 w = *(const float4*)(wt1 + (4*m4+mm)*128 + 4*cg);
#pragma unroll
      for (int kk = 0; kk < 5; ++kk){
        float ev = (mm==0)?e[kk].x:((mm==1)?e[kk].y:((mm==2)?e[kk].z:e[kk].w));
        b2[kk] = fma4s(w, ev, b2[kk]);
      }
    }
  }
  float4 p = make_float4(0.f,0.f,0.f,0.f);
#pragma unroll
  for (int kk = 0; kk < 5; ++kk) p = max4(p, b2[kk]);
  *(float4*)(smax + kg*128 + 4*cg) = p;
  __syncthreads();
  if (kg == 0){
    float4 r = *(const float4*)(smax + 4*cg);
#pragma unroll
    for (int g = 1; g < 4; ++g) r = max4(r, *(const float4*)(smax + g*128 + 4*cg));
    *(float4*)(out + (size_t)bi*128 + 4*cg) = r;
  }
}

// ---------------- T-Net 128->1024 + pool over points ----------------
__global__ __launch_bounds__(128) void k_tpool(const float* __restrict__ h, const float* __restrict__ W,
    float* __restrict__ g1024){
  int b = blockIdx.x, t = threadIdx.x;
  int c = blockIdx.y*128 + t;
  float4 w[32];
#pragma unroll
  for (int qq = 0; qq < 32; ++qq) w[qq] = *(const float4*)(W + (size_t)c*128 + 4*qq);
  const float* hb = h + (size_t)b*NPp*128;
  float mx = 0.0f;
  for (int i = 0; i < NPp; ++i){
    const float4* hr = (const float4*)(hb + (size_t)i*128);
    float a = 0.0f;
#pragma unroll
    for (int qq = 0; qq < 32; ++qq) a = fma4(w[qq], hr[qq], a);
    mx = fmaxf(mx, a);
  }
  g1024[(size_t)b*1024 + c] = mx;
}

// ---------------- T-Net MLP + 3x3 transform applied to new_xyz ----------------
__global__ __launch_bounds__(256) void k_trest(const float* __restrict__ g1024,
    const float* __restrict__ Wg0, const float* __restrict__ Wg1,
    const float* __restrict__ Wl, const float* __restrict__ bl,
    const float* __restrict__ new_xyz, float* __restrict__ x131){
  __shared__ __align__(16) float g1[1024];
  __shared__ __align__(16) float g5[512];
  __shared__ __align__(16) float g2[256];
  __shared__ float tm[12];
  int b = blockIdx.x, t = threadIdx.x;
  for (int m = t; m < 1024; m += 256) g1[m] = g1024[(size_t)b*1024 + m];
  __syncthreads();
#pragma unroll
  for (int cc = 0; cc < 2; ++cc){
    int c = t + cc*256;
    const float4* wr = (const float4*)(Wg0 + (size_t)c*1024);
    const float4* gv = (const float4*)g1;
    float a = 0.0f;
    for (int qq = 0; qq < 256; ++qq) a = fma4(wr[qq], gv[qq], a);
    g5[c] = fmaxf(a, 0.0f);
  }
  __syncthreads();
  {
    const float4* wr = (const float4*)(Wg1 + (size_t)t*512);
    const float4* gv = (const float4*)g5;
    float a = 0.0f;
    for (int qq = 0; qq < 128; ++qq) a = fma4(wr[qq], gv[qq], a);
    g2[t] = fmaxf(a, 0.0f);
  }
  __syncthreads();
  if (t < 9){
    const float4* wr = (const float4*)(Wl + (size_t)t*256);
    const float4* gv = (const float4*)g2;
    float a = 0.0f;
#pragma unroll
    for (int qq = 0; qq < 64; ++qq) a = fma4(wr[qq], gv[qq], a);
    a += bl[t];
    if (t == 0 || t == 4 || t == 8) a += 1.0f;
    tm[t] = a;
  }
  __syncthreads();
  {
    const float* nx = new_xyz + ((size_t)b*NPp + t)*3;
    float X = nx[0], Y = nx[1], Z = nx[2];
#pragma unroll
    for (int i = 0; i < 3; ++i){
      float v = __fadd_rn(__fadd_rn(__fmul_rn(tm[i*3+0], X), __fmul_rn(tm[i*3+1], Y)), __fmul_rn(tm[i*3+2], Z));
      x131[((size_t)b*NPp + t)*132 + 128 + i] = v;
    }
  }
}

// ---------------- 896->128 conv + global max pool (atomicMax; poison is negative int) ----------------
__global__ __launch_bounds__(128) void k_dgl(const float* __restrict__ f1, const float* __restrict__ f2,
    const float* __restrict__ f3, const float* __restrict__ W, float* __restrict__ g128){
  int b = blockIdx.x, t = threadIdx.x;
  int i0 = blockIdx.y * 16;
  const float* wr = W + (size_t)t*896;
  float acc[16];
#pragma unroll
  for (int ii = 0; ii < 16; ++ii) acc[ii] = 0.0f;
  for (int q = 0; q < 32; ++q){
    float4 w = *(const float4*)(wr + 4*q);
#pragma unroll
    for (int ii = 0; ii < 16; ++ii){
      float4 v = *(const float4*)(f1 + ((size_t)b*NPp + i0 + ii)*128 + 4*q);
      acc[ii] = fma4(w, v, acc[ii]);
    }
  }
  for (int q = 0; q < 64; ++q){
    float4 w = *(const float4*)(wr + 128 + 4*q);
#pragma unroll
    for (int ii = 0; ii < 16; ++ii){
      float4 v = *(const float4*)(f2 + ((size_t)b*NPp + i0 + ii)*256 + 4*q);
      acc[ii] = fma4(w, v, acc[ii]);
    }
  }
  for (int q = 0; q < 128; ++q){
    float4 w = *(const float4*)(wr + 384 + 4*q);
#pragma unroll
    for (int ii = 0; ii < 16; ++ii){
      float4 v = *(const float4*)(f3 + ((size_t)b*NPp + i0 + ii)*512 + 4*q);
      acc[ii] = fma4(w, v, acc[ii]);
    }
  }
#pragma unroll
  for (int ii = 0; ii < 16; ++ii){
    float v = fmaxf(acc[ii], 0.0f);
    atomicMax((int*)(g128 + (size_t)b*128 + t), __float_as_int(v));
  }
}

// ---------------- classifier head ----------------
__global__ __launch_bounds__(256) void k_final(const float* __restrict__ g128,
    const float* __restrict__ W0, const float* __restrict__ W1,
    const float* __restrict__ Wc, const float* __restrict__ bc, float* __restrict__ out){
  __shared__ __align__(16) float g0[128];
  __shared__ __align__(16) float g5[512];
  __shared__ __align__(16) float g2[256];
  int b = blockIdx.x, t = threadIdx.x;
  if (t < 128) g0[t] = g128[(size_t)b*128 + t];
  __syncthreads();
#pragma unroll
  for (int cc = 0; cc < 2; ++cc){
    int c = t + cc*256;
    const float4* wr = (const float4*)(W0 + (size_t)c*128);
    const float4* gv = (const float4*)g0;
    float a = 0.0f;
#pragma unroll
    for (int qq = 0; qq < 32; ++qq) a = fma4(wr[qq], gv[qq], a);
    g5[c] = fmaxf(a, 0.0f);
  }
  __syncthreads();
  {
    const float4* wr = (const float4*)(W1 + (size_t)t*512);
    const float4* gv = (const float4*)g5;
    float a = 0.0f;
    for (int qq = 0; qq < 128; ++qq) a = fma4(wr[qq], gv[qq], a);
    g2[t] = fmaxf(a, 0.0f);
  }
  __syncthreads();
  if (t < 40){
    const float4* wr = (const float4*)(Wc + (size_t)t*256);
    const float4* gv = (const float4*)g2;
    float a = 0.0f;
#pragma unroll
    for (int qq = 0; qq < 64; ++qq) a = fma4(wr[qq], gv[qq], a);
    out[(size_t)b*40 + t] = a + bc[t];
  }
}

extern "C" void kernel_launch(void* const* d_in, const int* in_sizes, int n_in,
                              void* d_out, int out_size, void* d_ws, size_t ws_size,
                              hipStream_t stream){
  (void)in_sizes; (void)n_in; (void)out_size; (void)ws_size;
  const float* points     = (const float*)d_in[0];
  const float* sa_w0      = (const float*)d_in[1];
  const float* sa_w1      = (const float*)d_in[2];
  const float* sa_w2      = (const float*)d_in[3];
  const float* t_ec_w0    = (const float*)d_in[4];
  const float* t_ec_w1    = (const float*)d_in[5];
  const float* t_local_w  = (const float*)d_in[6];
  const float* t_g_w0     = (const float*)d_in[7];
  const float* t_g_w1     = (const float*)d_in[8];
  const float* t_lin_w    = (const float*)d_in[9];
  const float* t_lin_b    = (const float*)d_in[10];
  const float* dg_ec_w0   = (const float*)d_in[11];
  const float* dg_ec_w1   = (const float*)d_in[12];
  const float* dg_ec_w2   = (const float*)d_in[13];
  const float* dg_local_w = (const float*)d_in[14];
  const float* dg_g_w0    = (const float*)d_in[15];
  const float* dg_g_w1    = (const float*)d_in[16];
  const float* cls_w      = (const float*)d_in[17];
  const float* cls_b      = (const float*)d_in[18];
  float* out = (float*)d_out;

  float* ws     = (float*)d_ws;
  float* xyz    = ws;                    // 393216
  float* xnrm   = xyz    + 393216;       // 131072
  float* nxyz   = xnrm   + 131072;       // 24576
  float* feat   = nxyz   + 24576;        // 1048576
  float* x131   = feat   + 1048576;      // 1081344
  float* nrm    = x131   + 1081344;      // 8192
  int*   idx    = (int*)(nrm + 8192);    // 163840
  float* ht     = (float*)(idx + 163840);// 1048576 (reused as f1)
  float* g1024v = ht     + 1048576;      // 32768
  float* f2     = g1024v + 32768;        // 2097152
  float* f3     = f2     + 2097152;      // 4194304
  float* g128v  = f3     + 4194304;      // 4096
  float* wt_t1  = g128v  + 4096;         // 8192   (64x128)
  float* waT0   = wt_t1  + 8192;         // 8384   (131x64)
  float* wbT0   = waT0   + 8384;         // 8384
  float* waD0   = wbT0   + 8384;         // 16768  (131x128)
  float* wbD0   = waD0   + 16768;        // 16768
  float* waD1   = wbD0   + 16768;        // 32768  (128x256)
  float* wbD1   = waD1   + 32768;        // 32768
  float* waD2   = wbD1   + 32768;        // 131072 (256x512)
  float* wbD2   = waD2   + 131072;       // 131072
  float* Ab     = wbD2   + 131072;       // 4194304
  float* Bb     = Ab     + 4194304;      // 4194304
  float* f1 = ht;
  float* xT = f3;                        // alias: xT lives in f3 until k_emax<512> writes f3

  k_prep<<<512, 256, 0, stream>>>(points, xyz, xnrm);
  k_wprep<<<771, 256, 0, stream>>>(t_ec_w0, t_ec_w1, dg_ec_w0, dg_ec_w1, dg_ec_w2,
                                   waT0, wbT0, wt_t1, waD0, wbD0, waD1, wbD1, waD2, wbD2);
  k_fps<<<BB, 256, 0, stream>>>(xyz, nxyz);
  k_sa<<<BB*NPp, 64, 0, stream>>>(xyz, xnrm, nxyz, sa_w0, sa_w1, sa_w2, feat, x131);

  // T-Net branch (x = [feat, new_xyz])
  k_gab<131,64,256><<<512, 256, 0, stream>>>(x131, 132, waT0, wbT0, Ab, Bb, xT);
  k_norm2<131><<<128, 64, 0, stream>>>(xT, nrm);
  k_knn3<131><<<1024, 512, 0, stream>>>(xT, nrm, idx);
  k_tedge3<<<BB*NPp, 128, 0, stream>>>(Ab, Bb, idx, wt_t1, ht);
  k_tpool<<<dim3(BB, 8), 128, 0, stream>>>(ht, t_local_w, g1024v);
  k_trest<<<BB, 256, 0, stream>>>(g1024v, t_g_w0, t_g_w1, t_lin_w, t_lin_b, nxyz, x131);

  // DGCNN layer 1 (x = [feat, xyz_t], 131 dims)
  k_gab<131,128,512><<<512, 512, 0, stream>>>(x131, 132, waD0, wbD0, Ab, Bb, xT);
  k_norm2<131><<<128, 64, 0, stream>>>(xT, nrm);
  k_knn3<131><<<1024, 512, 0, stream>>>(xT, nrm, idx);
  k_emax<128><<<1024, 256, 0, stream>>>(Ab, Bb, idx, f1);
  // layer 2
  k_gab<128,256,512><<<512, 512, 0, stream>>>(f1, 128, waD1, wbD1, Ab, Bb, xT);
  k_norm2<128><<<128, 64, 0, stream>>>(xT, nrm);
  k_knn3<128><<<1024, 512, 0, stream>>>(xT, nrm, idx);
  k_emax<256><<<2048, 256, 0, stream>>>(Ab, Bb, idx, f2);
  // layer 3
  k_gab<256,512,512><<<512, 512, 0, stream>>>(f2, 256, waD2, wbD2, Ab, Bb, xT);
  k_norm2<256><<<128, 64, 0, stream>>>(xT, nrm);
  k_knn3<256><<<1024, 512, 0, stream>>>(xT, nrm, idx);
  k_emax<512><<<4096, 256, 0, stream>>>(Ab, Bb, idx, f3);

  // local conv + global pool + head
  k_dgl<<<dim3(BB, 16), 128, 0, stream>>>(f1, f2, f3, dg_local_w, g128v);
  k_final<<<BB, 256, 0, stream>>>(g128v, dg_g_w0, dg_g_w1, cls_w, cls_b, out);
}

// Round 9
// 1699.328 us; speedup vs baseline: 1.0655x; 1.0304x over previous
//
#include <hip/hip_runtime.h>
#include <math.h>

#define BB 32
#define NN 4096
#define NPp 256
#define NSs 64
#define KC 20

__device__ __forceinline__ float fma4(const float4 w, const float4 v, float a){
  a = fmaf(w.x, v.x, a); a = fmaf(w.y, v.y, a);
  a = fmaf(w.z, v.z, a); a = fmaf(w.w, v.w, a); return a;
}
__device__ __forceinline__ float4 fma4s(const float4 w, float s, float4 a){
  a.x = fmaf(w.x, s, a.x); a.y = fmaf(w.y, s, a.y);
  a.z = fmaf(w.z, s, a.z); a.w = fmaf(w.w, s, a.w); return a;
}
__device__ __forceinline__ float4 max4(float4 a, float4 b){
  a.x = fmaxf(a.x, b.x); a.y = fmaxf(a.y, b.y);
  a.z = fmaxf(a.z, b.z); a.w = fmaxf(a.w, b.w); return a;
}
__device__ __forceinline__ float4 add4(float4 a, float4 b){
  a.x += b.x; a.y += b.y; a.z += b.z; a.w += b.w; return a;
}

template<int C>
__device__ __forceinline__ int dpp_i(int x){
  return __builtin_amdgcn_update_dpp(x, x, C, 0xf, 0xf, false);
}

// ---------------- unified weight prep (all transposes/splits in one kernel) ----------------
__global__ void k_wprep(const float* __restrict__ t0, const float* __restrict__ t1,
                        const float* __restrict__ d0, const float* __restrict__ d1,
                        const float* __restrict__ d2,
                        float* __restrict__ waT0, float* __restrict__ wbT0,
                        float* __restrict__ wt_t1,
                        float* __restrict__ waD0, float* __restrict__ wbD0,
                        float* __restrict__ waD1, float* __restrict__ wbD1,
                        float* __restrict__ waD2, float* __restrict__ wbD2){
  int i = blockIdx.x*256 + threadIdx.x;
  if (i < 8384){                       // t_ec_w0: [64][262] -> A/B [131][64]
    int m = i >> 6;
    int c = i & 63;
    float bb = t0[(size_t)c*262 + m];
    float dd = t0[(size_t)c*262 + 131 + m];
    waT0[i] = __fsub_rn(bb, dd); wbT0[i] = dd;
    return;
  }
  i -= 8384;
  if (i < 8192){                       // t_ec_w1: [128][64] -> [64][128]
    int m = i >> 7, c = i & 127;
    wt_t1[i] = t1[(size_t)c*64 + m];
    return;
  }
  i -= 8192;
  if (i < 16768){                      // dg_ec_w0: [128][262] -> A/B [131][128]
    int m = i >> 7, c = i & 127;
    float bb = d0[(size_t)c*262 + m];
    float dd = d0[(size_t)c*262 + 131 + m];
    waD0[i] = __fsub_rn(bb, dd); wbD0[i] = dd;
    return;
  }
  i -= 16768;
  if (i < 32768){                      // dg_ec_w1: [256][256] -> A/B [128][256]
    int m = i >> 8, c = i & 255;
    float bb = d1[(size_t)c*256 + m];
    float dd = d1[(size_t)c*256 + 128 + m];
    waD1[i] = __fsub_rn(bb, dd); wbD1[i] = dd;
    return;
  }
  i -= 32768;
  if (i < 131072){                     // dg_ec_w2: [512][512] -> A/B [256][512]
    int m = i >> 9, c = i & 511;
    float bb = d2[(size_t)c*512 + m];
    float dd = d2[(size_t)c*512 + 256 + m];
    waD2[i] = __fsub_rn(bb, dd); wbD2[i] = dd;
  }
}

// ---------------- transpose + point norms ----------------
__global__ void k_prep(const float* __restrict__ pts, float* __restrict__ xyz, float* __restrict__ xnrm){
  int i = blockIdx.x*256 + threadIdx.x;
  if (i >= BB*NN) return;
  int b = i >> 12, n = i & (NN-1);
  float X = pts[(b*3+0)*NN + n];
  float Y = pts[(b*3+1)*NN + n];
  float Z = pts[(b*3+2)*NN + n];
  xyz[i*3+0]=X; xyz[i*3+1]=Y; xyz[i*3+2]=Z;
  xnrm[i] = __fadd_rn(__fadd_rn(__fmul_rn(X,X), __fmul_rn(Y,Y)), __fmul_rn(Z,Z));
}

// ---------------- farthest point sampling: registers + DPP reduce, 1 barrier/iter ----------------
__global__ __launch_bounds__(256) void k_fps(const float* __restrict__ xyz, float* __restrict__ new_xyz){
  __shared__ float part[2][4][8];
  int b = blockIdx.x, t = threadIdx.x;
  int w = t >> 6;
  float px[16], py[16], pz[16], dist[16];
#pragma unroll
  for (int q = 0; q < 16; ++q){
    const float* p = xyz + ((size_t)b*NN + q*256 + t)*3;
    px[q] = p[0]; py[q] = p[1]; pz[q] = p[2];
    dist[q] = __builtin_inff();
  }
  const float* p0 = xyz + (size_t)b*NN*3;
  float Px = p0[0], Py = p0[1], Pz = p0[2];
  for (int it = 0; it < NPp; ++it){
    if (t == 0){
      float* o = new_xyz + ((size_t)b*NPp + it)*3;
      o[0] = Px; o[1] = Py; o[2] = Pz;
    }
    float bv = -1.0f, bx = 0.f, by = 0.f, bz = 0.f; int bj = 0;
#pragma unroll
    for (int q = 0; q < 16; ++q){
      float dx = __fsub_rn(px[q], Px);
      float dy = __fsub_rn(py[q], Py);
      float dz = __fsub_rn(pz[q], Pz);
      float dd = __fadd_rn(__fadd_rn(__fmul_rn(dx,dx), __fmul_rn(dy,dy)), __fmul_rn(dz,dz));
      float dm = fminf(dist[q], dd);
      dist[q] = dm;
      if (dm > bv){ bv = dm; bj = q*256 + t; bx = px[q]; by = py[q]; bz = pz[q]; }
    }
#define FPS_STAGE(C) { \
    float ov = __int_as_float(dpp_i<C>(__float_as_int(bv))); \
    int   oj = dpp_i<C>(bj); \
    float ox = __int_as_float(dpp_i<C>(__float_as_int(bx))); \
    float oy = __int_as_float(dpp_i<C>(__float_as_int(by))); \
    float oz = __int_as_float(dpp_i<C>(__float_as_int(bz))); \
    bool tk = (ov > bv) || (ov == bv && oj < bj); \
    bv = tk ? ov : bv; bj = tk ? oj : bj; \
    bx = tk ? ox : bx; by = tk ? oy : by; bz = tk ? oz : bz; }
    FPS_STAGE(0x111) FPS_STAGE(0x112) FPS_STAGE(0x114) FPS_STAGE(0x118)
    FPS_STAGE(0x142) FPS_STAGE(0x143)
#undef FPS_STAGE
    int par = it & 1;
    if ((t & 63) == 63){
      float* pp = part[par][w];
      pp[0] = bv; ((int*)pp)[1] = bj; pp[2] = bx; pp[3] = by; pp[4] = bz;
    }
    __syncthreads();
    const float* q0 = part[par][0];
    float fv = q0[0]; int fj = ((const int*)q0)[1];
    float fx = q0[2], fy = q0[3], fz = q0[4];
#pragma unroll
    for (int ww = 1; ww < 4; ++ww){
      const float* pp = part[par][ww];
      float ov = pp[0]; int oj = ((const int*)pp)[1];
      if (ov > fv || (ov == fv && oj < fj)){ fv = ov; fj = oj; fx = pp[2]; fy = pp[3]; fz = pp[4]; }
    }
    Px = fx; Py = fy; Pz = fz;
  }
}

// ---------------- ball query + SA convs + maxpool (fully-unrolled register arrays) ----------------
__global__ __launch_bounds__(64, 1) void k_sa(const float* __restrict__ xyz, const float* __restrict__ xnrm,
    const float* __restrict__ new_xyz, const float* __restrict__ w0, const float* __restrict__ w1,
    const float* __restrict__ w2, float* __restrict__ feat, float* __restrict__ x131){
  __shared__ int gix[64];
  int bi = blockIdx.x, lane = threadIdx.x;
  int b = bi >> 8;
  const float* q = new_xyz + (size_t)bi*3;
  float qx=q[0], qy=q[1], qz=q[2];
  float nq = __fadd_rn(__fadd_rn(__fmul_rn(qx,qx), __fmul_rn(qy,qy)), __fmul_rn(qz,qz));
  int cnt = 0;
  for (int base = 0; base < NN && cnt < NSs; base += 256){
#pragma unroll
    for (int u = 0; u < 4; ++u){
      int j = base + u*64 + lane;
      const float* p = xyz + ((size_t)b*NN + j)*3;
      float dot = __fadd_rn(__fadd_rn(__fmul_rn(qx,p[0]), __fmul_rn(qy,p[1])), __fmul_rn(qz,p[2]));
      float d2 = __fsub_rn(__fadd_rn(nq, xnrm[b*NN + j]), __fmul_rn(2.0f, dot));
      bool inb = d2 < 0.04f;
      unsigned long long m = __ballot(inb);
      int pos = cnt + (int)__popcll(m & ((1ull << lane) - 1ull));
      if (inb && pos < NSs) gix[pos] = j;
      cnt += (int)__popcll(m);
    }
  }
  __syncthreads();
  int g0 = gix[0];
  if (lane >= cnt) gix[lane] = g0;
  __syncthreads();
  // lane = sample; ALL loops touching h0h/h1 are fully unrolled so the arrays stay in VGPRs
  float h1[64];
  {
    int gj = gix[lane];
    const float* p = xyz + ((size_t)b*NN + gj)*3;
    float px = p[0]-qx, py = p[1]-qy, pz = p[2]-qz;
#pragma unroll
    for (int c = 0; c < 64; ++c) h1[c] = 0.0f;
#pragma unroll
    for (int half = 0; half < 2; ++half){
      float h0h[32];
#pragma unroll
      for (int mm = 0; mm < 32; ++mm){
        int c = half*32 + mm;
        float a = fmaf(w0[c*3+2], pz, fmaf(w0[c*3+1], py, w0[c*3]*px));
        h0h[mm] = fmaxf(a, 0.0f);
      }
#pragma unroll
      for (int c = 0; c < 64; ++c){
        const float4* wr = (const float4*)(w1 + c*64 + half*32);
        float a = h1[c];
#pragma unroll
        for (int qq = 0; qq < 8; ++qq){
          float4 w = wr[qq];
          a = fmaf(w.x, h0h[4*qq+0], a);
          a = fmaf(w.y, h0h[4*qq+1], a);
          a = fmaf(w.z, h0h[4*qq+2], a);
          a = fmaf(w.w, h0h[4*qq+3], a);
        }
        h1[c] = a;
      }
    }
#pragma unroll
    for (int c = 0; c < 64; ++c) h1[c] = fmaxf(h1[c], 0.0f);
  }
  // third conv: per-lane dot for each out channel, wave max-reduce via DPP, keep own channel
  float m0 = 0.0f, m1 = 0.0f;
#pragma unroll 2
  for (int c = 0; c < 128; ++c){
    const float4* wr = (const float4*)(w2 + (size_t)c*64);
    float a = 0.0f;
#pragma unroll
    for (int qq = 0; qq < 16; ++qq){
      float4 w = wr[qq];
      a = fmaf(w.x, h1[4*qq+0], a);
      a = fmaf(w.y, h1[4*qq+1], a);
      a = fmaf(w.z, h1[4*qq+2], a);
      a = fmaf(w.w, h1[4*qq+3], a);
    }
    a = fmaxf(a, 0.0f);
#define SA_MAX(C) { float o = __int_as_float(dpp_i<C>(__float_as_int(a))); a = fmaxf(a, o); }
    SA_MAX(0x111) SA_MAX(0x112) SA_MAX(0x114) SA_MAX(0x118) SA_MAX(0x142) SA_MAX(0x143)
#undef SA_MAX
    float r = __int_as_float(__builtin_amdgcn_readlane(__float_as_int(a), 63));
    if (c < 64){ if (lane == c) m0 = r; }
    else       { if (lane == c - 64) m1 = r; }
  }
  feat[(size_t)bi*128 + lane]      = m0;
  feat[(size_t)bi*128 + 64 + lane] = m1;
  x131[(size_t)bi*132 + lane]      = m0;
  x131[(size_t)bi*132 + 64 + lane] = m1;
  if (lane < 3) x131[(size_t)bi*132 + 128 + lane] = (lane==0)?qx:((lane==1)?qy:qz);
}

// ---------------- feature norms (from xT, coalesced) ----------------
template<int CIN>
__global__ void k_norm2(const float* __restrict__ xT, float* __restrict__ nrm){
  int p = blockIdx.x*64 + threadIdx.x;
  if (p >= BB*NPp) return;
  int b = p >> 8, col = p & 255;
  const float* base = xT + (size_t)b*CIN*256 + col;
  float a = 0.0f;
  for (int m = 0; m < CIN; ++m){
    float v = base[m*256];
    a = __fadd_rn(a, __fmul_rn(v, v));
  }
  nrm[p] = a;
}

// ---------------- kNN, 8 centroids/block, LDS-staged xT chunks ----------------
template<int CIN>
__global__ __launch_bounds__(512) void k_knn3(const float* __restrict__ xT,
    const float* __restrict__ nrm, int* __restrict__ idxo){
  __shared__ __align__(16) float sch[16*256];
  __shared__ __align__(16) float ds[8*256];
  int bi = blockIdx.x, t = threadIdx.x;
  int w = t >> 6, lane = t & 63;
  int b = bi >> 5;
  int coli = (bi & 31)*8 + w;
  const float* xb = xT + (size_t)b*CIN*256;
  float d0=0.f, d1=0.f, d2=0.f, d3=0.f;
  for (int m0 = 0; m0 < CIN; m0 += 16){
    int mc = (CIN - m0 < 16) ? (CIN - m0) : 16;
    for (int i = t; i < mc*64; i += 512){
      int mm = i >> 6, c4 = i & 63;
      *(float4*)(sch + mm*256 + c4*4) = *(const float4*)(xb + (size_t)(m0+mm)*256 + c4*4);
    }
    __syncthreads();
    for (int mm = 0; mm < mc; ++mm){
      float xm = sch[mm*256 + coli];
      float4 v = *(const float4*)(sch + mm*256 + 4*lane);
      d0 = fmaf(v.x, xm, d0); d1 = fmaf(v.y, xm, d1);
      d2 = fmaf(v.z, xm, d2); d3 = fmaf(v.w, xm, d3);
    }
    __syncthreads();
  }
  float ni = nrm[b*256 + coli];
  {
    int j0 = 4*lane;
    float4 dv;
    dv.x = __fsub_rn(__fadd_rn(ni, nrm[b*256 + j0+0]), __fmul_rn(2.0f, d0));
    dv.y = __fsub_rn(__fadd_rn(ni, nrm[b*256 + j0+1]), __fmul_rn(2.0f, d1));
    dv.z = __fsub_rn(__fadd_rn(ni, nrm[b*256 + j0+2]), __fmul_rn(2.0f, d2));
    dv.w = __fsub_rn(__fadd_rn(ni, nrm[b*256 + j0+3]), __fmul_rn(2.0f, d3));
    *(float4*)(ds + w*256 + j0) = dv;
  }
  __syncthreads();
  for (int r = 0; r < KC; ++r){
    float bv = 3.4e38f; int bj = NPp;
    float4 dv = *(const float4*)(ds + w*256 + 4*lane);
#pragma unroll
    for (int q = 0; q < 4; ++q){
      float v = (q==0)?dv.x:((q==1)?dv.y:((q==2)?dv.z:dv.w));
      int j = 4*lane + q;
      if (v < bv){ bv = v; bj = j; }
    }
#pragma unroll
    for (int off = 32; off >= 1; off >>= 1){
      float ov = __shfl_xor(bv, off, 64);
      int   oj = __shfl_xor(bj, off, 64);
      if (ov < bv || (ov == bv && oj < bj)){ bv = ov; bj = oj; }
    }
    if (lane == 0){ idxo[((size_t)b*256 + coli)*KC + r] = bj; ds[w*256 + bj] = 3.0e38f; }
    __syncthreads();
  }
}

// ---------------- per-point dual GEMM + fused xT transpose ----------------
template<int CIN, int COUT, int T>
__global__ __launch_bounds__(T) void k_gab(const float* __restrict__ x, int xstride,
    const float* __restrict__ wA, const float* __restrict__ wB,
    float* __restrict__ A, float* __restrict__ B, float* __restrict__ xT){
  constexpr int PC  = CIN + 1;
  constexpr int G   = COUT/4;
  constexpr int RS  = T/G;
  constexpr int RPT = 16/RS;
  __shared__ float xsh[16*PC];
  int bi = blockIdx.x, t = threadIdx.x;
  int g = t % G, rs = t / G;
  int i0 = bi*16;
  for (int i = t; i < 16*CIN; i += T){
    int r = i / CIN, m = i - r*CIN;
    xsh[r*PC + m] = x[(size_t)(i0+r)*xstride + m];
  }
  __syncthreads();
  {
    int bb = i0 >> 8, col0 = i0 & 255;
    float* xTb = xT + (size_t)bb*CIN*256 + col0;
    for (int i = t; i < 16*CIN; i += T){
      int m = i >> 4, r = i & 15;
      xTb[m*256 + r] = xsh[r*PC + m];
    }
  }
  float4 accA[RPT], accB[RPT];
#pragma unroll
  for (int rr = 0; rr < RPT; ++rr){
    accA[rr] = make_float4(0.f,0.f,0.f,0.f);
    accB[rr] = make_float4(0.f,0.f,0.f,0.f);
  }
  for (int m = 0; m < CIN; ++m){
    float4 wa = *(const float4*)(wA + (size_t)m*COUT + 4*g);
    float4 wb = *(const float4*)(wB + (size_t)m*COUT + 4*g);
#pragma unroll
    for (int rr = 0; rr < RPT; ++rr){
      float xv = xsh[(rs + rr*RS)*PC + m];
      accA[rr] = fma4s(wa, xv, accA[rr]);
      accB[rr] = fma4s(wb, xv, accB[rr]);
    }
  }
#pragma unroll
  for (int rr = 0; rr < RPT; ++rr){
    int r = i0 + rs + rr*RS;
    *(float4*)(A + (size_t)r*COUT + 4*g) = accA[rr];
    *(float4*)(B + (size_t)r*COUT + 4*g) = accB[rr];
  }
}

// ---------------- edge epilogue: out[i][c] = max_k relu(A[i][c] + B[j_ik][c]) ----------------
template<int COUT>
__global__ __launch_bounds__(256) void k_emax(const float* __restrict__ A, const float* __restrict__ Bm,
    const int* __restrict__ idx, float* __restrict__ out){
  constexpr int GT = COUT/4;
  constexpr int NC = 256/GT;
  __shared__ int js[NC*KC];
  int bi = blockIdx.x, t = threadIdx.x;
  int li = t / GT, c4 = (t % GT)*4;
  int ci = bi*NC + li;
  int rb = (ci >> 8) << 8;
  if (t < NC*KC) js[t] = idx[(size_t)bi*NC*KC + t];
  __syncthreads();
  float4 a = *(const float4*)(A + (size_t)ci*COUT + c4);
  float4 p = make_float4(0.f,0.f,0.f,0.f);
#pragma unroll
  for (int k = 0; k < KC; ++k){
    int j = js[li*KC + k];
    float4 b = *(const float4*)(Bm + (size_t)(rb + j)*COUT + c4);
    p = max4(p, add4(a, b));
  }
  *(float4*)(out + (size_t)ci*COUT + c4) = p;
}

// ---------------- T-Net edge: h0 = relu(A0+B0) then 64->128 conv + k-maxpool ----------------
__global__ __launch_bounds__(128) void k_tedge3(const float* __restrict__ A0, const float* __restrict__ B0,
    const int* __restrict__ idx, const float* __restrict__ wt1, float* __restrict__ out){
  __shared__ __align__(16) float h0s[20*68];
  __shared__ __align__(16) float smax[4*128];
  __shared__ int js[KC];
  int bi = blockIdx.x, t = threadIdx.x;
  int cg = t & 31, kg = t >> 5, k0 = kg*5;
  int rb = (bi >> 8) << 8;
  if (t < KC) js[t] = idx[(size_t)bi*KC + t];
  __syncthreads();
  for (int i = t; i < 20*64; i += 128){
    int k = i >> 6, c = i & 63;
    float v = A0[(size_t)bi*64 + c] + B0[(size_t)(rb + js[k])*64 + c];
    h0s[k*68 + c] = fmaxf(v, 0.0f);
  }
  __syncthreads();
  float4 b2[5];
#pragma unroll
  for (int kk = 0; kk < 5; ++kk) b2[kk] = make_float4(0.f,0.f,0.f,0.f);
  for (int m4 = 0; m4 < 16; ++m4){
    float4 e[5];
#pragma unroll
    for (int kk = 0; kk < 5; ++kk) e[kk] = *(const float4*)(h0s + (k0+kk)*68 + 4*m4);
#pragma unroll
    for (int mm = 0; mm < 4; ++mm){
      float4 w = *(const float4*)(wt1 + (4*m4+mm)*128 + 4*cg);
#pragma unroll
      for (int kk = 0; kk < 5; ++kk){
        float ev = (mm==0)?e[kk].x:((mm==1)?e[kk].y:((mm==2)?e[kk].z:e[kk].w));
        b2[kk] = fma4s(w, ev, b2[kk]);
      }
    }
  }
  float4 p = make_float4(0.f,0.f,0.f,0.f);
#pragma unroll
  for (int kk = 0; kk < 5; ++kk) p = max4(p, b2[kk]);
  *(float4*)(smax + kg*128 + 4*cg) = p;
  __syncthreads();
  if (kg == 0){
    float4 r = *(const float4*)(smax + 4*cg);
#pragma unroll
    for (int g = 1; g < 4; ++g) r = max4(r, *(const float4*)(smax + g*128 + 4*cg));
    *(float4*)(out + (size_t)bi*128 + 4*cg) = r;
  }
}

// ---------------- T-Net 128->1024 + pool over points ----------------
__global__ __launch_bounds__(128) void k_tpool(const float* __restrict__ h, const float* __restrict__ W,
    float* __restrict__ g1024){
  int b = blockIdx.x, t = threadIdx.x;
  int c = blockIdx.y*128 + t;
  float4 w[32];
#pragma unroll
  for (int qq = 0; qq < 32; ++qq) w[qq] = *(const float4*)(W + (size_t)c*128 + 4*qq);
  const float* hb = h + (size_t)b*NPp*128;
  float mx = 0.0f;
  for (int i = 0; i < NPp; ++i){
    const float4* hr = (const float4*)(hb + (size_t)i*128);
    float a = 0.0f;
#pragma unroll
    for (int qq = 0; qq < 32; ++qq) a = fma4(w[qq], hr[qq], a);
    mx = fmaxf(mx, a);
  }
  g1024[(size_t)b*1024 + c] = mx;
}

// ---------------- T-Net MLP + 3x3 transform applied to new_xyz ----------------
__global__ __launch_bounds__(256) void k_trest(const float* __restrict__ g1024,
    const float* __restrict__ Wg0, const float* __restrict__ Wg1,
    const float* __restrict__ Wl, const float* __restrict__ bl,
    const float* __restrict__ new_xyz, float* __restrict__ x131){
  __shared__ __align__(16) float g1[1024];
  __shared__ __align__(16) float g5[512];
  __shared__ __align__(16) float g2[256];
  __shared__ float tm[12];
  int b = blockIdx.x, t = threadIdx.x;
  for (int m = t; m < 1024; m += 256) g1[m] = g1024[(size_t)b*1024 + m];
  __syncthreads();
#pragma unroll
  for (int cc = 0; cc < 2; ++cc){
    int c = t + cc*256;
    const float4* wr = (const float4*)(Wg0 + (size_t)c*1024);
    const float4* gv = (const float4*)g1;
    float a = 0.0f;
    for (int qq = 0; qq < 256; ++qq) a = fma4(wr[qq], gv[qq], a);
    g5[c] = fmaxf(a, 0.0f);
  }
  __syncthreads();
  {
    const float4* wr = (const float4*)(Wg1 + (size_t)t*512);
    const float4* gv = (const float4*)g5;
    float a = 0.0f;
    for (int qq = 0; qq < 128; ++qq) a = fma4(wr[qq], gv[qq], a);
    g2[t] = fmaxf(a, 0.0f);
  }
  __syncthreads();
  if (t < 9){
    const float4* wr = (const float4*)(Wl + (size_t)t*256);
    const float4* gv = (const float4*)g2;
    float a = 0.0f;
#pragma unroll
    for (int qq = 0; qq < 64; ++qq) a = fma4(wr[qq], gv[qq], a);
    a += bl[t];
    if (t == 0 || t == 4 || t == 8) a += 1.0f;
    tm[t] = a;
  }
  __syncthreads();
  {
    const float* nx = new_xyz + ((size_t)b*NPp + t)*3;
    float X = nx[0], Y = nx[1], Z = nx[2];
#pragma unroll
    for (int i = 0; i < 3; ++i){
      float v = __fadd_rn(__fadd_rn(__fmul_rn(tm[i*3+0], X), __fmul_rn(tm[i*3+1], Y)), __fmul_rn(tm[i*3+2], Z));
      x131[((size_t)b*NPp + t)*132 + 128 + i] = v;
    }
  }
}

// ---------------- 896->128 conv + global max pool (atomicMax; poison is negative int) ----------------
__global__ __launch_bounds__(128) void k_dgl(const float* __restrict__ f1, const float* __restrict__ f2,
    const float* __restrict__ f3, const float* __restrict__ W, float* __restrict__ g128){
  int b = blockIdx.x, t = threadIdx.x;
  int i0 = blockIdx.y * 16;
  const float* wr = W + (size_t)t*896;
  float acc[16];
#pragma unroll
  for (int ii = 0; ii < 16; ++ii) acc[ii] = 0.0f;
  for (int q = 0; q < 32; ++q){
    float4 w = *(const float4*)(wr + 4*q);
#pragma unroll
    for (int ii = 0; ii < 16; ++ii){
      float4 v = *(const float4*)(f1 + ((size_t)b*NPp + i0 + ii)*128 + 4*q);
      acc[ii] = fma4(w, v, acc[ii]);
    }
  }
  for (int q = 0; q < 64; ++q){
    float4 w = *(const float4*)(wr + 128 + 4*q);
#pragma unroll
    for (int ii = 0; ii < 16; ++ii){
      float4 v = *(const float4*)(f2 + ((size_t)b*NPp + i0 + ii)*256 + 4*q);
      acc[ii] = fma4(w, v, acc[ii]);
    }
  }
  for (int q = 0; q < 128; ++q){
    float4 w = *(const float4*)(wr + 384 + 4*q);
#pragma unroll
    for (int ii = 0; ii < 16; ++ii){
      float4 v = *(const float4*)(f3 + ((size_t)b*NPp + i0 + ii)*512 + 4*q);
      acc[ii] = fma4(w, v, acc[ii]);
    }
  }
#pragma unroll
  for (int ii = 0; ii < 16; ++ii){
    float v = fmaxf(acc[ii], 0.0f);
    atomicMax((int*)(g128 + (size_t)b*128 + t), __float_as_int(v));
  }
}

// ---------------- classifier head ----------------
__global__ __launch_bounds__(256) void k_final(const float* __restrict__ g128,
    const float* __restrict__ W0, const float* __restrict__ W1,
    const float* __restrict__ Wc, const float* __restrict__ bc, float* __restrict__ out){
  __shared__ __align__(16) float g0[128];
  __shared__ __align__(16) float g5[512];
  __shared__ __align__(16) float g2[256];
  int b = blockIdx.x, t = threadIdx.x;
  if (t < 128) g0[t] = g128[(size_t)b*128 + t];
  __syncthreads();
#pragma unroll
  for (int cc = 0; cc < 2; ++cc){
    int c = t + cc*256;
    const float4* wr = (const float4*)(W0 + (size_t)c*128);
    const float4* gv = (const float4*)g0;
    float a = 0.0f;
#pragma unroll
    for (int qq = 0; qq < 32; ++qq) a = fma4(wr[qq], gv[qq], a);
    g5[c] = fmaxf(a, 0.0f);
  }
  __syncthreads();
  {
    const float4* wr = (const float4*)(W1 + (size_t)t*512);
    const float4* gv = (const float4*)g5;
    float a = 0.0f;
    for (int qq = 0; qq < 128; ++qq) a = fma4(wr[qq], gv[qq], a);
    g2[t] = fmaxf(a, 0.0f);
  }
  __syncthreads();
  if (t < 40){
    const float4* wr = (const float4*)(Wc + (size_t)t*256);
    const float4* gv = (const float4*)g2;
    float a = 0.0f;
#pragma unroll
    for (int qq = 0; qq < 64; ++qq) a = fma4(wr[qq], gv[qq], a);
    out[(size_t)b*40 + t] = a + bc[t];
  }
}

extern "C" void kernel_launch(void* const* d_in, const int* in_sizes, int n_in,
                              void* d_out, int out_size, void* d_ws, size_t ws_size,
                              hipStream_t stream){
  (void)in_sizes; (void)n_in; (void)out_size; (void)ws_size;
  const float* points     = (const float*)d_in[0];
  const float* sa_w0      = (const float*)d_in[1];
  const float* sa_w1      = (const float*)d_in[2];
  const float* sa_w2      = (const float*)d_in[3];
  const float* t_ec_w0    = (const float*)d_in[4];
  const float* t_ec_w1    = (const float*)d_in[5];
  const float* t_local_w  = (const float*)d_in[6];
  const float* t_g_w0     = (const float*)d_in[7];
  const float* t_g_w1     = (const float*)d_in[8];
  const float* t_lin_w    = (const float*)d_in[9];
  const float* t_lin_b    = (const float*)d_in[10];
  const float* dg_ec_w0   = (const float*)d_in[11];
  const float* dg_ec_w1   = (const float*)d_in[12];
  const float* dg_ec_w2   = (const float*)d_in[13];
  const float* dg_local_w = (const float*)d_in[14];
  const float* dg_g_w0    = (const float*)d_in[15];
  const float* dg_g_w1    = (const float*)d_in[16];
  const float* cls_w      = (const float*)d_in[17];
  const float* cls_b      = (const float*)d_in[18];
  float* out = (float*)d_out;

  float* ws     = (float*)d_ws;
  float* xyz    = ws;                    // 393216
  float* xnrm   = xyz    + 393216;       // 131072
  float* nxyz   = xnrm   + 131072;       // 24576
  float* feat   = nxyz   + 24576;        // 1048576
  float* x131   = feat   + 1048576;      // 1081344
  float* nrm    = x131   + 1081344;      // 8192
  int*   idx    = (int*)(nrm + 8192);    // 163840
  float* ht     = (float*)(idx + 163840);// 1048576 (reused as f1)
  float* g1024v = ht     + 1048576;      // 32768
  float* f2     = g1024v + 32768;        // 2097152
  float* f3     = f2     + 2097152;      // 4194304
  float* g128v  = f3     + 4194304;      // 4096
  float* wt_t1  = g128v  + 4096;         // 8192   (64x128)
  float* waT0   = wt_t1  + 8192;         // 8384   (131x64)
  float* wbT0   = waT0   + 8384;         // 8384
  float* waD0   = wbT0   + 8384;         // 16768  (131x128)
  float* wbD0   = waD0   + 16768;        // 16768
  float* waD1   = wbD0   + 16768;        // 32768  (128x256)
  float* wbD1   = waD1   + 32768;        // 32768
  float* waD2   = wbD1   + 32768;        // 131072 (256x512)
  float* wbD2   = waD2   + 131072;       // 131072
  float* Ab     = wbD2   + 131072;       // 4194304
  float* Bb     = Ab     + 4194304;      // 4194304
  float* f1 = ht;
  float* xT = f3;                        // alias: xT lives in f3 until k_emax<512> writes f3

  k_prep<<<512, 256, 0, stream>>>(points, xyz, xnrm);
  k_wprep<<<771, 256, 0, stream>>>(t_ec_w0, t_ec_w1, dg_ec_w0, dg_ec_w1, dg_ec_w2,
                                   waT0, wbT0, wt_t1, waD0, wbD0, waD1, wbD1, waD2, wbD2);
  k_fps<<<BB, 256, 0, stream>>>(xyz, nxyz);
  k_sa<<<BB*NPp, 64, 0, stream>>>(xyz, xnrm, nxyz, sa_w0, sa_w1, sa_w2, feat, x131);

  // T-Net branch (x = [feat, new_xyz])
  k_gab<131,64,256><<<512, 256, 0, stream>>>(x131, 132, waT0, wbT0, Ab, Bb, xT);
  k_norm2<131><<<128, 64, 0, stream>>>(xT, nrm);
  k_knn3<131><<<1024, 512, 0, stream>>>(xT, nrm, idx);
  k_tedge3<<<BB*NPp, 128, 0, stream>>>(Ab, Bb, idx, wt_t1, ht);
  k_tpool<<<dim3(BB, 8), 128, 0, stream>>>(ht, t_local_w, g1024v);
  k_trest<<<BB, 256, 0, stream>>>(g1024v, t_g_w0, t_g_w1, t_lin_w, t_lin_b, nxyz, x131);

  // DGCNN layer 1 (x = [feat, xyz_t], 131 dims)
  k_gab<131,128,512><<<512, 512, 0, stream>>>(x131, 132, waD0, wbD0, Ab, Bb, xT);
  k_norm2<131><<<128, 64, 0, stream>>>(xT, nrm);
  k_knn3<131><<<1024, 512, 0, stream>>>(xT, nrm, idx);
  k_emax<128><<<1024, 256, 0, stream>>>(Ab, Bb, idx, f1);
  // layer 2
  k_gab<128,256,512><<<512, 512, 0, stream>>>(f1, 128, waD1, wbD1, Ab, Bb, xT);
  k_norm2<128><<<128, 64, 0, stream>>>(xT, nrm);
  k_knn3<128><<<1024, 512, 0, stream>>>(xT, nrm, idx);
  k_emax<256><<<2048, 256, 0, stream>>>(Ab, Bb, idx, f2);
  // layer 3
  k_gab<256,512,512><<<512, 512, 0, stream>>>(f2, 256, waD2, wbD2, Ab, Bb, xT);
  k_norm2<256><<<128, 64, 0, stream>>>(xT, nrm);
  k_knn3<256><<<1024, 512, 0, stream>>>(xT, nrm, idx);
  k_emax<512><<<4096, 256, 0, stream>>>(Ab, Bb, idx, f3);

  // local conv + global pool + head
  k_dgl<<<dim3(BB, 16), 128, 0, stream>>>(f1, f2, f3, dg_local_w, g128v);
  k_final<<<BB, 256, 0, stream>>>(g128v, dg_g_w0, dg_g_w1, cls_w, cls_b, out);
}

// Round 10
// 1595.455 us; speedup vs baseline: 1.1349x; 1.0651x over previous
//
#include <hip/hip_runtime.h>
#include <math.h>

#define BB 32
#define NN 4096
#define NPp 256
#define NSs 64
#define KC 20

__device__ __forceinline__ float fma4(const float4 w, const float4 v, float a){
  a = fmaf(w.x, v.x, a); a = fmaf(w.y, v.y, a);
  a = fmaf(w.z, v.z, a); a = fmaf(w.w, v.w, a); return a;
}
__device__ __forceinline__ float4 fma4s(const float4 w, float s, float4 a){
  a.x = fmaf(w.x, s, a.x); a.y = fmaf(w.y, s, a.y);
  a.z = fmaf(w.z, s, a.z); a.w = fmaf(w.w, s, a.w); return a;
}
__device__ __forceinline__ float4 max4(float4 a, float4 b){
  a.x = fmaxf(a.x, b.x); a.y = fmaxf(a.y, b.y);
  a.z = fmaxf(a.z, b.z); a.w = fmaxf(a.w, b.w); return a;
}
__device__ __forceinline__ float4 add4(float4 a, float4 b){
  a.x += b.x; a.y += b.y; a.z += b.z; a.w += b.w; return a;
}

template<int C>
__device__ __forceinline__ int dpp_i(int x){
  return __builtin_amdgcn_update_dpp(x, x, C, 0xf, 0xf, false);
}

// ---------------- unified weight prep (all transposes/splits in one kernel) ----------------
__global__ void k_wprep(const float* __restrict__ t0, const float* __restrict__ t1,
                        const float* __restrict__ d0, const float* __restrict__ d1,
                        const float* __restrict__ d2,
                        float* __restrict__ waT0, float* __restrict__ wbT0,
                        float* __restrict__ wt_t1,
                        float* __restrict__ waD0, float* __restrict__ wbD0,
                        float* __restrict__ waD1, float* __restrict__ wbD1,
                        float* __restrict__ waD2, float* __restrict__ wbD2){
  int i = blockIdx.x*256 + threadIdx.x;
  if (i < 8384){                       // t_ec_w0: [64][262] -> A/B [131][64]
    int m = i >> 6;
    int c = i & 63;
    float bb = t0[(size_t)c*262 + m];
    float dd = t0[(size_t)c*262 + 131 + m];
    waT0[i] = __fsub_rn(bb, dd); wbT0[i] = dd;
    return;
  }
  i -= 8384;
  if (i < 8192){                       // t_ec_w1: [128][64] -> [64][128]
    int m = i >> 7, c = i & 127;
    wt_t1[i] = t1[(size_t)c*64 + m];
    return;
  }
  i -= 8192;
  if (i < 16768){                      // dg_ec_w0: [128][262] -> A/B [131][128]
    int m = i >> 7, c = i & 127;
    float bb = d0[(size_t)c*262 + m];
    float dd = d0[(size_t)c*262 + 131 + m];
    waD0[i] = __fsub_rn(bb, dd); wbD0[i] = dd;
    return;
  }
  i -= 16768;
  if (i < 32768){                      // dg_ec_w1: [256][256] -> A/B [128][256]
    int m = i >> 8, c = i & 255;
    float bb = d1[(size_t)c*256 + m];
    float dd = d1[(size_t)c*256 + 128 + m];
    waD1[i] = __fsub_rn(bb, dd); wbD1[i] = dd;
    return;
  }
  i -= 32768;
  if (i < 131072){                     // dg_ec_w2: [512][512] -> A/B [256][512]
    int m = i >> 9, c = i & 511;
    float bb = d2[(size_t)c*512 + m];
    float dd = d2[(size_t)c*512 + 256 + m];
    waD2[i] = __fsub_rn(bb, dd); wbD2[i] = dd;
  }
}

// ---------------- transpose + point norms ----------------
__global__ void k_prep(const float* __restrict__ pts, float* __restrict__ xyz, float* __restrict__ xnrm){
  int i = blockIdx.x*256 + threadIdx.x;
  if (i >= BB*NN) return;
  int b = i >> 12, n = i & (NN-1);
  float X = pts[(b*3+0)*NN + n];
  float Y = pts[(b*3+1)*NN + n];
  float Z = pts[(b*3+2)*NN + n];
  xyz[i*3+0]=X; xyz[i*3+1]=Y; xyz[i*3+2]=Z;
  xnrm[i] = __fadd_rn(__fadd_rn(__fmul_rn(X,X), __fmul_rn(Y,Y)), __fmul_rn(Z,Z));
}

// ---------------- farthest point sampling: registers + DPP reduce, 1 barrier/iter ----------------
__global__ __launch_bounds__(256) void k_fps(const float* __restrict__ xyz, float* __restrict__ new_xyz){
  __shared__ float part[2][4][8];
  int b = blockIdx.x, t = threadIdx.x;
  int w = t >> 6;
  float px[16], py[16], pz[16], dist[16];
#pragma unroll
  for (int q = 0; q < 16; ++q){
    const float* p = xyz + ((size_t)b*NN + q*256 + t)*3;
    px[q] = p[0]; py[q] = p[1]; pz[q] = p[2];
    dist[q] = __builtin_inff();
  }
  const float* p0 = xyz + (size_t)b*NN*3;
  float Px = p0[0], Py = p0[1], Pz = p0[2];
  for (int it = 0; it < NPp; ++it){
    if (t == 0){
      float* o = new_xyz + ((size_t)b*NPp + it)*3;
      o[0] = Px; o[1] = Py; o[2] = Pz;
    }
    float bv = -1.0f, bx = 0.f, by = 0.f, bz = 0.f; int bj = 0;
#pragma unroll
    for (int q = 0; q < 16; ++q){
      float dx = __fsub_rn(px[q], Px);
      float dy = __fsub_rn(py[q], Py);
      float dz = __fsub_rn(pz[q], Pz);
      float dd = __fadd_rn(__fadd_rn(__fmul_rn(dx,dx), __fmul_rn(dy,dy)), __fmul_rn(dz,dz));
      float dm = fminf(dist[q], dd);
      dist[q] = dm;
      if (dm > bv){ bv = dm; bj = q*256 + t; bx = px[q]; by = py[q]; bz = pz[q]; }
    }
#define FPS_STAGE(C) { \
    float ov = __int_as_float(dpp_i<C>(__float_as_int(bv))); \
    int   oj = dpp_i<C>(bj); \
    float ox = __int_as_float(dpp_i<C>(__float_as_int(bx))); \
    float oy = __int_as_float(dpp_i<C>(__float_as_int(by))); \
    float oz = __int_as_float(dpp_i<C>(__float_as_int(bz))); \
    bool tk = (ov > bv) || (ov == bv && oj < bj); \
    bv = tk ? ov : bv; bj = tk ? oj : bj; \
    bx = tk ? ox : bx; by = tk ? oy : by; bz = tk ? oz : bz; }
    FPS_STAGE(0x111) FPS_STAGE(0x112) FPS_STAGE(0x114) FPS_STAGE(0x118)
    FPS_STAGE(0x142) FPS_STAGE(0x143)
#undef FPS_STAGE
    int par = it & 1;
    if ((t & 63) == 63){
      float* pp = part[par][w];
      pp[0] = bv; ((int*)pp)[1] = bj; pp[2] = bx; pp[3] = by; pp[4] = bz;
    }
    __syncthreads();
    const float* q0 = part[par][0];
    float fv = q0[0]; int fj = ((const int*)q0)[1];
    float fx = q0[2], fy = q0[3], fz = q0[4];
#pragma unroll
    for (int ww = 1; ww < 4; ++ww){
      const float* pp = part[par][ww];
      float ov = pp[0]; int oj = ((const int*)pp)[1];
      if (ov > fv || (ov == fv && oj < fj)){ fv = ov; fj = oj; fx = pp[2]; fy = pp[3]; fz = pp[4]; }
    }
    Px = fx; Py = fy; Pz = fz;
  }
}

// ---------------- ball query + SA convs + maxpool (fully-unrolled register arrays) ----------------
__global__ __launch_bounds__(64, 1) void k_sa(const float* __restrict__ xyz, const float* __restrict__ xnrm,
    const float* __restrict__ new_xyz, const float* __restrict__ w0, const float* __restrict__ w1,
    const float* __restrict__ w2, float* __restrict__ feat, float* __restrict__ x131){
  __shared__ int gix[64];
  int bi = blockIdx.x, lane = threadIdx.x;
  int b = bi >> 8;
  const float* q = new_xyz + (size_t)bi*3;
  float qx=q[0], qy=q[1], qz=q[2];
  float nq = __fadd_rn(__fadd_rn(__fmul_rn(qx,qx), __fmul_rn(qy,qy)), __fmul_rn(qz,qz));
  int cnt = 0;
  for (int base = 0; base < NN && cnt < NSs; base += 256){
#pragma unroll
    for (int u = 0; u < 4; ++u){
      int j = base + u*64 + lane;
      const float* p = xyz + ((size_t)b*NN + j)*3;
      float dot = __fadd_rn(__fadd_rn(__fmul_rn(qx,p[0]), __fmul_rn(qy,p[1])), __fmul_rn(qz,p[2]));
      float d2 = __fsub_rn(__fadd_rn(nq, xnrm[b*NN + j]), __fmul_rn(2.0f, dot));
      bool inb = d2 < 0.04f;
      unsigned long long m = __ballot(inb);
      int pos = cnt + (int)__popcll(m & ((1ull << lane) - 1ull));
      if (inb && pos < NSs) gix[pos] = j;
      cnt += (int)__popcll(m);
    }
  }
  __syncthreads();
  int g0 = gix[0];
  if (lane >= cnt) gix[lane] = g0;
  __syncthreads();
  // lane = sample; ALL loops touching h0h/h1 are fully unrolled so the arrays stay in VGPRs
  float h1[64];
  {
    int gj = gix[lane];
    const float* p = xyz + ((size_t)b*NN + gj)*3;
    float px = p[0]-qx, py = p[1]-qy, pz = p[2]-qz;
#pragma unroll
    for (int c = 0; c < 64; ++c) h1[c] = 0.0f;
#pragma unroll
    for (int half = 0; half < 2; ++half){
      float h0h[32];
#pragma unroll
      for (int mm = 0; mm < 32; ++mm){
        int c = half*32 + mm;
        float a = fmaf(w0[c*3+2], pz, fmaf(w0[c*3+1], py, w0[c*3]*px));
        h0h[mm] = fmaxf(a, 0.0f);
      }
#pragma unroll
      for (int c = 0; c < 64; ++c){
        const float4* wr = (const float4*)(w1 + c*64 + half*32);
        float a = h1[c];
#pragma unroll
        for (int qq = 0; qq < 8; ++qq){
          float4 w = wr[qq];
          a = fmaf(w.x, h0h[4*qq+0], a);
          a = fmaf(w.y, h0h[4*qq+1], a);
          a = fmaf(w.z, h0h[4*qq+2], a);
          a = fmaf(w.w, h0h[4*qq+3], a);
        }
        h1[c] = a;
      }
    }
#pragma unroll
    for (int c = 0; c < 64; ++c) h1[c] = fmaxf(h1[c], 0.0f);
  }
  // third conv: per-lane dot for each out channel, wave max-reduce via DPP, keep own channel
  float m0 = 0.0f, m1 = 0.0f;
#pragma unroll 2
  for (int c = 0; c < 128; ++c){
    const float4* wr = (const float4*)(w2 + (size_t)c*64);
    float a = 0.0f;
#pragma unroll
    for (int qq = 0; qq < 16; ++qq){
      float4 w = wr[qq];
      a = fmaf(w.x, h1[4*qq+0], a);
      a = fmaf(w.y, h1[4*qq+1], a);
      a = fmaf(w.z, h1[4*qq+2], a);
      a = fmaf(w.w, h1[4*qq+3], a);
    }
    a = fmaxf(a, 0.0f);
#define SA_MAX(C) { float o = __int_as_float(dpp_i<C>(__float_as_int(a))); a = fmaxf(a, o); }
    SA_MAX(0x111) SA_MAX(0x112) SA_MAX(0x114) SA_MAX(0x118) SA_MAX(0x142) SA_MAX(0x143)
#undef SA_MAX
    float r = __int_as_float(__builtin_amdgcn_readlane(__float_as_int(a), 63));
    if (c < 64){ if (lane == c) m0 = r; }
    else       { if (lane == c - 64) m1 = r; }
  }
  feat[(size_t)bi*128 + lane]      = m0;
  feat[(size_t)bi*128 + 64 + lane] = m1;
  x131[(size_t)bi*132 + lane]      = m0;
  x131[(size_t)bi*132 + 64 + lane] = m1;
  if (lane < 3) x131[(size_t)bi*132 + 128 + lane] = (lane==0)?qx:((lane==1)?qy:qz);
}

// ---------------- feature norms (from xT, coalesced) ----------------
template<int CIN>
__global__ void k_norm2(const float* __restrict__ xT, float* __restrict__ nrm){
  int p = blockIdx.x*64 + threadIdx.x;
  if (p >= BB*NPp) return;
  int b = p >> 8, col = p & 255;
  const float* base = xT + (size_t)b*CIN*256 + col;
  float a = 0.0f;
  for (int m = 0; m < CIN; ++m){
    float v = base[m*256];
    a = __fadd_rn(a, __fmul_rn(v, v));
  }
  nrm[p] = a;
}

// ---------------- kNN, 8 centroids/block, LDS-staged xT chunks ----------------
template<int CIN>
__global__ __launch_bounds__(512) void k_knn3(const float* __restrict__ xT,
    const float* __restrict__ nrm, int* __restrict__ idxo){
  __shared__ __align__(16) float sch[16*256];
  __shared__ __align__(16) float ds[8*256];
  int bi = blockIdx.x, t = threadIdx.x;
  int w = t >> 6, lane = t & 63;
  int b = bi >> 5;
  int coli = (bi & 31)*8 + w;
  const float* xb = xT + (size_t)b*CIN*256;
  float d0=0.f, d1=0.f, d2=0.f, d3=0.f;
  for (int m0 = 0; m0 < CIN; m0 += 16){
    int mc = (CIN - m0 < 16) ? (CIN - m0) : 16;
    for (int i = t; i < mc*64; i += 512){
      int mm = i >> 6, c4 = i & 63;
      *(float4*)(sch + mm*256 + c4*4) = *(const float4*)(xb + (size_t)(m0+mm)*256 + c4*4);
    }
    __syncthreads();
    for (int mm = 0; mm < mc; ++mm){
      float xm = sch[mm*256 + coli];
      float4 v = *(const float4*)(sch + mm*256 + 4*lane);
      d0 = fmaf(v.x, xm, d0); d1 = fmaf(v.y, xm, d1);
      d2 = fmaf(v.z, xm, d2); d3 = fmaf(v.w, xm, d3);
    }
    __syncthreads();
  }
  float ni = nrm[b*256 + coli];
  {
    int j0 = 4*lane;
    float4 dv;
    dv.x = __fsub_rn(__fadd_rn(ni, nrm[b*256 + j0+0]), __fmul_rn(2.0f, d0));
    dv.y = __fsub_rn(__fadd_rn(ni, nrm[b*256 + j0+1]), __fmul_rn(2.0f, d1));
    dv.z = __fsub_rn(__fadd_rn(ni, nrm[b*256 + j0+2]), __fmul_rn(2.0f, d2));
    dv.w = __fsub_rn(__fadd_rn(ni, nrm[b*256 + j0+3]), __fmul_rn(2.0f, d3));
    *(float4*)(ds + w*256 + j0) = dv;
  }
  __syncthreads();
  for (int r = 0; r < KC; ++r){
    float bv = 3.4e38f; int bj = NPp;
    float4 dv = *(const float4*)(ds + w*256 + 4*lane);
#pragma unroll
    for (int q = 0; q < 4; ++q){
      float v = (q==0)?dv.x:((q==1)?dv.y:((q==2)?dv.z:dv.w));
      int j = 4*lane + q;
      if (v < bv){ bv = v; bj = j; }
    }
#pragma unroll
    for (int off = 32; off >= 1; off >>= 1){
      float ov = __shfl_xor(bv, off, 64);
      int   oj = __shfl_xor(bj, off, 64);
      if (ov < bv || (ov == bv && oj < bj)){ bv = ov; bj = oj; }
    }
    if (lane == 0){ idxo[((size_t)b*256 + coli)*KC + r] = bj; ds[w*256 + bj] = 3.0e38f; }
    __syncthreads();
  }
}

// ---------------- per-point dual GEMM + fused xT transpose ----------------
template<int CIN, int COUT, int T>
__global__ __launch_bounds__(T) void k_gab(const float* __restrict__ x, int xstride,
    const float* __restrict__ wA, const float* __restrict__ wB,
    float* __restrict__ A, float* __restrict__ B, float* __restrict__ xT){
  constexpr int PC  = CIN + 1;
  constexpr int G   = COUT/4;
  constexpr int RS  = T/G;
  constexpr int RPT = 16/RS;
  __shared__ float xsh[16*PC];
  int bi = blockIdx.x, t = threadIdx.x;
  int g = t % G, rs = t / G;
  int i0 = bi*16;
  for (int i = t; i < 16*CIN; i += T){
    int r = i / CIN, m = i - r*CIN;
    xsh[r*PC + m] = x[(size_t)(i0+r)*xstride + m];
  }
  __syncthreads();
  {
    int bb = i0 >> 8, col0 = i0 & 255;
    float* xTb = xT + (size_t)bb*CIN*256 + col0;
    for (int i = t; i < 16*CIN; i += T){
      int m = i >> 4, r = i & 15;
      xTb[m*256 + r] = xsh[r*PC + m];
    }
  }
  float4 accA[RPT], accB[RPT];
#pragma unroll
  for (int rr = 0; rr < RPT; ++rr){
    accA[rr] = make_float4(0.f,0.f,0.f,0.f);
    accB[rr] = make_float4(0.f,0.f,0.f,0.f);
  }
  for (int m = 0; m < CIN; ++m){
    float4 wa = *(const float4*)(wA + (size_t)m*COUT + 4*g);
    float4 wb = *(const float4*)(wB + (size_t)m*COUT + 4*g);
#pragma unroll
    for (int rr = 0; rr < RPT; ++rr){
      float xv = xsh[(rs + rr*RS)*PC + m];
      accA[rr] = fma4s(wa, xv, accA[rr]);
      accB[rr] = fma4s(wb, xv, accB[rr]);
    }
  }
#pragma unroll
  for (int rr = 0; rr < RPT; ++rr){
    int r = i0 + rs + rr*RS;
    *(float4*)(A + (size_t)r*COUT + 4*g) = accA[rr];
    *(float4*)(B + (size_t)r*COUT + 4*g) = accB[rr];
  }
}

// ---------------- edge epilogue: out[i][c] = max_k relu(A[i][c] + B[j_ik][c]) ----------------
template<int COUT>
__global__ __launch_bounds__(256) void k_emax(const float* __restrict__ A, const float* __restrict__ Bm,
    const int* __restrict__ idx, float* __restrict__ out){
  constexpr int GT = COUT/4;
  constexpr int NC = 256/GT;
  __shared__ int js[NC*KC];
  int bi = blockIdx.x, t = threadIdx.x;
  int li = t / GT, c4 = (t % GT)*4;
  int ci = bi*NC + li;
  int rb = (ci >> 8) << 8;
  if (t < NC*KC) js[t] = idx[(size_t)bi*NC*KC + t];
  __syncthreads();
  float4 a = *(const float4*)(A + (size_t)ci*COUT + c4);
  float4 p = make_float4(0.f,0.f,0.f,0.f);
#pragma unroll
  for (int k = 0; k < KC; ++k){
    int j = js[li*KC + k];
    float4 b = *(const float4*)(Bm + (size_t)(rb + j)*COUT + c4);
    p = max4(p, add4(a, b));
  }
  *(float4*)(out + (size_t)ci*COUT + c4) = p;
}

// ---------------- T-Net edge: h0 = relu(A0+B0) then 64->128 conv + k-maxpool ----------------
__global__ __launch_bounds__(128) void k_tedge3(const float* __restrict__ A0, const float* __restrict__ B0,
    const int* __restrict__ idx, const float* __restrict__ wt1, float* __restrict__ out){
  __shared__ __align__(16) float h0s[20*68];
  __shared__ __align__(16) float smax[4*128];
  __shared__ int js[KC];
  int bi = blockIdx.x, t = threadIdx.x;
  int cg = t & 31, kg = t >> 5, k0 = kg*5;
  int rb = (bi >> 8) << 8;
  if (t < KC) js[t] = idx[(size_t)bi*KC + t];
  __syncthreads();
  for (int i = t; i < 20*64; i += 128){
    int k = i >> 6, c = i & 63;
    float v = A0[(size_t)bi*64 + c] + B0[(size_t)(rb + js[k])*64 + c];
    h0s[k*68 + c] = fmaxf(v, 0.0f);
  }
  __syncthreads();
  float4 b2[5];
#pragma unroll
  for (int kk = 0; kk < 5; ++kk) b2[kk] = make_float4(0.f,0.f,0.f,0.f);
  for (int m4 = 0; m4 < 16; ++m4){
    float4 e[5];
#pragma unroll
    for (int kk = 0; kk < 5; ++kk) e[kk] = *(const float4*)(h0s + (k0+kk)*68 + 4*m4);
#pragma unroll
    for (int mm = 0; mm < 4; ++mm){
      float4 w = *(const float4*)(wt1 + (4*m4+mm)*128 + 4*cg);
#pragma unroll
      for (int kk = 0; kk < 5; ++kk){
        float ev = (mm==0)?e[kk].x:((mm==1)?e[kk].y:((mm==2)?e[kk].z:e[kk].w));
        b2[kk] = fma4s(w, ev, b2[kk]);
      }
    }
  }
  float4 p = make_float4(0.f,0.f,0.f,0.f);
#pragma unroll
  for (int kk = 0; kk < 5; ++kk) p = max4(p, b2[kk]);
  *(float4*)(smax + kg*128 + 4*cg) = p;
  __syncthreads();
  if (kg == 0){
    float4 r = *(const float4*)(smax + 4*cg);
#pragma unroll
    for (int g = 1; g < 4; ++g) r = max4(r, *(const float4*)(smax + g*128 + 4*cg));
    *(float4*)(out + (size_t)bi*128 + 4*cg) = r;
  }
}

// ---------------- T-Net 128->1024 + pool: 8 point-chunks, atomicMax combine ----------------
__global__ __launch_bounds__(128) void k_tpool(const float* __restrict__ h, const float* __restrict__ W,
    float* __restrict__ g1024){
  int b = blockIdx.x, t = threadIdx.x;
  int c = blockIdx.y*128 + t;
  int i0 = blockIdx.z*32;
  float4 w[32];
#pragma unroll
  for (int qq = 0; qq < 32; ++qq) w[qq] = *(const float4*)(W + (size_t)c*128 + 4*qq);
  const float* hb = h + (size_t)b*NPp*128;
  float mx = 0.0f;   // seed 0 = relu; partials >=0 so int-compare atomicMax is exact
  for (int i = i0; i < i0 + 32; ++i){
    const float4* hr = (const float4*)(hb + (size_t)i*128);
    float a = 0.0f;
#pragma unroll
    for (int qq = 0; qq < 32; ++qq) a = fma4(w[qq], hr[qq], a);
    mx = fmaxf(mx, a);
  }
  atomicMax((int*)(g1024 + (size_t)b*1024 + c), __float_as_int(mx));
}

// ---------------- T-Net MLP + 3x3 transform applied to new_xyz ----------------
__global__ __launch_bounds__(256) void k_trest(const float* __restrict__ g1024,
    const float* __restrict__ Wg0, const float* __restrict__ Wg1,
    const float* __restrict__ Wl, const float* __restrict__ bl,
    const float* __restrict__ new_xyz, float* __restrict__ x131){
  __shared__ __align__(16) float g1[1024];
  __shared__ __align__(16) float g5[512];
  __shared__ __align__(16) float g2[256];
  __shared__ float tm[12];
  int b = blockIdx.x, t = threadIdx.x;
  for (int m = t; m < 1024; m += 256) g1[m] = g1024[(size_t)b*1024 + m];
  __syncthreads();
#pragma unroll
  for (int cc = 0; cc < 2; ++cc){
    int c = t + cc*256;
    const float4* wr = (const float4*)(Wg0 + (size_t)c*1024);
    const float4* gv = (const float4*)g1;
    float a = 0.0f;
    for (int qq = 0; qq < 256; ++qq) a = fma4(wr[qq], gv[qq], a);
    g5[c] = fmaxf(a, 0.0f);
  }
  __syncthreads();
  {
    const float4* wr = (const float4*)(Wg1 + (size_t)t*512);
    const float4* gv = (const float4*)g5;
    float a = 0.0f;
    for (int qq = 0; qq < 128; ++qq) a = fma4(wr[qq], gv[qq], a);
    g2[t] = fmaxf(a, 0.0f);
  }
  __syncthreads();
  if (t < 9){
    const float4* wr = (const float4*)(Wl + (size_t)t*256);
    const float4* gv = (const float4*)g2;
    float a = 0.0f;
#pragma unroll
    for (int qq = 0; qq < 64; ++qq) a = fma4(wr[qq], gv[qq], a);
    a += bl[t];
    if (t == 0 || t == 4 || t == 8) a += 1.0f;
    tm[t] = a;
  }
  __syncthreads();
  {
    const float* nx = new_xyz + ((size_t)b*NPp + t)*3;
    float X = nx[0], Y = nx[1], Z = nx[2];
#pragma unroll
    for (int i = 0; i < 3; ++i){
      float v = __fadd_rn(__fadd_rn(__fmul_rn(tm[i*3+0], X), __fmul_rn(tm[i*3+1], Y)), __fmul_rn(tm[i*3+2], Z));
      x131[((size_t)b*NPp + t)*132 + 128 + i] = v;
    }
  }
}

// ---------------- 896->128 conv + global max pool (atomicMax; poison is negative int) ----------------
__global__ __launch_bounds__(128) void k_dgl(const float* __restrict__ f1, const float* __restrict__ f2,
    const float* __restrict__ f3, const float* __restrict__ W, float* __restrict__ g128){
  int b = blockIdx.x, t = threadIdx.x;
  int i0 = blockIdx.y * 16;
  const float* wr = W + (size_t)t*896;
  float acc[16];
#pragma unroll
  for (int ii = 0; ii < 16; ++ii) acc[ii] = 0.0f;
  for (int q = 0; q < 32; ++q){
    float4 w = *(const float4*)(wr + 4*q);
#pragma unroll
    for (int ii = 0; ii < 16; ++ii){
      float4 v = *(const float4*)(f1 + ((size_t)b*NPp + i0 + ii)*128 + 4*q);
      acc[ii] = fma4(w, v, acc[ii]);
    }
  }
  for (int q = 0; q < 64; ++q){
    float4 w = *(const float4*)(wr + 128 + 4*q);
#pragma unroll
    for (int ii = 0; ii < 16; ++ii){
      float4 v = *(const float4*)(f2 + ((size_t)b*NPp + i0 + ii)*256 + 4*q);
      acc[ii] = fma4(w, v, acc[ii]);
    }
  }
  for (int q = 0; q < 128; ++q){
    float4 w = *(const float4*)(wr + 384 + 4*q);
#pragma unroll
    for (int ii = 0; ii < 16; ++ii){
      float4 v = *(const float4*)(f3 + ((size_t)b*NPp + i0 + ii)*512 + 4*q);
      acc[ii] = fma4(w, v, acc[ii]);
    }
  }
#pragma unroll
  for (int ii = 0; ii < 16; ++ii){
    float v = fmaxf(acc[ii], 0.0f);
    atomicMax((int*)(g128 + (size_t)b*128 + t), __float_as_int(v));
  }
}

// ---------------- classifier head ----------------
__global__ __launch_bounds__(256) void k_final(const float* __restrict__ g128,
    const float* __restrict__ W0, const float* __restrict__ W1,
    const float* __restrict__ Wc, const float* __restrict__ bc, float* __restrict__ out){
  __shared__ __align__(16) float g0[128];
  __shared__ __align__(16) float g5[512];
  __shared__ __align__(16) float g2[256];
  int b = blockIdx.x, t = threadIdx.x;
  if (t < 128) g0[t] = g128[(size_t)b*128 + t];
  __syncthreads();
#pragma unroll
  for (int cc = 0; cc < 2; ++cc){
    int c = t + cc*256;
    const float4* wr = (const float4*)(W0 + (size_t)c*128);
    const float4* gv = (const float4*)g0;
    float a = 0.0f;
#pragma unroll
    for (int qq = 0; qq < 32; ++qq) a = fma4(wr[qq], gv[qq], a);
    g5[c] = fmaxf(a, 0.0f);
  }
  __syncthreads();
  {
    const float4* wr = (const float4*)(W1 + (size_t)t*512);
    const float4* gv = (const float4*)g5;
    float a = 0.0f;
    for (int qq = 0; qq < 128; ++qq) a = fma4(wr[qq], gv[qq], a);
    g2[t] = fmaxf(a, 0.0f);
  }
  __syncthreads();
  if (t < 40){
    const float4* wr = (const float4*)(Wc + (size_t)t*256);
    const float4* gv = (const float4*)g2;
    float a = 0.0f;
#pragma unroll
    for (int qq = 0; qq < 64; ++qq) a = fma4(wr[qq], gv[qq], a);
    out[(size_t)b*40 + t] = a + bc[t];
  }
}

extern "C" void kernel_launch(void* const* d_in, const int* in_sizes, int n_in,
                              void* d_out, int out_size, void* d_ws, size_t ws_size,
                              hipStream_t stream){
  (void)in_sizes; (void)n_in; (void)out_size; (void)ws_size;
  const float* points     = (const float*)d_in[0];
  const float* sa_w0      = (const float*)d_in[1];
  const float* sa_w1      = (const float*)d_in[2];
  const float* sa_w2      = (const float*)d_in[3];
  const float* t_ec_w0    = (const float*)d_in[4];
  const float* t_ec_w1    = (const float*)d_in[5];
  const float* t_local_w  = (const float*)d_in[6];
  const float* t_g_w0     = (const float*)d_in[7];
  const float* t_g_w1     = (const float*)d_in[8];
  const float* t_lin_w    = (const float*)d_in[9];
  const float* t_lin_b    = (const float*)d_in[10];
  const float* dg_ec_w0   = (const float*)d_in[11];
  const float* dg_ec_w1   = (const float*)d_in[12];
  const float* dg_ec_w2   = (const float*)d_in[13];
  const float* dg_local_w = (const float*)d_in[14];
  const float* dg_g_w0    = (const float*)d_in[15];
  const float* dg_g_w1    = (const float*)d_in[16];
  const float* cls_w      = (const float*)d_in[17];
  const float* cls_b      = (const float*)d_in[18];
  float* out = (float*)d_out;

  float* ws     = (float*)d_ws;
  float* xyz    = ws;                    // 393216
  float* xnrm   = xyz    + 393216;       // 131072
  float* nxyz   = xnrm   + 131072;       // 24576
  float* feat   = nxyz   + 24576;        // 1048576
  float* x131   = feat   + 1048576;      // 1081344
  float* nrm    = x131   + 1081344;      // 8192
  int*   idx    = (int*)(nrm + 8192);    // 163840
  float* ht     = (float*)(idx + 163840);// 1048576 (reused as f1)
  float* g1024v = ht     + 1048576;      // 32768
  float* f2     = g1024v + 32768;        // 2097152
  float* f3     = f2     + 2097152;      // 4194304
  float* g128v  = f3     + 4194304;      // 4096
  float* wt_t1  = g128v  + 4096;         // 8192   (64x128)
  float* waT0   = wt_t1  + 8192;         // 8384   (131x64)
  float* wbT0   = waT0   + 8384;         // 8384
  float* waD0   = wbT0   + 8384;         // 16768  (131x128)
  float* wbD0   = waD0   + 16768;        // 16768
  float* waD1   = wbD0   + 16768;        // 32768  (128x256)
  float* wbD1   = waD1   + 32768;        // 32768
  float* waD2   = wbD1   + 32768;        // 131072 (256x512)
  float* wbD2   = waD2   + 131072;       // 131072
  float* Ab     = wbD2   + 131072;       // 4194304
  float* Bb     = Ab     + 4194304;      // 4194304
  float* f1 = ht;
  float* xT = f3;                        // alias: xT lives in f3 until k_emax<512> writes f3

  k_prep<<<512, 256, 0, stream>>>(points, xyz, xnrm);
  k_wprep<<<771, 256, 0, stream>>>(t_ec_w0, t_ec_w1, dg_ec_w0, dg_ec_w1, dg_ec_w2,
                                   waT0, wbT0, wt_t1, waD0, wbD0, waD1, wbD1, waD2, wbD2);
  k_fps<<<BB, 256, 0, stream>>>(xyz, nxyz);
  k_sa<<<BB*NPp, 64, 0, stream>>>(xyz, xnrm, nxyz, sa_w0, sa_w1, sa_w2, feat, x131);

  // T-Net branch (x = [feat, new_xyz])
  k_gab<131,64,256><<<512, 256, 0, stream>>>(x131, 132, waT0, wbT0, Ab, Bb, xT);
  k_norm2<131><<<128, 64, 0, stream>>>(xT, nrm);
  k_knn3<131><<<1024, 512, 0, stream>>>(xT, nrm, idx);
  k_tedge3<<<BB*NPp, 128, 0, stream>>>(Ab, Bb, idx, wt_t1, ht);
  k_tpool<<<dim3(BB, 8, 8), 128, 0, stream>>>(ht, t_local_w, g1024v);
  k_trest<<<BB, 256, 0, stream>>>(g1024v, t_g_w0, t_g_w1, t_lin_w, t_lin_b, nxyz, x131);

  // DGCNN layer 1 (x = [feat, xyz_t], 131 dims)
  k_gab<131,128,512><<<512, 512, 0, stream>>>(x131, 132, waD0, wbD0, Ab, Bb, xT);
  k_norm2<131><<<128, 64, 0, stream>>>(xT, nrm);
  k_knn3<131><<<1024, 512, 0, stream>>>(xT, nrm, idx);
  k_emax<128><<<1024, 256, 0, stream>>>(Ab, Bb, idx, f1);
  // layer 2
  k_gab<128,256,512><<<512, 512, 0, stream>>>(f1, 128, waD1, wbD1, Ab, Bb, xT);
  k_norm2<128><<<128, 64, 0, stream>>>(xT, nrm);
  k_knn3<128><<<1024, 512, 0, stream>>>(xT, nrm, idx);
  k_emax<256><<<2048, 256, 0, stream>>>(Ab, Bb, idx, f2);
  // layer 3
  k_gab<256,512,512><<<512, 512, 0, stream>>>(f2, 256, waD2, wbD2, Ab, Bb, xT);
  k_norm2<256><<<128, 64, 0, stream>>>(xT, nrm);
  k_knn3<256><<<1024, 512, 0, stream>>>(xT, nrm, idx);
  k_emax<512><<<4096, 256, 0, stream>>>(Ab, Bb, idx, f3);

  // local conv + global pool + head
  k_dgl<<<dim3(BB, 16), 128, 0, stream>>>(f1, f2, f3, dg_local_w, g128v);
  k_final<<<BB, 256, 0, stream>>>(g128v, dg_g_w0, dg_g_w1, cls_w, cls_b, out);
}

// Round 11
// 1553.454 us; speedup vs baseline: 1.1656x; 1.0270x over previous
//
#include <hip/hip_runtime.h>
#include <math.h>

#define BB 32
#define NN 4096
#define NPp 256
#define NSs 64
#define KC 20

__device__ __forceinline__ float fma4(const float4 w, const float4 v, float a){
  a = fmaf(w.x, v.x, a); a = fmaf(w.y, v.y, a);
  a = fmaf(w.z, v.z, a); a = fmaf(w.w, v.w, a); return a;
}
__device__ __forceinline__ float4 fma4s(const float4 w, float s, float4 a){
  a.x = fmaf(w.x, s, a.x); a.y = fmaf(w.y, s, a.y);
  a.z = fmaf(w.z, s, a.z); a.w = fmaf(w.w, s, a.w); return a;
}
__device__ __forceinline__ float4 max4(float4 a, float4 b){
  a.x = fmaxf(a.x, b.x); a.y = fmaxf(a.y, b.y);
  a.z = fmaxf(a.z, b.z); a.w = fmaxf(a.w, b.w); return a;
}
__device__ __forceinline__ float4 add4(float4 a, float4 b){
  a.x += b.x; a.y += b.y; a.z += b.z; a.w += b.w; return a;
}

template<int C>
__device__ __forceinline__ int dpp_i(int x){
  return __builtin_amdgcn_update_dpp(x, x, C, 0xf, 0xf, false);
}

// ---------------- unified weight prep (all transposes/splits in one kernel) ----------------
__global__ void k_wprep(const float* __restrict__ t0, const float* __restrict__ t1,
                        const float* __restrict__ d0, const float* __restrict__ d1,
                        const float* __restrict__ d2,
                        float* __restrict__ waT0, float* __restrict__ wbT0,
                        float* __restrict__ wt_t1,
                        float* __restrict__ waD0, float* __restrict__ wbD0,
                        float* __restrict__ waD1, float* __restrict__ wbD1,
                        float* __restrict__ waD2, float* __restrict__ wbD2){
  int i = blockIdx.x*256 + threadIdx.x;
  if (i < 8384){                       // t_ec_w0: [64][262] -> A/B [131][64]
    int m = i >> 6;
    int c = i & 63;
    float bb = t0[(size_t)c*262 + m];
    float dd = t0[(size_t)c*262 + 131 + m];
    waT0[i] = __fsub_rn(bb, dd); wbT0[i] = dd;
    return;
  }
  i -= 8384;
  if (i < 8192){                       // t_ec_w1: [128][64] -> [64][128]
    int m = i >> 7, c = i & 127;
    wt_t1[i] = t1[(size_t)c*64 + m];
    return;
  }
  i -= 8192;
  if (i < 16768){                      // dg_ec_w0: [128][262] -> A/B [131][128]
    int m = i >> 7, c = i & 127;
    float bb = d0[(size_t)c*262 + m];
    float dd = d0[(size_t)c*262 + 131 + m];
    waD0[i] = __fsub_rn(bb, dd); wbD0[i] = dd;
    return;
  }
  i -= 16768;
  if (i < 32768){                      // dg_ec_w1: [256][256] -> A/B [128][256]
    int m = i >> 8, c = i & 255;
    float bb = d1[(size_t)c*256 + m];
    float dd = d1[(size_t)c*256 + 128 + m];
    waD1[i] = __fsub_rn(bb, dd); wbD1[i] = dd;
    return;
  }
  i -= 32768;
  if (i < 131072){                     // dg_ec_w2: [512][512] -> A/B [256][512]
    int m = i >> 9, c = i & 511;
    float bb = d2[(size_t)c*512 + m];
    float dd = d2[(size_t)c*512 + 256 + m];
    waD2[i] = __fsub_rn(bb, dd); wbD2[i] = dd;
  }
}

// ---------------- transpose + point norms ----------------
__global__ void k_prep(const float* __restrict__ pts, float* __restrict__ xyz, float* __restrict__ xnrm){
  int i = blockIdx.x*256 + threadIdx.x;
  if (i >= BB*NN) return;
  int b = i >> 12, n = i & (NN-1);
  float X = pts[(b*3+0)*NN + n];
  float Y = pts[(b*3+1)*NN + n];
  float Z = pts[(b*3+2)*NN + n];
  xyz[i*3+0]=X; xyz[i*3+1]=Y; xyz[i*3+2]=Z;
  xnrm[i] = __fadd_rn(__fadd_rn(__fmul_rn(X,X), __fmul_rn(Y,Y)), __fmul_rn(Z,Z));
}

// ---------------- farthest point sampling: no in-loop global stores ----------------
__global__ __launch_bounds__(256) void k_fps(const float* __restrict__ xyz, float* __restrict__ new_xyz){
  __shared__ float part[2][4][8];
  int b = blockIdx.x, t = threadIdx.x;
  int w = t >> 6;
  float px[16], py[16], pz[16], dist[16];
#pragma unroll
  for (int q = 0; q < 16; ++q){
    const float* p = xyz + ((size_t)b*NN + q*256 + t)*3;
    px[q] = p[0]; py[q] = p[1]; pz[q] = p[2];
    dist[q] = __builtin_inff();
  }
  const float* p0 = xyz + (size_t)b*NN*3;
  float Px = p0[0], Py = p0[1], Pz = p0[2];
  float sx = 0.f, sy = 0.f, sz = 0.f;   // thread t snapshots iteration t's pivot
  for (int it = 0; it < NPp; ++it){
    if (t == it){ sx = Px; sy = Py; sz = Pz; }
    float bv = -1.0f, bx = 0.f, by = 0.f, bz = 0.f; int bj = 0;
#pragma unroll
    for (int q = 0; q < 16; ++q){
      float dx = __fsub_rn(px[q], Px);
      float dy = __fsub_rn(py[q], Py);
      float dz = __fsub_rn(pz[q], Pz);
      float dd = __fadd_rn(__fadd_rn(__fmul_rn(dx,dx), __fmul_rn(dy,dy)), __fmul_rn(dz,dz));
      float dm = fminf(dist[q], dd);
      dist[q] = dm;
      if (dm > bv){ bv = dm; bj = q*256 + t; bx = px[q]; by = py[q]; bz = pz[q]; }
    }
#define FPS_STAGE(C) { \
    float ov = __int_as_float(dpp_i<C>(__float_as_int(bv))); \
    int   oj = dpp_i<C>(bj); \
    float ox = __int_as_float(dpp_i<C>(__float_as_int(bx))); \
    float oy = __int_as_float(dpp_i<C>(__float_as_int(by))); \
    float oz = __int_as_float(dpp_i<C>(__float_as_int(bz))); \
    bool tk = (ov > bv) || (ov == bv && oj < bj); \
    bv = tk ? ov : bv; bj = tk ? oj : bj; \
    bx = tk ? ox : bx; by = tk ? oy : by; bz = tk ? oz : bz; }
    FPS_STAGE(0x111) FPS_STAGE(0x112) FPS_STAGE(0x114) FPS_STAGE(0x118)
    FPS_STAGE(0x142) FPS_STAGE(0x143)
#undef FPS_STAGE
    int par = it & 1;
    if ((t & 63) == 63){
      float* pp = part[par][w];
      pp[0] = bv; ((int*)pp)[1] = bj; pp[2] = bx; pp[3] = by; pp[4] = bz;
    }
    __syncthreads();
    const float* q0 = part[par][0];
    float fv = q0[0]; int fj = ((const int*)q0)[1];
    float fx = q0[2], fy = q0[3], fz = q0[4];
#pragma unroll
    for (int ww = 1; ww < 4; ++ww){
      const float* pp = part[par][ww];
      float ov = pp[0]; int oj = ((const int*)pp)[1];
      if (ov > fv || (ov == fv && oj < fj)){ fv = ov; fj = oj; fx = pp[2]; fy = pp[3]; fz = pp[4]; }
    }
    Px = fx; Py = fy; Pz = fz;
  }
  // coalesced pivot write-out, once per launch
  {
    float* o = new_xyz + ((size_t)b*NPp + t)*3;
    o[0] = sx; o[1] = sy; o[2] = sz;
  }
}

// ---------------- ball query + SA convs + maxpool (fully-unrolled register arrays) ----------------
__global__ __launch_bounds__(64, 1) void k_sa(const float* __restrict__ xyz, const float* __restrict__ xnrm,
    const float* __restrict__ new_xyz, const float* __restrict__ w0, const float* __restrict__ w1,
    const float* __restrict__ w2, float* __restrict__ feat, float* __restrict__ x131){
  __shared__ int gix[64];
  int bi = blockIdx.x, lane = threadIdx.x;
  int b = bi >> 8;
  const float* q = new_xyz + (size_t)bi*3;
  float qx=q[0], qy=q[1], qz=q[2];
  float nq = __fadd_rn(__fadd_rn(__fmul_rn(qx,qx), __fmul_rn(qy,qy)), __fmul_rn(qz,qz));
  int cnt = 0;
  for (int base = 0; base < NN && cnt < NSs; base += 256){
#pragma unroll
    for (int u = 0; u < 4; ++u){
      int j = base + u*64 + lane;
      const float* p = xyz + ((size_t)b*NN + j)*3;
      float dot = __fadd_rn(__fadd_rn(__fmul_rn(qx,p[0]), __fmul_rn(qy,p[1])), __fmul_rn(qz,p[2]));
      float d2 = __fsub_rn(__fadd_rn(nq, xnrm[b*NN + j]), __fmul_rn(2.0f, dot));
      bool inb = d2 < 0.04f;
      unsigned long long m = __ballot(inb);
      int pos = cnt + (int)__popcll(m & ((1ull << lane) - 1ull));
      if (inb && pos < NSs) gix[pos] = j;
      cnt += (int)__popcll(m);
    }
  }
  __syncthreads();
  int g0 = gix[0];
  if (lane >= cnt) gix[lane] = g0;
  __syncthreads();
  // lane = sample; ALL loops touching h0h/h1 are fully unrolled so the arrays stay in VGPRs
  float h1[64];
  {
    int gj = gix[lane];
    const float* p = xyz + ((size_t)b*NN + gj)*3;
    float px = p[0]-qx, py = p[1]-qy, pz = p[2]-qz;
#pragma unroll
    for (int c = 0; c < 64; ++c) h1[c] = 0.0f;
#pragma unroll
    for (int half = 0; half < 2; ++half){
      float h0h[32];
#pragma unroll
      for (int mm = 0; mm < 32; ++mm){
        int c = half*32 + mm;
        float a = fmaf(w0[c*3+2], pz, fmaf(w0[c*3+1], py, w0[c*3]*px));
        h0h[mm] = fmaxf(a, 0.0f);
      }
#pragma unroll
      for (int c = 0; c < 64; ++c){
        const float4* wr = (const float4*)(w1 + c*64 + half*32);
        float a = h1[c];
#pragma unroll
        for (int qq = 0; qq < 8; ++qq){
          float4 w = wr[qq];
          a = fmaf(w.x, h0h[4*qq+0], a);
          a = fmaf(w.y, h0h[4*qq+1], a);
          a = fmaf(w.z, h0h[4*qq+2], a);
          a = fmaf(w.w, h0h[4*qq+3], a);
        }
        h1[c] = a;
      }
    }
#pragma unroll
    for (int c = 0; c < 64; ++c) h1[c] = fmaxf(h1[c], 0.0f);
  }
  // third conv: per-lane dot for each out channel, wave max-reduce via DPP, keep own channel
  float m0 = 0.0f, m1 = 0.0f;
#pragma unroll 2
  for (int c = 0; c < 128; ++c){
    const float4* wr = (const float4*)(w2 + (size_t)c*64);
    float a = 0.0f;
#pragma unroll
    for (int qq = 0; qq < 16; ++qq){
      float4 w = wr[qq];
      a = fmaf(w.x, h1[4*qq+0], a);
      a = fmaf(w.y, h1[4*qq+1], a);
      a = fmaf(w.z, h1[4*qq+2], a);
      a = fmaf(w.w, h1[4*qq+3], a);
    }
    a = fmaxf(a, 0.0f);
#define SA_MAX(C) { float o = __int_as_float(dpp_i<C>(__float_as_int(a))); a = fmaxf(a, o); }
    SA_MAX(0x111) SA_MAX(0x112) SA_MAX(0x114) SA_MAX(0x118) SA_MAX(0x142) SA_MAX(0x143)
#undef SA_MAX
    float r = __int_as_float(__builtin_amdgcn_readlane(__float_as_int(a), 63));
    if (c < 64){ if (lane == c) m0 = r; }
    else       { if (lane == c - 64) m1 = r; }
  }
  feat[(size_t)bi*128 + lane]      = m0;
  feat[(size_t)bi*128 + 64 + lane] = m1;
  x131[(size_t)bi*132 + lane]      = m0;
  x131[(size_t)bi*132 + 64 + lane] = m1;
  if (lane < 3) x131[(size_t)bi*132 + 128 + lane] = (lane==0)?qx:((lane==1)?qy:qz);
}

// ---------------- feature norms (from xT, coalesced) ----------------
template<int CIN>
__global__ void k_norm2(const float* __restrict__ xT, float* __restrict__ nrm){
  int p = blockIdx.x*64 + threadIdx.x;
  if (p >= BB*NPp) return;
  int b = p >> 8, col = p & 255;
  const float* base = xT + (size_t)b*CIN*256 + col;
  float a = 0.0f;
  for (int m = 0; m < CIN; ++m){
    float v = base[m*256];
    a = __fadd_rn(a, __fmul_rn(v, v));
  }
  nrm[p] = a;
}

// ---------------- kNN, 8 centroids/block, LDS-staged xT chunks ----------------
template<int CIN>
__global__ __launch_bounds__(512) void k_knn3(const float* __restrict__ xT,
    const float* __restrict__ nrm, int* __restrict__ idxo){
  __shared__ __align__(16) float sch[16*256];
  __shared__ __align__(16) float ds[8*256];
  int bi = blockIdx.x, t = threadIdx.x;
  int w = t >> 6, lane = t & 63;
  int b = bi >> 5;
  int coli = (bi & 31)*8 + w;
  const float* xb = xT + (size_t)b*CIN*256;
  float d0=0.f, d1=0.f, d2=0.f, d3=0.f;
  for (int m0 = 0; m0 < CIN; m0 += 16){
    int mc = (CIN - m0 < 16) ? (CIN - m0) : 16;
    for (int i = t; i < mc*64; i += 512){
      int mm = i >> 6, c4 = i & 63;
      *(float4*)(sch + mm*256 + c4*4) = *(const float4*)(xb + (size_t)(m0+mm)*256 + c4*4);
    }
    __syncthreads();
    for (int mm = 0; mm < mc; ++mm){
      float xm = sch[mm*256 + coli];
      float4 v = *(const float4*)(sch + mm*256 + 4*lane);
      d0 = fmaf(v.x, xm, d0); d1 = fmaf(v.y, xm, d1);
      d2 = fmaf(v.z, xm, d2); d3 = fmaf(v.w, xm, d3);
    }
    __syncthreads();
  }
  float ni = nrm[b*256 + coli];
  {
    int j0 = 4*lane;
    float4 dv;
    dv.x = __fsub_rn(__fadd_rn(ni, nrm[b*256 + j0+0]), __fmul_rn(2.0f, d0));
    dv.y = __fsub_rn(__fadd_rn(ni, nrm[b*256 + j0+1]), __fmul_rn(2.0f, d1));
    dv.z = __fsub_rn(__fadd_rn(ni, nrm[b*256 + j0+2]), __fmul_rn(2.0f, d2));
    dv.w = __fsub_rn(__fadd_rn(ni, nrm[b*256 + j0+3]), __fmul_rn(2.0f, d3));
    *(float4*)(ds + w*256 + j0) = dv;
  }
  __syncthreads();
  for (int r = 0; r < KC; ++r){
    float bv = 3.4e38f; int bj = NPp;
    float4 dv = *(const float4*)(ds + w*256 + 4*lane);
#pragma unroll
    for (int q = 0; q < 4; ++q){
      float v = (q==0)?dv.x:((q==1)?dv.y:((q==2)?dv.z:dv.w));
      int j = 4*lane + q;
      if (v < bv){ bv = v; bj = j; }
    }
#pragma unroll
    for (int off = 32; off >= 1; off >>= 1){
      float ov = __shfl_xor(bv, off, 64);
      int   oj = __shfl_xor(bj, off, 64);
      if (ov < bv || (ov == bv && oj < bj)){ bv = ov; bj = oj; }
    }
    if (lane == 0){ idxo[((size_t)b*256 + coli)*KC + r] = bj; ds[w*256 + bj] = 3.0e38f; }
    __syncthreads();
  }
}

// ---------------- per-point dual GEMM + fused xT transpose ----------------
template<int CIN, int COUT, int T>
__global__ __launch_bounds__(T) void k_gab(const float* __restrict__ x, int xstride,
    const float* __restrict__ wA, const float* __restrict__ wB,
    float* __restrict__ A, float* __restrict__ B, float* __restrict__ xT){
  constexpr int PC  = CIN + 1;
  constexpr int G   = COUT/4;
  constexpr int RS  = T/G;
  constexpr int RPT = 16/RS;
  __shared__ float xsh[16*PC];
  int bi = blockIdx.x, t = threadIdx.x;
  int g = t % G, rs = t / G;
  int i0 = bi*16;
  for (int i = t; i < 16*CIN; i += T){
    int r = i / CIN, m = i - r*CIN;
    xsh[r*PC + m] = x[(size_t)(i0+r)*xstride + m];
  }
  __syncthreads();
  {
    int bb = i0 >> 8, col0 = i0 & 255;
    float* xTb = xT + (size_t)bb*CIN*256 + col0;
    for (int i = t; i < 16*CIN; i += T){
      int m = i >> 4, r = i & 15;
      xTb[m*256 + r] = xsh[r*PC + m];
    }
  }
  float4 accA[RPT], accB[RPT];
#pragma unroll
  for (int rr = 0; rr < RPT; ++rr){
    accA[rr] = make_float4(0.f,0.f,0.f,0.f);
    accB[rr] = make_float4(0.f,0.f,0.f,0.f);
  }
  for (int m = 0; m < CIN; ++m){
    float4 wa = *(const float4*)(wA + (size_t)m*COUT + 4*g);
    float4 wb = *(const float4*)(wB + (size_t)m*COUT + 4*g);
#pragma unroll
    for (int rr = 0; rr < RPT; ++rr){
      float xv = xsh[(rs + rr*RS)*PC + m];
      accA[rr] = fma4s(wa, xv, accA[rr]);
      accB[rr] = fma4s(wb, xv, accB[rr]);
    }
  }
#pragma unroll
  for (int rr = 0; rr < RPT; ++rr){
    int r = i0 + rs + rr*RS;
    *(float4*)(A + (size_t)r*COUT + 4*g) = accA[rr];
    *(float4*)(B + (size_t)r*COUT + 4*g) = accB[rr];
  }
}

// ---------------- edge epilogue: out[i][c] = max_k relu(A[i][c] + B[j_ik][c]) ----------------
template<int COUT>
__global__ __launch_bounds__(256) void k_emax(const float* __restrict__ A, const float* __restrict__ Bm,
    const int* __restrict__ idx, float* __restrict__ out){
  constexpr int GT = COUT/4;
  constexpr int NC = 256/GT;
  __shared__ int js[NC*KC];
  int bi = blockIdx.x, t = threadIdx.x;
  int li = t / GT, c4 = (t % GT)*4;
  int ci = bi*NC + li;
  int rb = (ci >> 8) << 8;
  if (t < NC*KC) js[t] = idx[(size_t)bi*NC*KC + t];
  __syncthreads();
  float4 a = *(const float4*)(A + (size_t)ci*COUT + c4);
  float4 p = make_float4(0.f,0.f,0.f,0.f);
#pragma unroll
  for (int k = 0; k < KC; ++k){
    int j = js[li*KC + k];
    float4 b = *(const float4*)(Bm + (size_t)(rb + j)*COUT + c4);
    p = max4(p, add4(a, b));
  }
  *(float4*)(out + (size_t)ci*COUT + c4) = p;
}

// ---------------- T-Net edge: h0 = relu(A0+B0) then 64->128 conv + k-maxpool ----------------
__global__ __launch_bounds__(128) void k_tedge3(const float* __restrict__ A0, const float* __restrict__ B0,
    const int* __restrict__ idx, const float* __restrict__ wt1, float* __restrict__ out){
  __shared__ __align__(16) float h0s[20*68];
  __shared__ __align__(16) float smax[4*128];
  __shared__ int js[KC];
  int bi = blockIdx.x, t = threadIdx.x;
  int cg = t & 31, kg = t >> 5, k0 = kg*5;
  int rb = (bi >> 8) << 8;
  if (t < KC) js[t] = idx[(size_t)bi*KC + t];
  __syncthreads();
  for (int i = t; i < 20*64; i += 128){
    int k = i >> 6, c = i & 63;
    float v = A0[(size_t)bi*64 + c] + B0[(size_t)(rb + js[k])*64 + c];
    h0s[k*68 + c] = fmaxf(v, 0.0f);
  }
  __syncthreads();
  float4 b2[5];
#pragma unroll
  for (int kk = 0; kk < 5; ++kk) b2[kk] = make_float4(0.f,0.f,0.f,0.f);
  for (int m4 = 0; m4 < 16; ++m4){
    float4 e[5];
#pragma unroll
    for (int kk = 0; kk < 5; ++kk) e[kk] = *(const float4*)(h0s + (k0+kk)*68 + 4*m4);
#pragma unroll
    for (int mm = 0; mm < 4; ++mm){
      float4 w = *(const float4*)(wt1 + (4*m4+mm)*128 + 4*cg);
#pragma unroll
      for (int kk = 0; kk < 5; ++kk){
        float ev = (mm==0)?e[kk].x:((mm==1)?e[kk].y:((mm==2)?e[kk].z:e[kk].w));
        b2[kk] = fma4s(w, ev, b2[kk]);
      }
    }
  }
  float4 p = make_float4(0.f,0.f,0.f,0.f);
#pragma unroll
  for (int kk = 0; kk < 5; ++kk) p = max4(p, b2[kk]);
  *(float4*)(smax + kg*128 + 4*cg) = p;
  __syncthreads();
  if (kg == 0){
    float4 r = *(const float4*)(smax + 4*cg);
#pragma unroll
    for (int g = 1; g < 4; ++g) r = max4(r, *(const float4*)(smax + g*128 + 4*cg));
    *(float4*)(out + (size_t)bi*128 + 4*cg) = r;
  }
}

// ---------------- T-Net 128->1024 + pool: 8 point-chunks, atomicMax combine ----------------
__global__ __launch_bounds__(128) void k_tpool(const float* __restrict__ h, const float* __restrict__ W,
    float* __restrict__ g1024){
  int b = blockIdx.x, t = threadIdx.x;
  int c = blockIdx.y*128 + t;
  int i0 = blockIdx.z*32;
  float4 w[32];
#pragma unroll
  for (int qq = 0; qq < 32; ++qq) w[qq] = *(const float4*)(W + (size_t)c*128 + 4*qq);
  const float* hb = h + (size_t)b*NPp*128;
  float mx = 0.0f;   // seed 0 = relu; partials >=0 so int-compare atomicMax is exact
  for (int i = i0; i < i0 + 32; ++i){
    const float4* hr = (const float4*)(hb + (size_t)i*128);
    float a = 0.0f;
#pragma unroll
    for (int qq = 0; qq < 32; ++qq) a = fma4(w[qq], hr[qq], a);
    mx = fmaxf(mx, a);
  }
  atomicMax((int*)(g1024 + (size_t)b*1024 + c), __float_as_int(mx));
}

// ---------------- T-Net MLP + 3x3 transform applied to new_xyz ----------------
__global__ __launch_bounds__(256) void k_trest(const float* __restrict__ g1024,
    const float* __restrict__ Wg0, const float* __restrict__ Wg1,
    const float* __restrict__ Wl, const float* __restrict__ bl,
    const float* __restrict__ new_xyz, float* __restrict__ x131){
  __shared__ __align__(16) float g1[1024];
  __shared__ __align__(16) float g5[512];
  __shared__ __align__(16) float g2[256];
  __shared__ float tm[12];
  int b = blockIdx.x, t = threadIdx.x;
  for (int m = t; m < 1024; m += 256) g1[m] = g1024[(size_t)b*1024 + m];
  __syncthreads();
#pragma unroll
  for (int cc = 0; cc < 2; ++cc){
    int c = t + cc*256;
    const float4* wr = (const float4*)(Wg0 + (size_t)c*1024);
    const float4* gv = (const float4*)g1;
    float a = 0.0f;
    for (int qq = 0; qq < 256; ++qq) a = fma4(wr[qq], gv[qq], a);
    g5[c] = fmaxf(a, 0.0f);
  }
  __syncthreads();
  {
    const float4* wr = (const float4*)(Wg1 + (size_t)t*512);
    const float4* gv = (const float4*)g5;
    float a = 0.0f;
    for (int qq = 0; qq < 128; ++qq) a = fma4(wr[qq], gv[qq], a);
    g2[t] = fmaxf(a, 0.0f);
  }
  __syncthreads();
  if (t < 9){
    const float4* wr = (const float4*)(Wl + (size_t)t*256);
    const float4* gv = (const float4*)g2;
    float a = 0.0f;
#pragma unroll
    for (int qq = 0; qq < 64; ++qq) a = fma4(wr[qq], gv[qq], a);
    a += bl[t];
    if (t == 0 || t == 4 || t == 8) a += 1.0f;
    tm[t] = a;
  }
  __syncthreads();
  {
    const float* nx = new_xyz + ((size_t)b*NPp + t)*3;
    float X = nx[0], Y = nx[1], Z = nx[2];
#pragma unroll
    for (int i = 0; i < 3; ++i){
      float v = __fadd_rn(__fadd_rn(__fmul_rn(tm[i*3+0], X), __fmul_rn(tm[i*3+1], Y)), __fmul_rn(tm[i*3+2], Z));
      x131[((size_t)b*NPp + t)*132 + 128 + i] = v;
    }
  }
}

// ---------------- 896->128 conv + global max pool (atomicMax; poison is negative int) ----------------
__global__ __launch_bounds__(128) void k_dgl(const float* __restrict__ f1, const float* __restrict__ f2,
    const float* __restrict__ f3, const float* __restrict__ W, float* __restrict__ g128){
  int b = blockIdx.x, t = threadIdx.x;
  int i0 = blockIdx.y * 16;
  const float* wr = W + (size_t)t*896;
  float acc[16];
#pragma unroll
  for (int ii = 0; ii < 16; ++ii) acc[ii] = 0.0f;
  for (int q = 0; q < 32; ++q){
    float4 w = *(const float4*)(wr + 4*q);
#pragma unroll
    for (int ii = 0; ii < 16; ++ii){
      float4 v = *(const float4*)(f1 + ((size_t)b*NPp + i0 + ii)*128 + 4*q);
      acc[ii] = fma4(w, v, acc[ii]);
    }
  }
  for (int q = 0; q < 64; ++q){
    float4 w = *(const float4*)(wr + 128 + 4*q);
#pragma unroll
    for (int ii = 0; ii < 16; ++ii){
      float4 v = *(const float4*)(f2 + ((size_t)b*NPp + i0 + ii)*256 + 4*q);
      acc[ii] = fma4(w, v, acc[ii]);
    }
  }
  for (int q = 0; q < 128; ++q){
    float4 w = *(const float4*)(wr + 384 + 4*q);
#pragma unroll
    for (int ii = 0; ii < 16; ++ii){
      float4 v = *(const float4*)(f3 + ((size_t)b*NPp + i0 + ii)*512 + 4*q);
      acc[ii] = fma4(w, v, acc[ii]);
    }
  }
#pragma unroll
  for (int ii = 0; ii < 16; ++ii){
    float v = fmaxf(acc[ii], 0.0f);
    atomicMax((int*)(g128 + (size_t)b*128 + t), __float_as_int(v));
  }
}

// ---------------- classifier head ----------------
__global__ __launch_bounds__(256) void k_final(const float* __restrict__ g128,
    const float* __restrict__ W0, const float* __restrict__ W1,
    const float* __restrict__ Wc, const float* __restrict__ bc, float* __restrict__ out){
  __shared__ __align__(16) float g0[128];
  __shared__ __align__(16) float g5[512];
  __shared__ __align__(16) float g2[256];
  int b = blockIdx.x, t = threadIdx.x;
  if (t < 128) g0[t] = g128[(size_t)b*128 + t];
  __syncthreads();
#pragma unroll
  for (int cc = 0; cc < 2; ++cc){
    int c = t + cc*256;
    const float4* wr = (const float4*)(W0 + (size_t)c*128);
    const float4* gv = (const float4*)g0;
    float a = 0.0f;
#pragma unroll
    for (int qq = 0; qq < 32; ++qq) a = fma4(wr[qq], gv[qq], a);
    g5[c] = fmaxf(a, 0.0f);
  }
  __syncthreads();
  {
    const float4* wr = (const float4*)(W1 + (size_t)t*512);
    const float4* gv = (const float4*)g5;
    float a = 0.0f;
    for (int qq = 0; qq < 128; ++qq) a = fma4(wr[qq], gv[qq], a);
    g2[t] = fmaxf(a, 0.0f);
  }
  __syncthreads();
  if (t < 40){
    const float4* wr = (const float4*)(Wc + (size_t)t*256);
    const float4* gv = (const float4*)g2;
    float a = 0.0f;
#pragma unroll
    for (int qq = 0; qq < 64; ++qq) a = fma4(wr[qq], gv[qq], a);
    out[(size_t)b*40 + t] = a + bc[t];
  }
}

extern "C" void kernel_launch(void* const* d_in, const int* in_sizes, int n_in,
                              void* d_out, int out_size, void* d_ws, size_t ws_size,
                              hipStream_t stream){
  (void)in_sizes; (void)n_in; (void)out_size; (void)ws_size;
  const float* points     = (const float*)d_in[0];
  const float* sa_w0      = (const float*)d_in[1];
  const float* sa_w1      = (const float*)d_in[2];
  const float* sa_w2      = (const float*)d_in[3];
  const float* t_ec_w0    = (const float*)d_in[4];
  const float* t_ec_w1    = (const float*)d_in[5];
  const float* t_local_w  = (const float*)d_in[6];
  const float* t_g_w0     = (const float*)d_in[7];
  const float* t_g_w1     = (const float*)d_in[8];
  const float* t_lin_w    = (const float*)d_in[9];
  const float* t_lin_b    = (const float*)d_in[10];
  const float* dg_ec_w0   = (const float*)d_in[11];
  const float* dg_ec_w1   = (const float*)d_in[12];
  const float* dg_ec_w2   = (const float*)d_in[13];
  const float* dg_local_w = (const float*)d_in[14];
  const float* dg_g_w0    = (const float*)d_in[15];
  const float* dg_g_w1    = (const float*)d_in[16];
  const float* cls_w      = (const float*)d_in[17];
  const float* cls_b      = (const float*)d_in[18];
  float* out = (float*)d_out;

  float* ws     = (float*)d_ws;
  float* xyz    = ws;                    // 393216
  float* xnrm   = xyz    + 393216;       // 131072
  float* nxyz   = xnrm   + 131072;       // 24576
  float* feat   = nxyz   + 24576;        // 1048576
  float* x131   = feat   + 1048576;      // 1081344
  float* nrm    = x131   + 1081344;      // 8192
  int*   idx    = (int*)(nrm + 8192);    // 163840
  float* ht     = (float*)(idx + 163840);// 1048576 (reused as f1)
  float* g1024v = ht     + 1048576;      // 32768
  float* f2     = g1024v + 32768;        // 2097152
  float* f3     = f2     + 2097152;      // 4194304
  float* g128v  = f3     + 4194304;      // 4096
  float* wt_t1  = g128v  + 4096;         // 8192   (64x128)
  float* waT0   = wt_t1  + 8192;         // 8384   (131x64)
  float* wbT0   = waT0   + 8384;         // 8384
  float* waD0   = wbT0   + 8384;         // 16768  (131x128)
  float* wbD0   = waD0   + 16768;        // 16768
  float* waD1   = wbD0   + 16768;        // 32768  (128x256)
  float* wbD1   = waD1   + 32768;        // 32768
  float* waD2   = wbD1   + 32768;        // 131072 (256x512)
  float* wbD2   = waD2   + 131072;       // 131072
  float* Ab     = wbD2   + 131072;       // 4194304
  float* Bb     = Ab     + 4194304;      // 4194304
  float* f1 = ht;
  float* xT = f3;                        // alias: xT lives in f3 until k_emax<512> writes f3

  k_prep<<<512, 256, 0, stream>>>(points, xyz, xnrm);
  k_wprep<<<771, 256, 0, stream>>>(t_ec_w0, t_ec_w1, dg_ec_w0, dg_ec_w1, dg_ec_w2,
                                   waT0, wbT0, wt_t1, waD0, wbD0, waD1, wbD1, waD2, wbD2);
  k_fps<<<BB, 256, 0, stream>>>(xyz, nxyz);
  k_sa<<<BB*NPp, 64, 0, stream>>>(xyz, xnrm, nxyz, sa_w0, sa_w1, sa_w2, feat, x131);

  // T-Net branch (x = [feat, new_xyz])
  k_gab<131,64,256><<<512, 256, 0, stream>>>(x131, 132, waT0, wbT0, Ab, Bb, xT);
  k_norm2<131><<<128, 64, 0, stream>>>(xT, nrm);
  k_knn3<131><<<1024, 512, 0, stream>>>(xT, nrm, idx);
  k_tedge3<<<BB*NPp, 128, 0, stream>>>(Ab, Bb, idx, wt_t1, ht);
  k_tpool<<<dim3(BB, 8, 8), 128, 0, stream>>>(ht, t_local_w, g1024v);
  k_trest<<<BB, 256, 0, stream>>>(g1024v, t_g_w0, t_g_w1, t_lin_w, t_lin_b, nxyz, x131);

  // DGCNN layer 1 (x = [feat, xyz_t], 131 dims)
  k_gab<131,128,512><<<512, 512, 0, stream>>>(x131, 132, waD0, wbD0, Ab, Bb, xT);
  k_norm2<131><<<128, 64, 0, stream>>>(xT, nrm);
  k_knn3<131><<<1024, 512, 0, stream>>>(xT, nrm, idx);
  k_emax<128><<<1024, 256, 0, stream>>>(Ab, Bb, idx, f1);
  // layer 2
  k_gab<128,256,512><<<512, 512, 0, stream>>>(f1, 128, waD1, wbD1, Ab, Bb, xT);
  k_norm2<128><<<128, 64, 0, stream>>>(xT, nrm);
  k_knn3<128><<<1024, 512, 0, stream>>>(xT, nrm, idx);
  k_emax<256><<<2048, 256, 0, stream>>>(Ab, Bb, idx, f2);
  // layer 3
  k_gab<256,512,512><<<512, 512, 0, stream>>>(f2, 256, waD2, wbD2, Ab, Bb, xT);
  k_norm2<256><<<128, 64, 0, stream>>>(xT, nrm);
  k_knn3<256><<<1024, 512, 0, stream>>>(xT, nrm, idx);
  k_emax<512><<<4096, 256, 0, stream>>>(Ab, Bb, idx, f3);

  // local conv + global pool + head
  k_dgl<<<dim3(BB, 16), 128, 0, stream>>>(f1, f2, f3, dg_local_w, g128v);
  k_final<<<BB, 256, 0, stream>>>(g128v, dg_g_w0, dg_g_w1, cls_w, cls_b, out);
}

// Round 12
// 1381.847 us; speedup vs baseline: 1.3104x; 1.1242x over previous
//
#include <hip/hip_runtime.h>
#include <math.h>

#define BB 32
#define NN 4096
#define NPp 256
#define NSs 64
#define KC 20

typedef unsigned long long ull;

__device__ __forceinline__ float fma4(const float4 w, const float4 v, float a){
  a = fmaf(w.x, v.x, a); a = fmaf(w.y, v.y, a);
  a = fmaf(w.z, v.z, a); a = fmaf(w.w, v.w, a); return a;
}
__device__ __forceinline__ float4 fma4s(const float4 w, float s, float4 a){
  a.x = fmaf(w.x, s, a.x); a.y = fmaf(w.y, s, a.y);
  a.z = fmaf(w.z, s, a.z); a.w = fmaf(w.w, s, a.w); return a;
}
__device__ __forceinline__ float4 max4(float4 a, float4 b){
  a.x = fmaxf(a.x, b.x); a.y = fmaxf(a.y, b.y);
  a.z = fmaxf(a.z, b.z); a.w = fmaxf(a.w, b.w); return a;
}
__device__ __forceinline__ float4 add4(float4 a, float4 b){
  a.x += b.x; a.y += b.y; a.z += b.z; a.w += b.w; return a;
}

template<int C>
__device__ __forceinline__ int dpp_i(int x){
  return __builtin_amdgcn_update_dpp(x, x, C, 0xf, 0xf, false);
}

// ---------------- unified weight prep (all transposes/splits in one kernel) ----------------
__global__ void k_wprep(const float* __restrict__ t0, const float* __restrict__ t1,
                        const float* __restrict__ d0, const float* __restrict__ d1,
                        const float* __restrict__ d2,
                        float* __restrict__ waT0, float* __restrict__ wbT0,
                        float* __restrict__ wt_t1,
                        float* __restrict__ waD0, float* __restrict__ wbD0,
                        float* __restrict__ waD1, float* __restrict__ wbD1,
                        float* __restrict__ waD2, float* __restrict__ wbD2){
  int i = blockIdx.x*256 + threadIdx.x;
  if (i < 8384){                       // t_ec_w0: [64][262] -> A/B [131][64]
    int m = i >> 6;
    int c = i & 63;
    float bb = t0[(size_t)c*262 + m];
    float dd = t0[(size_t)c*262 + 131 + m];
    waT0[i] = __fsub_rn(bb, dd); wbT0[i] = dd;
    return;
  }
  i -= 8384;
  if (i < 8192){                       // t_ec_w1: [128][64] -> [64][128]
    int m = i >> 7, c = i & 127;
    wt_t1[i] = t1[(size_t)c*64 + m];
    return;
  }
  i -= 8192;
  if (i < 16768){                      // dg_ec_w0: [128][262] -> A/B [131][128]
    int m = i >> 7, c = i & 127;
    float bb = d0[(size_t)c*262 + m];
    float dd = d0[(size_t)c*262 + 131 + m];
    waD0[i] = __fsub_rn(bb, dd); wbD0[i] = dd;
    return;
  }
  i -= 16768;
  if (i < 32768){                      // dg_ec_w1: [256][256] -> A/B [128][256]
    int m = i >> 8, c = i & 255;
    float bb = d1[(size_t)c*256 + m];
    float dd = d1[(size_t)c*256 + 128 + m];
    waD1[i] = __fsub_rn(bb, dd); wbD1[i] = dd;
    return;
  }
  i -= 32768;
  if (i < 131072){                     // dg_ec_w2: [512][512] -> A/B [256][512]
    int m = i >> 9, c = i & 511;
    float bb = d2[(size_t)c*512 + m];
    float dd = d2[(size_t)c*512 + 256 + m];
    waD2[i] = __fsub_rn(bb, dd); wbD2[i] = dd;
  }
}

// ---------------- transpose + point norms ----------------
__global__ void k_prep(const float* __restrict__ pts, float* __restrict__ xyz, float* __restrict__ xnrm){
  int i = blockIdx.x*256 + threadIdx.x;
  if (i >= BB*NN) return;
  int b = i >> 12, n = i & (NN-1);
  float X = pts[(b*3+0)*NN + n];
  float Y = pts[(b*3+1)*NN + n];
  float Z = pts[(b*3+2)*NN + n];
  xyz[i*3+0]=X; xyz[i*3+1]=Y; xyz[i*3+2]=Z;
  xnrm[i] = __fadd_rn(__fadd_rn(__fmul_rn(X,X), __fmul_rn(Y,Y)), __fmul_rn(Z,Z));
}

// ---------------- farthest point sampling: u64 keys, quad_perm combine ----------------
// key = (bits(d) << 32) | (4095 - j): d >= 0 so bit order == float order; j-sets are
// disjoint per wave so cross-wave keys are distinct; max(key) == (max d, min j) exactly.
__global__ __launch_bounds__(256) void k_fps(const float* __restrict__ xyz, float* __restrict__ new_xyz){
  __shared__ __align__(16) float part[2][4][8];  // [par][wave][key_lo,key_hi,x,y,z,...]
  int b = blockIdx.x, t = threadIdx.x;
  int w = t >> 6, lane = t & 63;
  float px[16], py[16], pz[16], dist[16];
#pragma unroll
  for (int q = 0; q < 16; ++q){
    const float* p = xyz + ((size_t)b*NN + q*256 + t)*3;
    px[q] = p[0]; py[q] = p[1]; pz[q] = p[2];
    dist[q] = __builtin_inff();
  }
  const float* p0 = xyz + (size_t)b*NN*3;
  float Px = p0[0], Py = p0[1], Pz = p0[2];
  float sx = 0.f, sy = 0.f, sz = 0.f;   // thread t snapshots iteration t's pivot
  for (int it = 0; it < NPp; ++it){
    if (t == it){ sx = Px; sy = Py; sz = Pz; }
    float bv = -1.0f, bx = 0.f, by = 0.f, bz = 0.f; int bj = 0;
#pragma unroll
    for (int q = 0; q < 16; ++q){
      float dx = __fsub_rn(px[q], Px);
      float dy = __fsub_rn(py[q], Py);
      float dz = __fsub_rn(pz[q], Pz);
      float dd = __fadd_rn(__fadd_rn(__fmul_rn(dx,dx), __fmul_rn(dy,dy)), __fmul_rn(dz,dz));
      float dm = fminf(dist[q], dd);
      dist[q] = dm;
      if (dm > bv){ bv = dm; bj = q*256 + t; bx = px[q]; by = py[q]; bz = pz[q]; }
    }
    // pack (bv >= 0 after loop since dm >= 0 > -1 always taken at q=0)
    ull key = ((ull)__float_as_uint(bv) << 32) | (unsigned)(4095 - bj);
#define FPS_STAGE(C) { \
    unsigned ol = (unsigned)dpp_i<C>((int)(unsigned)key); \
    unsigned oh = (unsigned)dpp_i<C>((int)(unsigned)(key >> 32)); \
    float ox = __int_as_float(dpp_i<C>(__float_as_int(bx))); \
    float oy = __int_as_float(dpp_i<C>(__float_as_int(by))); \
    float oz = __int_as_float(dpp_i<C>(__float_as_int(bz))); \
    ull ok = ((ull)oh << 32) | ol; \
    bool tk = ok > key; \
    key = tk ? ok : key; bx = tk ? ox : bx; by = tk ? oy : by; bz = tk ? oz : bz; }
    FPS_STAGE(0x111) FPS_STAGE(0x112) FPS_STAGE(0x114) FPS_STAGE(0x118)
    FPS_STAGE(0x142) FPS_STAGE(0x143)
#undef FPS_STAGE
    int par = it & 1;
    if (lane == 63){
      float4 v;
      v.x = __uint_as_float((unsigned)key);
      v.y = __uint_as_float((unsigned)(key >> 32));
      v.z = bx; v.w = by;
      *(float4*)&part[par][w][0] = v;
      part[par][w][4] = bz;
    }
    __syncthreads();
    // combine 4 wave-partials: lane&3 indexes the partial; 2 quad_perm stages -> every lane has winner
    {
      const float* pp = &part[par][lane & 3][0];
      float4 v = *(const float4*)pp;
      float vz = pp[4];
      ull k2 = ((ull)__float_as_uint(v.y) << 32) | __float_as_uint(v.x);
      float cx = v.z, cy = v.w, cz = vz;
#define FPS_Q(C) { \
      unsigned ol = (unsigned)dpp_i<C>((int)(unsigned)k2); \
      unsigned oh = (unsigned)dpp_i<C>((int)(unsigned)(k2 >> 32)); \
      float ox = __int_as_float(dpp_i<C>(__float_as_int(cx))); \
      float oy = __int_as_float(dpp_i<C>(__float_as_int(cy))); \
      float oz = __int_as_float(dpp_i<C>(__float_as_int(cz))); \
      ull ok = ((ull)oh << 32) | ol; \
      bool tk = ok > k2; \
      k2 = tk ? ok : k2; cx = tk ? ox : cx; cy = tk ? oy : cy; cz = tk ? oz : cz; }
      FPS_Q(0xB1) FPS_Q(0x4E)
#undef FPS_Q
      Px = cx; Py = cy; Pz = cz;
    }
  }
  // coalesced pivot write-out, once per launch
  {
    float* o = new_xyz + ((size_t)b*NPp + t)*3;
    o[0] = sx; o[1] = sy; o[2] = sz;
  }
}

// ---------------- ball query + SA convs + maxpool (fully-unrolled register arrays) ----------------
__global__ __launch_bounds__(64, 1) void k_sa(const float* __restrict__ xyz, const float* __restrict__ xnrm,
    const float* __restrict__ new_xyz, const float* __restrict__ w0, const float* __restrict__ w1,
    const float* __restrict__ w2, float* __restrict__ feat, float* __restrict__ x131){
  __shared__ int gix[64];
  int bi = blockIdx.x, lane = threadIdx.x;
  int b = bi >> 8;
  const float* q = new_xyz + (size_t)bi*3;
  float qx=q[0], qy=q[1], qz=q[2];
  float nq = __fadd_rn(__fadd_rn(__fmul_rn(qx,qx), __fmul_rn(qy,qy)), __fmul_rn(qz,qz));
  int cnt = 0;
  for (int base = 0; base < NN && cnt < NSs; base += 256){
#pragma unroll
    for (int u = 0; u < 4; ++u){
      int j = base + u*64 + lane;
      const float* p = xyz + ((size_t)b*NN + j)*3;
      float dot = __fadd_rn(__fadd_rn(__fmul_rn(qx,p[0]), __fmul_rn(qy,p[1])), __fmul_rn(qz,p[2]));
      float d2 = __fsub_rn(__fadd_rn(nq, xnrm[b*NN + j]), __fmul_rn(2.0f, dot));
      bool inb = d2 < 0.04f;
      unsigned long long m = __ballot(inb);
      int pos = cnt + (int)__popcll(m & ((1ull << lane) - 1ull));
      if (inb && pos < NSs) gix[pos] = j;
      cnt += (int)__popcll(m);
    }
  }
  __syncthreads();
  int g0 = gix[0];
  if (lane >= cnt) gix[lane] = g0;
  __syncthreads();
  float h1[64];
  {
    int gj = gix[lane];
    const float* p = xyz + ((size_t)b*NN + gj)*3;
    float px = p[0]-qx, py = p[1]-qy, pz = p[2]-qz;
#pragma unroll
    for (int c = 0; c < 64; ++c) h1[c] = 0.0f;
#pragma unroll
    for (int half = 0; half < 2; ++half){
      float h0h[32];
#pragma unroll
      for (int mm = 0; mm < 32; ++mm){
        int c = half*32 + mm;
        float a = fmaf(w0[c*3+2], pz, fmaf(w0[c*3+1], py, w0[c*3]*px));
        h0h[mm] = fmaxf(a, 0.0f);
      }
#pragma unroll
      for (int c = 0; c < 64; ++c){
        const float4* wr = (const float4*)(w1 + c*64 + half*32);
        float a = h1[c];
#pragma unroll
        for (int qq = 0; qq < 8; ++qq){
          float4 w = wr[qq];
          a = fmaf(w.x, h0h[4*qq+0], a);
          a = fmaf(w.y, h0h[4*qq+1], a);
          a = fmaf(w.z, h0h[4*qq+2], a);
          a = fmaf(w.w, h0h[4*qq+3], a);
        }
        h1[c] = a;
      }
    }
#pragma unroll
    for (int c = 0; c < 64; ++c) h1[c] = fmaxf(h1[c], 0.0f);
  }
  float m0 = 0.0f, m1 = 0.0f;
#pragma unroll 2
  for (int c = 0; c < 128; ++c){
    const float4* wr = (const float4*)(w2 + (size_t)c*64);
    float a = 0.0f;
#pragma unroll
    for (int qq = 0; qq < 16; ++qq){
      float4 w = wr[qq];
      a = fmaf(w.x, h1[4*qq+0], a);
      a = fmaf(w.y, h1[4*qq+1], a);
      a = fmaf(w.z, h1[4*qq+2], a);
      a = fmaf(w.w, h1[4*qq+3], a);
    }
    a = fmaxf(a, 0.0f);
#define SA_MAX(C) { float o = __int_as_float(dpp_i<C>(__float_as_int(a))); a = fmaxf(a, o); }
    SA_MAX(0x111) SA_MAX(0x112) SA_MAX(0x114) SA_MAX(0x118) SA_MAX(0x142) SA_MAX(0x143)
#undef SA_MAX
    float r = __int_as_float(__builtin_amdgcn_readlane(__float_as_int(a), 63));
    if (c < 64){ if (lane == c) m0 = r; }
    else       { if (lane == c - 64) m1 = r; }
  }
  feat[(size_t)bi*128 + lane]      = m0;
  feat[(size_t)bi*128 + 64 + lane] = m1;
  x131[(size_t)bi*132 + lane]      = m0;
  x131[(size_t)bi*132 + 64 + lane] = m1;
  if (lane < 3) x131[(size_t)bi*132 + 128 + lane] = (lane==0)?qx:((lane==1)?qy:qz);
}

// ---------------- kNN: distances in registers, u64-DPP selection, no selection LDS ----------------
template<int CIN>
__global__ __launch_bounds__(512) void k_knn3(const float* __restrict__ xT,
    const float* __restrict__ nrm, int* __restrict__ idxo){
  __shared__ __align__(16) float sch[16*256];
  int bi = blockIdx.x, t = threadIdx.x;
  int w = t >> 6, lane = t & 63;
  int b = bi >> 5;
  int coli = (bi & 31)*8 + w;
  const float* xb = xT + (size_t)b*CIN*256;
  float d0=0.f, d1=0.f, d2=0.f, d3=0.f;
  for (int m0 = 0; m0 < CIN; m0 += 16){
    int mc = (CIN - m0 < 16) ? (CIN - m0) : 16;
    for (int i = t; i < mc*64; i += 512){
      int mm = i >> 6, c4 = i & 63;
      *(float4*)(sch + mm*256 + c4*4) = *(const float4*)(xb + (size_t)(m0+mm)*256 + c4*4);
    }
    __syncthreads();
    for (int mm = 0; mm < mc; ++mm){
      float xm = sch[mm*256 + coli];
      float4 v = *(const float4*)(sch + mm*256 + 4*lane);
      d0 = fmaf(v.x, xm, d0); d1 = fmaf(v.y, xm, d1);
      d2 = fmaf(v.z, xm, d2); d3 = fmaf(v.w, xm, d3);
    }
    __syncthreads();
  }
  float ni = nrm[b*256 + coli];
  float4 dv;
  {
    int j0 = 4*lane;
    dv.x = __fsub_rn(__fadd_rn(ni, nrm[b*256 + j0+0]), __fmul_rn(2.0f, d0));
    dv.y = __fsub_rn(__fadd_rn(ni, nrm[b*256 + j0+1]), __fmul_rn(2.0f, d1));
    dv.z = __fsub_rn(__fadd_rn(ni, nrm[b*256 + j0+2]), __fmul_rn(2.0f, d2));
    dv.w = __fsub_rn(__fadd_rn(ni, nrm[b*256 + j0+3]), __fmul_rn(2.0f, d3));
  }
  for (int r = 0; r < KC; ++r){
    float bv = 3.4e38f; int bj = NPp;
    if (dv.x < bv){ bv = dv.x; bj = 4*lane+0; }
    if (dv.y < bv){ bv = dv.y; bj = 4*lane+1; }
    if (dv.z < bv){ bv = dv.z; bj = 4*lane+2; }
    if (dv.w < bv){ bv = dv.w; bj = 4*lane+3; }
    // sign-transform so uint order == float order (d may be slightly negative)
    unsigned xf = __float_as_uint(bv);
    xf = (xf & 0x80000000u) ? ~xf : (xf | 0x80000000u);
    ull key = ((ull)xf << 32) | (unsigned)bj;   // min-reduce => (min d, min j)
#define KN_STAGE(C) { \
    unsigned ol = (unsigned)dpp_i<C>((int)(unsigned)key); \
    unsigned oh = (unsigned)dpp_i<C>((int)(unsigned)(key >> 32)); \
    ull ok = ((ull)oh << 32) | ol; \
    if (ok < key) key = ok; }
    KN_STAGE(0x111) KN_STAGE(0x112) KN_STAGE(0x114) KN_STAGE(0x118)
    KN_STAGE(0x142) KN_STAGE(0x143)
#undef KN_STAGE
    int bjw = __builtin_amdgcn_readlane((int)(unsigned)key, 63);
    if (lane == 0) idxo[((size_t)b*256 + coli)*KC + r] = bjw;
    if ((bjw >> 2) == lane){
      int e = bjw & 3;
      if      (e == 0) dv.x = 3.0e38f;
      else if (e == 1) dv.y = 3.0e38f;
      else if (e == 2) dv.z = 3.0e38f;
      else             dv.w = 3.0e38f;
    }
  }
}

// ---------------- per-point dual GEMM + fused xT transpose + fused norms ----------------
template<int CIN, int COUT, int T>
__global__ __launch_bounds__(T) void k_gab(const float* __restrict__ x, int xstride,
    const float* __restrict__ wA, const float* __restrict__ wB,
    float* __restrict__ A, float* __restrict__ B, float* __restrict__ xT,
    float* __restrict__ nrm){
  constexpr int PC  = CIN + 1;
  constexpr int G   = COUT/4;
  constexpr int RS  = T/G;
  constexpr int RPT = 16/RS;
  __shared__ float xsh[16*PC];
  int bi = blockIdx.x, t = threadIdx.x;
  int g = t % G, rs = t / G;
  int i0 = bi*16;
  for (int i = t; i < 16*CIN; i += T){
    int r = i / CIN, m = i - r*CIN;
    xsh[r*PC + m] = x[(size_t)(i0+r)*xstride + m];
  }
  __syncthreads();
  {
    int bb = i0 >> 8, col0 = i0 & 255;
    float* xTb = xT + (size_t)bb*CIN*256 + col0;
    for (int i = t; i < 16*CIN; i += T){
      int m = i >> 4, r = i & 15;
      xTb[m*256 + r] = xsh[r*PC + m];
    }
  }
  // fused point norms (same ascending-m strict chain as the old k_norm2)
  if (t < 16){
    const float* xr = xsh + t*PC;
    float a = 0.0f;
    for (int m = 0; m < CIN; ++m) a = __fadd_rn(a, __fmul_rn(xr[m], xr[m]));
    nrm[i0 + t] = a;
  }
  float4 accA[RPT], accB[RPT];
#pragma unroll
  for (int rr = 0; rr < RPT; ++rr){
    accA[rr] = make_float4(0.f,0.f,0.f,0.f);
    accB[rr] = make_float4(0.f,0.f,0.f,0.f);
  }
  for (int m = 0; m < CIN; ++m){
    float4 wa = *(const float4*)(wA + (size_t)m*COUT + 4*g);
    float4 wb = *(const float4*)(wB + (size_t)m*COUT + 4*g);
#pragma unroll
    for (int rr = 0; rr < RPT; ++rr){
      float xv = xsh[(rs + rr*RS)*PC + m];
      accA[rr] = fma4s(wa, xv, accA[rr]);
      accB[rr] = fma4s(wb, xv, accB[rr]);
    }
  }
#pragma unroll
  for (int rr = 0; rr < RPT; ++rr){
    int r = i0 + rs + rr*RS;
    *(float4*)(A + (size_t)r*COUT + 4*g) = accA[rr];
    *(float4*)(B + (size_t)r*COUT + 4*g) = accB[rr];
  }
}

// ---------------- edge epilogue: out[i][c] = max_k relu(A[i][c] + B[j_ik][c]) ----------------
template<int COUT>
__global__ __launch_bounds__(256) void k_emax(const float* __restrict__ A, const float* __restrict__ Bm,
    const int* __restrict__ idx, float* __restrict__ out){
  constexpr int GT = COUT/4;
  constexpr int NC = 256/GT;
  __shared__ int js[NC*KC];
  int bi = blockIdx.x, t = threadIdx.x;
  int li = t / GT, c4 = (t % GT)*4;
  int ci = bi*NC + li;
  int rb = (ci >> 8) << 8;
  if (t < NC*KC) js[t] = idx[(size_t)bi*NC*KC + t];
  __syncthreads();
  float4 a = *(const float4*)(A + (size_t)ci*COUT + c4);
  float4 p = make_float4(0.f,0.f,0.f,0.f);
#pragma unroll
  for (int k = 0; k < KC; ++k){
    int j = js[li*KC + k];
    float4 b = *(const float4*)(Bm + (size_t)(rb + j)*COUT + c4);
    p = max4(p, add4(a, b));
  }
  *(float4*)(out + (size_t)ci*COUT + c4) = p;
}

// ---------------- T-Net edge: h0 = relu(A0+B0) then 64->128 conv + k-maxpool ----------------
__global__ __launch_bounds__(128) void k_tedge3(const float* __restrict__ A0, const float* __restrict__ B0,
    const int* __restrict__ idx, const float* __restrict__ wt1, float* __restrict__ out){
  __shared__ __align__(16) float h0s[20*68];
  __shared__ __align__(16) float smax[4*128];
  __shared__ int js[KC];
  int bi = blockIdx.x, t = threadIdx.x;
  int cg = t & 31, kg = t >> 5, k0 = kg*5;
  int rb = (bi >> 8) << 8;
  if (t < KC) js[t] = idx[(size_t)bi*KC + t];
  __syncthreads();
  for (int i = t; i < 20*64; i += 128){
    int k = i >> 6, c = i & 63;
    float v = A0[(size_t)bi*64 + c] + B0[(size_t)(rb + js[k])*64 + c];
    h0s[k*68 + c] = fmaxf(v, 0.0f);
  }
  __syncthreads();
  float4 b2[5];
#pragma unroll
  for (int kk = 0; kk < 5; ++kk) b2[kk] = make_float4(0.f,0.f,0.f,0.f);
  for (int m4 = 0; m4 < 16; ++m4){
    float4 e[5];
#pragma unroll
    for (int kk = 0; kk < 5; ++kk) e[kk] = *(const float4*)(h0s + (k0+kk)*68 + 4*m4);
#pragma unroll
    for (int mm = 0; mm < 4; ++mm){
      float4 w = *(const float4*)(wt1 + (4*m4+mm)*128 + 4*cg);
#pragma unroll
      for (int kk = 0; kk < 5; ++kk){
        float ev = (mm==0)?e[kk].x:((mm==1)?e[kk].y:((mm==2)?e[kk].z:e[kk].w));
        b2[kk] = fma4s(w, ev, b2[kk]);
      }
    }
  }
  float4 p = make_float4(0.f,0.f,0.f,0.f);
#pragma unroll
  for (int kk = 0; kk < 5; ++kk) p = max4(p, b2[kk]);
  *(float4*)(smax + kg*128 + 4*cg) = p;
  __syncthreads();
  if (kg == 0){
    float4 r = *(const float4*)(smax + 4*cg);
#pragma unroll
    for (int g = 1; g < 4; ++g) r = max4(r, *(const float4*)(smax + g*128 + 4*cg));
    *(float4*)(out + (size_t)bi*128 + 4*cg) = r;
  }
}

// ---------------- T-Net 128->1024 + pool: 8 point-chunks, atomicMax combine ----------------
__global__ __launch_bounds__(128) void k_tpool(const float* __restrict__ h, const float* __restrict__ W,
    float* __restrict__ g1024){
  int b = blockIdx.x, t = threadIdx.x;
  int c = blockIdx.y*128 + t;
  int i0 = blockIdx.z*32;
  float4 w[32];
#pragma unroll
  for (int qq = 0; qq < 32; ++qq) w[qq] = *(const float4*)(W + (size_t)c*128 + 4*qq);
  const float* hb = h + (size_t)b*NPp*128;
  float mx = 0.0f;   // seed 0 = relu; partials >=0 so int-compare atomicMax is exact
  for (int i = i0; i < i0 + 32; ++i){
    const float4* hr = (const float4*)(hb + (size_t)i*128);
    float a = 0.0f;
#pragma unroll
    for (int qq = 0; qq < 32; ++qq) a = fma4(w[qq], hr[qq], a);
    mx = fmaxf(mx, a);
  }
  atomicMax((int*)(g1024 + (size_t)b*1024 + c), __float_as_int(mx));
}

// ---------------- T-Net MLP + 3x3 transform applied to new_xyz ----------------
__global__ __launch_bounds__(256) void k_trest(const float* __restrict__ g1024,
    const float* __restrict__ Wg0, const float* __restrict__ Wg1,
    const float* __restrict__ Wl, const float* __restrict__ bl,
    const float* __restrict__ new_xyz, float* __restrict__ x131){
  __shared__ __align__(16) float g1[1024];
  __shared__ __align__(16) float g5[512];
  __shared__ __align__(16) float g2[256];
  __shared__ float tm[12];
  int b = blockIdx.x, t = threadIdx.x;
  for (int m = t; m < 1024; m += 256) g1[m] = g1024[(size_t)b*1024 + m];
  __syncthreads();
#pragma unroll
  for (int cc = 0; cc < 2; ++cc){
    int c = t + cc*256;
    const float4* wr = (const float4*)(Wg0 + (size_t)c*1024);
    const float4* gv = (const float4*)g1;
    float a = 0.0f;
    for (int qq = 0; qq < 256; ++qq) a = fma4(wr[qq], gv[qq], a);
    g5[c] = fmaxf(a, 0.0f);
  }
  __syncthreads();
  {
    const float4* wr = (const float4*)(Wg1 + (size_t)t*512);
    const float4* gv = (const float4*)g5;
    float a = 0.0f;
    for (int qq = 0; qq < 128; ++qq) a = fma4(wr[qq], gv[qq], a);
    g2[t] = fmaxf(a, 0.0f);
  }
  __syncthreads();
  if (t < 9){
    const float4* wr = (const float4*)(Wl + (size_t)t*256);
    const float4* gv = (const float4*)g2;
    float a = 0.0f;
#pragma unroll
    for (int qq = 0; qq < 64; ++qq) a = fma4(wr[qq], gv[qq], a);
    a += bl[t];
    if (t == 0 || t == 4 || t == 8) a += 1.0f;
    tm[t] = a;
  }
  __syncthreads();
  {
    const float* nx = new_xyz + ((size_t)b*NPp + t)*3;
    float X = nx[0], Y = nx[1], Z = nx[2];
#pragma unroll
    for (int i = 0; i < 3; ++i){
      float v = __fadd_rn(__fadd_rn(__fmul_rn(tm[i*3+0], X), __fmul_rn(tm[i*3+1], Y)), __fmul_rn(tm[i*3+2], Z));
      x131[((size_t)b*NPp + t)*132 + 128 + i] = v;
    }
  }
}

// ---------------- 896->128 conv + global max pool (atomicMax; poison is negative int) ----------------
__global__ __launch_bounds__(128) void k_dgl(const float* __restrict__ f1, const float* __restrict__ f2,
    const float* __restrict__ f3, const float* __restrict__ W, float* __restrict__ g128){
  int b = blockIdx.x, t = threadIdx.x;
  int i0 = blockIdx.y * 16;
  const float* wr = W + (size_t)t*896;
  float acc[16];
#pragma unroll
  for (int ii = 0; ii < 16; ++ii) acc[ii] = 0.0f;
  for (int q = 0; q < 32; ++q){
    float4 w = *(const float4*)(wr + 4*q);
#pragma unroll
    for (int ii = 0; ii < 16; ++ii){
      float4 v = *(const float4*)(f1 + ((size_t)b*NPp + i0 + ii)*128 + 4*q);
      acc[ii] = fma4(w, v, acc[ii]);
    }
  }
  for (int q = 0; q < 64; ++q){
    float4 w = *(const float4*)(wr + 128 + 4*q);
#pragma unroll
    for (int ii = 0; ii < 16; ++ii){
      float4 v = *(const float4*)(f2 + ((size_t)b*NPp + i0 + ii)*256 + 4*q);
      acc[ii] = fma4(w, v, acc[ii]);
    }
  }
  for (int q = 0; q < 128; ++q){
    float4 w = *(const float4*)(wr + 384 + 4*q);
#pragma unroll
    for (int ii = 0; ii < 16; ++ii){
      float4 v = *(const float4*)(f3 + ((size_t)b*NPp + i0 + ii)*512 + 4*q);
      acc[ii] = fma4(w, v, acc[ii]);
    }
  }
#pragma unroll
  for (int ii = 0; ii < 16; ++ii){
    float v = fmaxf(acc[ii], 0.0f);
    atomicMax((int*)(g128 + (size_t)b*128 + t), __float_as_int(v));
  }
}

// ---------------- classifier head ----------------
__global__ __launch_bounds__(256) void k_final(const float* __restrict__ g128,
    const float* __restrict__ W0, const float* __restrict__ W1,
    const float* __restrict__ Wc, const float* __restrict__ bc, float* __restrict__ out){
  __shared__ __align__(16) float g0[128];
  __shared__ __align__(16) float g5[512];
  __shared__ __align__(16) float g2[256];
  int b = blockIdx.x, t = threadIdx.x;
  if (t < 128) g0[t] = g128[(size_t)b*128 + t];
  __syncthreads();
#pragma unroll
  for (int cc = 0; cc < 2; ++cc){
    int c = t + cc*256;
    const float4* wr = (const float4*)(W0 + (size_t)c*128);
    const float4* gv = (const float4*)g0;
    float a = 0.0f;
#pragma unroll
    for (int qq = 0; qq < 32; ++qq) a = fma4(wr[qq], gv[qq], a);
    g5[c] = fmaxf(a, 0.0f);
  }
  __syncthreads();
  {
    const float4* wr = (const float4*)(W1 + (size_t)t*512);
    const float4* gv = (const float4*)g5;
    float a = 0.0f;
    for (int qq = 0; qq < 128; ++qq) a = fma4(wr[qq], gv[qq], a);
    g2[t] = fmaxf(a, 0.0f);
  }
  __syncthreads();
  if (t < 40){
    const float4* wr = (const float4*)(Wc + (size_t)t*256);
    const float4* gv = (const float4*)g2;
    float a = 0.0f;
#pragma unroll
    for (int qq = 0; qq < 64; ++qq) a = fma4(wr[qq], gv[qq], a);
    out[(size_t)b*40 + t] = a + bc[t];
  }
}

extern "C" void kernel_launch(void* const* d_in, const int* in_sizes, int n_in,
                              void* d_out, int out_size, void* d_ws, size_t ws_size,
                              hipStream_t stream){
  (void)in_sizes; (void)n_in; (void)out_size; (void)ws_size;
  const float* points     = (const float*)d_in[0];
  const float* sa_w0      = (const float*)d_in[1];
  const float* sa_w1      = (const float*)d_in[2];
  const float* sa_w2      = (const float*)d_in[3];
  const float* t_ec_w0    = (const float*)d_in[4];
  const float* t_ec_w1    = (const float*)d_in[5];
  const float* t_local_w  = (const float*)d_in[6];
  const float* t_g_w0     = (const float*)d_in[7];
  const float* t_g_w1     = (const float*)d_in[8];
  const float* t_lin_w    = (const float*)d_in[9];
  const float* t_lin_b    = (const float*)d_in[10];
  const float* dg_ec_w0   = (const float*)d_in[11];
  const float* dg_ec_w1   = (const float*)d_in[12];
  const float* dg_ec_w2   = (const float*)d_in[13];
  const float* dg_local_w = (const float*)d_in[14];
  const float* dg_g_w0    = (const float*)d_in[15];
  const float* dg_g_w1    = (const float*)d_in[16];
  const float* cls_w      = (const float*)d_in[17];
  const float* cls_b      = (const float*)d_in[18];
  float* out = (float*)d_out;

  float* ws     = (float*)d_ws;
  float* xyz    = ws;                    // 393216
  float* xnrm   = xyz    + 393216;       // 131072
  float* nxyz   = xnrm   + 131072;       // 24576
  float* feat   = nxyz   + 24576;        // 1048576
  float* x131   = feat   + 1048576;      // 1081344
  float* nrm    = x131   + 1081344;      // 8192
  int*   idx    = (int*)(nrm + 8192);    // 163840
  float* ht     = (float*)(idx + 163840);// 1048576 (reused as f1)
  float* g1024v = ht     + 1048576;      // 32768
  float* f2     = g1024v + 32768;        // 2097152
  float* f3     = f2     + 2097152;      // 4194304
  float* g128v  = f3     + 4194304;      // 4096
  float* wt_t1  = g128v  + 4096;         // 8192   (64x128)
  float* waT0   = wt_t1  + 8192;         // 8384   (131x64)
  float* wbT0   = waT0   + 8384;         // 8384
  float* waD0   = wbT0   + 8384;         // 16768  (131x128)
  float* wbD0   = waD0   + 16768;        // 16768
  float* waD1   = wbD0   + 16768;        // 32768  (128x256)
  float* wbD1   = waD1   + 32768;        // 32768
  float* waD2   = wbD1   + 32768;        // 131072 (256x512)
  float* wbD2   = waD2   + 131072;       // 131072
  float* Ab     = wbD2   + 131072;       // 4194304
  float* Bb     = Ab     + 4194304;      // 4194304
  float* f1 = ht;
  float* xT = f3;                        // alias: xT lives in f3 until k_emax<512> writes f3

  k_prep<<<512, 256, 0, stream>>>(points, xyz, xnrm);
  k_wprep<<<771, 256, 0, stream>>>(t_ec_w0, t_ec_w1, dg_ec_w0, dg_ec_w1, dg_ec_w2,
                                   waT0, wbT0, wt_t1, waD0, wbD0, waD1, wbD1, waD2, wbD2);
  k_fps<<<BB, 256, 0, stream>>>(xyz, nxyz);
  k_sa<<<BB*NPp, 64, 0, stream>>>(xyz, xnrm, nxyz, sa_w0, sa_w1, sa_w2, feat, x131);

  // T-Net branch (x = [feat, new_xyz])
  k_gab<131,64,256><<<512, 256, 0, stream>>>(x131, 132, waT0, wbT0, Ab, Bb, xT, nrm);
  k_knn3<131><<<1024, 512, 0, stream>>>(xT, nrm, idx);
  k_tedge3<<<BB*NPp, 128, 0, stream>>>(Ab, Bb, idx, wt_t1, ht);
  k_tpool<<<dim3(BB, 8, 8), 128, 0, stream>>>(ht, t_local_w, g1024v);
  k_trest<<<BB, 256, 0, stream>>>(g1024v, t_g_w0, t_g_w1, t_lin_w, t_lin_b, nxyz, x131);

  // DGCNN layer 1 (x = [feat, xyz_t], 131 dims)
  k_gab<131,128,512><<<512, 512, 0, stream>>>(x131, 132, waD0, wbD0, Ab, Bb, xT, nrm);
  k_knn3<131><<<1024, 512, 0, stream>>>(xT, nrm, idx);
  k_emax<128><<<1024, 256, 0, stream>>>(Ab, Bb, idx, f1);
  // layer 2
  k_gab<128,256,512><<<512, 512, 0, stream>>>(f1, 128, waD1, wbD1, Ab, Bb, xT, nrm);
  k_knn3<128><<<1024, 512, 0, stream>>>(xT, nrm, idx);
  k_emax<256><<<2048, 256, 0, stream>>>(Ab, Bb, idx, f2);
  // layer 3
  k_gab<256,512,512><<<512, 512, 0, stream>>>(f2, 256, waD2, wbD2, Ab, Bb, xT, nrm);
  k_knn3<256><<<1024, 512, 0, stream>>>(xT, nrm, idx);
  k_emax<512><<<4096, 256, 0, stream>>>(Ab, Bb, idx, f3);

  // local conv + global pool + head
  k_dgl<<<dim3(BB, 16), 128, 0, stream>>>(f1, f2, f3, dg_local_w, g128v);
  k_final<<<BB, 256, 0, stream>>>(g128v, dg_g_w0, dg_g_w1, cls_w, cls_b, out);
}

// Round 13
// 1375.721 us; speedup vs baseline: 1.3162x; 1.0045x over previous
//
#include <hip/hip_runtime.h>
#include <math.h>

#define BB 32
#define NN 4096
#define NPp 256
#define NSs 64
#define KC 20

typedef unsigned long long ull;

__device__ __forceinline__ float fma4(const float4 w, const float4 v, float a){
  a = fmaf(w.x, v.x, a); a = fmaf(w.y, v.y, a);
  a = fmaf(w.z, v.z, a); a = fmaf(w.w, v.w, a); return a;
}
__device__ __forceinline__ float4 fma4s(const float4 w, float s, float4 a){
  a.x = fmaf(w.x, s, a.x); a.y = fmaf(w.y, s, a.y);
  a.z = fmaf(w.z, s, a.z); a.w = fmaf(w.w, s, a.w); return a;
}
__device__ __forceinline__ float4 max4(float4 a, float4 b){
  a.x = fmaxf(a.x, b.x); a.y = fmaxf(a.y, b.y);
  a.z = fmaxf(a.z, b.z); a.w = fmaxf(a.w, b.w); return a;
}
__device__ __forceinline__ float4 add4(float4 a, float4 b){
  a.x += b.x; a.y += b.y; a.z += b.z; a.w += b.w; return a;
}

template<int C>
__device__ __forceinline__ int dpp_i(int x){
  return __builtin_amdgcn_update_dpp(x, x, C, 0xf, 0xf, false);
}

// ---------------- unified weight prep (all transposes/splits in one kernel) ----------------
__global__ void k_wprep(const float* __restrict__ t0, const float* __restrict__ t1,
                        const float* __restrict__ d0, const float* __restrict__ d1,
                        const float* __restrict__ d2,
                        float* __restrict__ waT0, float* __restrict__ wbT0,
                        float* __restrict__ wt_t1,
                        float* __restrict__ waD0, float* __restrict__ wbD0,
                        float* __restrict__ waD1, float* __restrict__ wbD1,
                        float* __restrict__ waD2, float* __restrict__ wbD2){
  int i = blockIdx.x*256 + threadIdx.x;
  if (i < 8384){                       // t_ec_w0: [64][262] -> A/B [131][64]
    int m = i >> 6;
    int c = i & 63;
    float bb = t0[(size_t)c*262 + m];
    float dd = t0[(size_t)c*262 + 131 + m];
    waT0[i] = __fsub_rn(bb, dd); wbT0[i] = dd;
    return;
  }
  i -= 8384;
  if (i < 8192){                       // t_ec_w1: [128][64] -> [64][128]
    int m = i >> 7, c = i & 127;
    wt_t1[i] = t1[(size_t)c*64 + m];
    return;
  }
  i -= 8192;
  if (i < 16768){                      // dg_ec_w0: [128][262] -> A/B [131][128]
    int m = i >> 7, c = i & 127;
    float bb = d0[(size_t)c*262 + m];
    float dd = d0[(size_t)c*262 + 131 + m];
    waD0[i] = __fsub_rn(bb, dd); wbD0[i] = dd;
    return;
  }
  i -= 16768;
  if (i < 32768){                      // dg_ec_w1: [256][256] -> A/B [128][256]
    int m = i >> 8, c = i & 255;
    float bb = d1[(size_t)c*256 + m];
    float dd = d1[(size_t)c*256 + 128 + m];
    waD1[i] = __fsub_rn(bb, dd); wbD1[i] = dd;
    return;
  }
  i -= 32768;
  if (i < 131072){                     // dg_ec_w2: [512][512] -> A/B [256][512]
    int m = i >> 9, c = i & 511;
    float bb = d2[(size_t)c*512 + m];
    float dd = d2[(size_t)c*512 + 256 + m];
    waD2[i] = __fsub_rn(bb, dd); wbD2[i] = dd;
  }
}

// ---------------- transpose + point norms ----------------
__global__ void k_prep(const float* __restrict__ pts, float* __restrict__ xyz, float* __restrict__ xnrm){
  int i = blockIdx.x*256 + threadIdx.x;
  if (i >= BB*NN) return;
  int b = i >> 12, n = i & (NN-1);
  float X = pts[(b*3+0)*NN + n];
  float Y = pts[(b*3+1)*NN + n];
  float Z = pts[(b*3+2)*NN + n];
  xyz[i*3+0]=X; xyz[i*3+1]=Y; xyz[i*3+2]=Z;
  xnrm[i] = __fadd_rn(__fadd_rn(__fmul_rn(X,X), __fmul_rn(Y,Y)), __fmul_rn(Z,Z));
}

// ---------------- farthest point sampling: u64 keys, quad_perm combine ----------------
__global__ __launch_bounds__(256) void k_fps(const float* __restrict__ xyz, float* __restrict__ new_xyz){
  __shared__ __align__(16) float part[2][4][8];
  int b = blockIdx.x, t = threadIdx.x;
  int w = t >> 6, lane = t & 63;
  float px[16], py[16], pz[16], dist[16];
#pragma unroll
  for (int q = 0; q < 16; ++q){
    const float* p = xyz + ((size_t)b*NN + q*256 + t)*3;
    px[q] = p[0]; py[q] = p[1]; pz[q] = p[2];
    dist[q] = __builtin_inff();
  }
  const float* p0 = xyz + (size_t)b*NN*3;
  float Px = p0[0], Py = p0[1], Pz = p0[2];
  float sx = 0.f, sy = 0.f, sz = 0.f;
  for (int it = 0; it < NPp; ++it){
    if (t == it){ sx = Px; sy = Py; sz = Pz; }
    float bv = -1.0f, bx = 0.f, by = 0.f, bz = 0.f; int bj = 0;
#pragma unroll
    for (int q = 0; q < 16; ++q){
      float dx = __fsub_rn(px[q], Px);
      float dy = __fsub_rn(py[q], Py);
      float dz = __fsub_rn(pz[q], Pz);
      float dd = __fadd_rn(__fadd_rn(__fmul_rn(dx,dx), __fmul_rn(dy,dy)), __fmul_rn(dz,dz));
      float dm = fminf(dist[q], dd);
      dist[q] = dm;
      if (dm > bv){ bv = dm; bj = q*256 + t; bx = px[q]; by = py[q]; bz = pz[q]; }
    }
    ull key = ((ull)__float_as_uint(bv) << 32) | (unsigned)(4095 - bj);
#define FPS_STAGE(C) { \
    unsigned ol = (unsigned)dpp_i<C>((int)(unsigned)key); \
    unsigned oh = (unsigned)dpp_i<C>((int)(unsigned)(key >> 32)); \
    float ox = __int_as_float(dpp_i<C>(__float_as_int(bx))); \
    float oy = __int_as_float(dpp_i<C>(__float_as_int(by))); \
    float oz = __int_as_float(dpp_i<C>(__float_as_int(bz))); \
    ull ok = ((ull)oh << 32) | ol; \
    bool tk = ok > key; \
    key = tk ? ok : key; bx = tk ? ox : bx; by = tk ? oy : by; bz = tk ? oz : bz; }
    FPS_STAGE(0x111) FPS_STAGE(0x112) FPS_STAGE(0x114) FPS_STAGE(0x118)
    FPS_STAGE(0x142) FPS_STAGE(0x143)
#undef FPS_STAGE
    int par = it & 1;
    if (lane == 63){
      float4 v;
      v.x = __uint_as_float((unsigned)key);
      v.y = __uint_as_float((unsigned)(key >> 32));
      v.z = bx; v.w = by;
      *(float4*)&part[par][w][0] = v;
      part[par][w][4] = bz;
    }
    __syncthreads();
    {
      const float* pp = &part[par][lane & 3][0];
      float4 v = *(const float4*)pp;
      float vz = pp[4];
      ull k2 = ((ull)__float_as_uint(v.y) << 32) | __float_as_uint(v.x);
      float cx = v.z, cy = v.w, cz = vz;
#define FPS_Q(C) { \
      unsigned ol = (unsigned)dpp_i<C>((int)(unsigned)k2); \
      unsigned oh = (unsigned)dpp_i<C>((int)(unsigned)(k2 >> 32)); \
      float ox = __int_as_float(dpp_i<C>(__float_as_int(cx))); \
      float oy = __int_as_float(dpp_i<C>(__float_as_int(cy))); \
      float oz = __int_as_float(dpp_i<C>(__float_as_int(cz))); \
      ull ok = ((ull)oh << 32) | ol; \
      bool tk = ok > k2; \
      k2 = tk ? ok : k2; cx = tk ? ox : cx; cy = tk ? oy : cy; cz = tk ? oz : cz; }
      FPS_Q(0xB1) FPS_Q(0x4E)
#undef FPS_Q
      Px = cx; Py = cy; Pz = cz;
    }
  }
  {
    float* o = new_xyz + ((size_t)b*NPp + t)*3;
    o[0] = sx; o[1] = sy; o[2] = sz;
  }
}

// ---------------- ball query + SA convs + maxpool: 4 centroids/block (wave = centroid) ----------------
__global__ __launch_bounds__(256, 1) void k_sa(const float* __restrict__ xyz, const float* __restrict__ xnrm,
    const float* __restrict__ new_xyz, const float* __restrict__ w0, const float* __restrict__ w1,
    const float* __restrict__ w2, float* __restrict__ feat, float* __restrict__ x131){
  __shared__ int gix[4][64];
  int t = threadIdx.x;
  int wv = t >> 6, lane = t & 63;
  int bi = blockIdx.x*4 + wv;
  int b = bi >> 8;
  int* gw = gix[wv];
  const float* q = new_xyz + (size_t)bi*3;
  float qx=q[0], qy=q[1], qz=q[2];
  float nq = __fadd_rn(__fadd_rn(__fmul_rn(qx,qx), __fmul_rn(qy,qy)), __fmul_rn(qz,qz));
  int cnt = 0;
  for (int base = 0; base < NN && cnt < NSs; base += 256){
#pragma unroll
    for (int u = 0; u < 4; ++u){
      int j = base + u*64 + lane;
      const float* p = xyz + ((size_t)b*NN + j)*3;
      float dot = __fadd_rn(__fadd_rn(__fmul_rn(qx,p[0]), __fmul_rn(qy,p[1])), __fmul_rn(qz,p[2]));
      float d2 = __fsub_rn(__fadd_rn(nq, xnrm[b*NN + j]), __fmul_rn(2.0f, dot));
      bool inb = d2 < 0.04f;
      unsigned long long m = __ballot(inb);
      int pos = cnt + (int)__popcll(m & ((1ull << lane) - 1ull));
      if (inb && pos < NSs) gw[pos] = j;
      cnt += (int)__popcll(m);
    }
  }
  // within-wave LDS ordering only — no block barrier needed
  int g0 = gw[0];
  if (lane >= cnt) gw[lane] = g0;
  float h1[64];
  {
    int gj = gw[lane];
    const float* p = xyz + ((size_t)b*NN + gj)*3;
    float px = p[0]-qx, py = p[1]-qy, pz = p[2]-qz;
#pragma unroll
    for (int c = 0; c < 64; ++c) h1[c] = 0.0f;
#pragma unroll
    for (int half = 0; half < 2; ++half){
      float h0h[32];
#pragma unroll
      for (int mm = 0; mm < 32; ++mm){
        int c = half*32 + mm;
        float a = fmaf(w0[c*3+2], pz, fmaf(w0[c*3+1], py, w0[c*3]*px));
        h0h[mm] = fmaxf(a, 0.0f);
      }
#pragma unroll
      for (int c = 0; c < 64; ++c){
        const float4* wr = (const float4*)(w1 + c*64 + half*32);
        float a = h1[c];
#pragma unroll
        for (int qq = 0; qq < 8; ++qq){
          float4 w = wr[qq];
          a = fmaf(w.x, h0h[4*qq+0], a);
          a = fmaf(w.y, h0h[4*qq+1], a);
          a = fmaf(w.z, h0h[4*qq+2], a);
          a = fmaf(w.w, h0h[4*qq+3], a);
        }
        h1[c] = a;
      }
    }
#pragma unroll
    for (int c = 0; c < 64; ++c) h1[c] = fmaxf(h1[c], 0.0f);
  }
  float m0 = 0.0f, m1 = 0.0f;
#pragma unroll 2
  for (int c = 0; c < 128; ++c){
    const float4* wr = (const float4*)(w2 + (size_t)c*64);
    float a = 0.0f;
#pragma unroll
    for (int qq = 0; qq < 16; ++qq){
      float4 w = wr[qq];
      a = fmaf(w.x, h1[4*qq+0], a);
      a = fmaf(w.y, h1[4*qq+1], a);
      a = fmaf(w.z, h1[4*qq+2], a);
      a = fmaf(w.w, h1[4*qq+3], a);
    }
    a = fmaxf(a, 0.0f);
#define SA_MAX(C) { float o = __int_as_float(dpp_i<C>(__float_as_int(a))); a = fmaxf(a, o); }
    SA_MAX(0x111) SA_MAX(0x112) SA_MAX(0x114) SA_MAX(0x118) SA_MAX(0x142) SA_MAX(0x143)
#undef SA_MAX
    float r = __int_as_float(__builtin_amdgcn_readlane(__float_as_int(a), 63));
    if (c < 64){ if (lane == c) m0 = r; }
    else       { if (lane == c - 64) m1 = r; }
  }
  feat[(size_t)bi*128 + lane]      = m0;
  feat[(size_t)bi*128 + 64 + lane] = m1;
  x131[(size_t)bi*132 + lane]      = m0;
  x131[(size_t)bi*132 + 64 + lane] = m1;
  if (lane < 3) x131[(size_t)bi*132 + 128 + lane] = (lane==0)?qx:((lane==1)?qy:qz);
}

// ---------------- kNN: distances in registers, u64-DPP selection, no selection LDS ----------------
template<int CIN>
__global__ __launch_bounds__(512) void k_knn3(const float* __restrict__ xT,
    const float* __restrict__ nrm, int* __restrict__ idxo){
  __shared__ __align__(16) float sch[16*256];
  int bi = blockIdx.x, t = threadIdx.x;
  int w = t >> 6, lane = t & 63;
  int b = bi >> 5;
  int coli = (bi & 31)*8 + w;
  const float* xb = xT + (size_t)b*CIN*256;
  float d0=0.f, d1=0.f, d2=0.f, d3=0.f;
  for (int m0 = 0; m0 < CIN; m0 += 16){
    int mc = (CIN - m0 < 16) ? (CIN - m0) : 16;
    for (int i = t; i < mc*64; i += 512){
      int mm = i >> 6, c4 = i & 63;
      *(float4*)(sch + mm*256 + c4*4) = *(const float4*)(xb + (size_t)(m0+mm)*256 + c4*4);
    }
    __syncthreads();
    for (int mm = 0; mm < mc; ++mm){
      float xm = sch[mm*256 + coli];
      float4 v = *(const float4*)(sch + mm*256 + 4*lane);
      d0 = fmaf(v.x, xm, d0); d1 = fmaf(v.y, xm, d1);
      d2 = fmaf(v.z, xm, d2); d3 = fmaf(v.w, xm, d3);
    }
    __syncthreads();
  }
  float ni = nrm[b*256 + coli];
  float4 dv;
  {
    int j0 = 4*lane;
    dv.x = __fsub_rn(__fadd_rn(ni, nrm[b*256 + j0+0]), __fmul_rn(2.0f, d0));
    dv.y = __fsub_rn(__fadd_rn(ni, nrm[b*256 + j0+1]), __fmul_rn(2.0f, d1));
    dv.z = __fsub_rn(__fadd_rn(ni, nrm[b*256 + j0+2]), __fmul_rn(2.0f, d2));
    dv.w = __fsub_rn(__fadd_rn(ni, nrm[b*256 + j0+3]), __fmul_rn(2.0f, d3));
  }
  for (int r = 0; r < KC; ++r){
    float bv = 3.4e38f; int bj = NPp;
    if (dv.x < bv){ bv = dv.x; bj = 4*lane+0; }
    if (dv.y < bv){ bv = dv.y; bj = 4*lane+1; }
    if (dv.z < bv){ bv = dv.z; bj = 4*lane+2; }
    if (dv.w < bv){ bv = dv.w; bj = 4*lane+3; }
    unsigned xf = __float_as_uint(bv);
    xf = (xf & 0x80000000u) ? ~xf : (xf | 0x80000000u);
    ull key = ((ull)xf << 32) | (unsigned)bj;
#define KN_STAGE(C) { \
    unsigned ol = (unsigned)dpp_i<C>((int)(unsigned)key); \
    unsigned oh = (unsigned)dpp_i<C>((int)(unsigned)(key >> 32)); \
    ull ok = ((ull)oh << 32) | ol; \
    if (ok < key) key = ok; }
    KN_STAGE(0x111) KN_STAGE(0x112) KN_STAGE(0x114) KN_STAGE(0x118)
    KN_STAGE(0x142) KN_STAGE(0x143)
#undef KN_STAGE
    int bjw = __builtin_amdgcn_readlane((int)(unsigned)key, 63);
    if (lane == 0) idxo[((size_t)b*256 + coli)*KC + r] = bjw;
    if ((bjw >> 2) == lane){
      int e = bjw & 3;
      if      (e == 0) dv.x = 3.0e38f;
      else if (e == 1) dv.y = 3.0e38f;
      else if (e == 2) dv.z = 3.0e38f;
      else             dv.w = 3.0e38f;
    }
  }
}

// ---------------- per-point dual GEMM + fused xT transpose + fused norms ----------------
template<int CIN, int COUT, int T>
__global__ __launch_bounds__(T) void k_gab(const float* __restrict__ x, int xstride,
    const float* __restrict__ wA, const float* __restrict__ wB,
    float* __restrict__ A, float* __restrict__ B, float* __restrict__ xT,
    float* __restrict__ nrm){
  constexpr int PC  = CIN + 1;
  constexpr int G   = COUT/4;
  constexpr int RS  = T/G;
  constexpr int RPT = 16/RS;
  __shared__ float xsh[16*PC];
  int bi = blockIdx.x, t = threadIdx.x;
  int g = t % G, rs = t / G;
  int i0 = bi*16;
  for (int i = t; i < 16*CIN; i += T){
    int r = i / CIN, m = i - r*CIN;
    xsh[r*PC + m] = x[(size_t)(i0+r)*xstride + m];
  }
  __syncthreads();
  {
    int bb = i0 >> 8, col0 = i0 & 255;
    float* xTb = xT + (size_t)bb*CIN*256 + col0;
    for (int i = t; i < 16*CIN; i += T){
      int m = i >> 4, r = i & 15;
      xTb[m*256 + r] = xsh[r*PC + m];
    }
  }
  if (t < 16){
    const float* xr = xsh + t*PC;
    float a = 0.0f;
    for (int m = 0; m < CIN; ++m) a = __fadd_rn(a, __fmul_rn(xr[m], xr[m]));
    nrm[i0 + t] = a;
  }
  float4 accA[RPT], accB[RPT];
#pragma unroll
  for (int rr = 0; rr < RPT; ++rr){
    accA[rr] = make_float4(0.f,0.f,0.f,0.f);
    accB[rr] = make_float4(0.f,0.f,0.f,0.f);
  }
  for (int m = 0; m < CIN; ++m){
    float4 wa = *(const float4*)(wA + (size_t)m*COUT + 4*g);
    float4 wb = *(const float4*)(wB + (size_t)m*COUT + 4*g);
#pragma unroll
    for (int rr = 0; rr < RPT; ++rr){
      float xv = xsh[(rs + rr*RS)*PC + m];
      accA[rr] = fma4s(wa, xv, accA[rr]);
      accB[rr] = fma4s(wb, xv, accB[rr]);
    }
  }
#pragma unroll
  for (int rr = 0; rr < RPT; ++rr){
    int r = i0 + rs + rr*RS;
    *(float4*)(A + (size_t)r*COUT + 4*g) = accA[rr];
    *(float4*)(B + (size_t)r*COUT + 4*g) = accB[rr];
  }
}

// ---------------- edge epilogue: out[i][c] = max_k relu(A[i][c] + B[j_ik][c]) ----------------
template<int COUT>
__global__ __launch_bounds__(256) void k_emax(const float* __restrict__ A, const float* __restrict__ Bm,
    const int* __restrict__ idx, float* __restrict__ out){
  constexpr int GT = COUT/4;
  constexpr int NC = 256/GT;
  __shared__ int js[NC*KC];
  int bi = blockIdx.x, t = threadIdx.x;
  int li = t / GT, c4 = (t % GT)*4;
  int ci = bi*NC + li;
  int rb = (ci >> 8) << 8;
  if (t < NC*KC) js[t] = idx[(size_t)bi*NC*KC + t];
  __syncthreads();
  float4 a = *(const float4*)(A + (size_t)ci*COUT + c4);
  float4 p = make_float4(0.f,0.f,0.f,0.f);
#pragma unroll
  for (int k = 0; k < KC; ++k){
    int j = js[li*KC + k];
    float4 b = *(const float4*)(Bm + (size_t)(rb + j)*COUT + c4);
    p = max4(p, add4(a, b));
  }
  *(float4*)(out + (size_t)ci*COUT + c4) = p;
}

// ---------------- T-Net edge: h0 = relu(A0+B0) then 64->128 conv + k-maxpool ----------------
__global__ __launch_bounds__(128) void k_tedge3(const float* __restrict__ A0, const float* __restrict__ B0,
    const int* __restrict__ idx, const float* __restrict__ wt1, float* __restrict__ out){
  __shared__ __align__(16) float h0s[20*68];
  __shared__ __align__(16) float smax[4*128];
  __shared__ int js[KC];
  int bi = blockIdx.x, t = threadIdx.x;
  int cg = t & 31, kg = t >> 5, k0 = kg*5;
  int rb = (bi >> 8) << 8;
  if (t < KC) js[t] = idx[(size_t)bi*KC + t];
  __syncthreads();
  for (int i = t; i < 20*64; i += 128){
    int k = i >> 6, c = i & 63;
    float v = A0[(size_t)bi*64 + c] + B0[(size_t)(rb + js[k])*64 + c];
    h0s[k*68 + c] = fmaxf(v, 0.0f);
  }
  __syncthreads();
  float4 b2[5];
#pragma unroll
  for (int kk = 0; kk < 5; ++kk) b2[kk] = make_float4(0.f,0.f,0.f,0.f);
  for (int m4 = 0; m4 < 16; ++m4){
    float4 e[5];
#pragma unroll
    for (int kk = 0; kk < 5; ++kk) e[kk] = *(const float4*)(h0s + (k0+kk)*68 + 4*m4);
#pragma unroll
    for (int mm = 0; mm < 4; ++mm){
      float4 w = *(const float4*)(wt1 + (4*m4+mm)*128 + 4*cg);
#pragma unroll
      for (int kk = 0; kk < 5; ++kk){
        float ev = (mm==0)?e[kk].x:((mm==1)?e[kk].y:((mm==2)?e[kk].z:e[kk].w));
        b2[kk] = fma4s(w, ev, b2[kk]);
      }
    }
  }
  float4 p = make_float4(0.f,0.f,0.f,0.f);
#pragma unroll
  for (int kk = 0; kk < 5; ++kk) p = max4(p, b2[kk]);
  *(float4*)(smax + kg*128 + 4*cg) = p;
  __syncthreads();
  if (kg == 0){
    float4 r = *(const float4*)(smax + 4*cg);
#pragma unroll
    for (int g = 1; g < 4; ++g) r = max4(r, *(const float4*)(smax + g*128 + 4*cg));
    *(float4*)(out + (size_t)bi*128 + 4*cg) = r;
  }
}

// ---------------- T-Net 128->1024 + pool: 8 point-chunks, atomicMax combine ----------------
__global__ __launch_bounds__(128) void k_tpool(const float* __restrict__ h, const float* __restrict__ W,
    float* __restrict__ g1024){
  int b = blockIdx.x, t = threadIdx.x;
  int c = blockIdx.y*128 + t;
  int i0 = blockIdx.z*32;
  float4 w[32];
#pragma unroll
  for (int qq = 0; qq < 32; ++qq) w[qq] = *(const float4*)(W + (size_t)c*128 + 4*qq);
  const float* hb = h + (size_t)b*NPp*128;
  float mx = 0.0f;
  for (int i = i0; i < i0 + 32; ++i){
    const float4* hr = (const float4*)(hb + (size_t)i*128);
    float a = 0.0f;
#pragma unroll
    for (int qq = 0; qq < 32; ++qq) a = fma4(w[qq], hr[qq], a);
    mx = fmaxf(mx, a);
  }
  atomicMax((int*)(g1024 + (size_t)b*1024 + c), __float_as_int(mx));
}

// ---------------- T-Net MLP + 3x3 transform applied to new_xyz ----------------
__global__ __launch_bounds__(256) void k_trest(const float* __restrict__ g1024,
    const float* __restrict__ Wg0, const float* __restrict__ Wg1,
    const float* __restrict__ Wl, const float* __restrict__ bl,
    const float* __restrict__ new_xyz, float* __restrict__ x131){
  __shared__ __align__(16) float g1[1024];
  __shared__ __align__(16) float g5[512];
  __shared__ __align__(16) float g2[256];
  __shared__ float tm[12];
  int b = blockIdx.x, t = threadIdx.x;
  for (int m = t; m < 1024; m += 256) g1[m] = g1024[(size_t)b*1024 + m];
  __syncthreads();
#pragma unroll
  for (int cc = 0; cc < 2; ++cc){
    int c = t + cc*256;
    const float4* wr = (const float4*)(Wg0 + (size_t)c*1024);
    const float4* gv = (const float4*)g1;
    float a = 0.0f;
    for (int qq = 0; qq < 256; ++qq) a = fma4(wr[qq], gv[qq], a);
    g5[c] = fmaxf(a, 0.0f);
  }
  __syncthreads();
  {
    const float4* wr = (const float4*)(Wg1 + (size_t)t*512);
    const float4* gv = (const float4*)g5;
    float a = 0.0f;
    for (int qq = 0; qq < 128; ++qq) a = fma4(wr[qq], gv[qq], a);
    g2[t] = fmaxf(a, 0.0f);
  }
  __syncthreads();
  if (t < 9){
    const float4* wr = (const float4*)(Wl + (size_t)t*256);
    const float4* gv = (const float4*)g2;
    float a = 0.0f;
#pragma unroll
    for (int qq = 0; qq < 64; ++qq) a = fma4(wr[qq], gv[qq], a);
    a += bl[t];
    if (t == 0 || t == 4 || t == 8) a += 1.0f;
    tm[t] = a;
  }
  __syncthreads();
  {
    const float* nx = new_xyz + ((size_t)b*NPp + t)*3;
    float X = nx[0], Y = nx[1], Z = nx[2];
#pragma unroll
    for (int i = 0; i < 3; ++i){
      float v = __fadd_rn(__fadd_rn(__fmul_rn(tm[i*3+0], X), __fmul_rn(tm[i*3+1], Y)), __fmul_rn(tm[i*3+2], Z));
      x131[((size_t)b*NPp + t)*132 + 128 + i] = v;
    }
  }
}

// ---------------- 896->128 conv + global max pool (atomicMax; poison is negative int) ----------------
__global__ __launch_bounds__(128) void k_dgl(const float* __restrict__ f1, const float* __restrict__ f2,
    const float* __restrict__ f3, const float* __restrict__ W, float* __restrict__ g128){
  int b = blockIdx.x, t = threadIdx.x;
  int i0 = blockIdx.y * 16;
  const float* wr = W + (size_t)t*896;
  float acc[16];
#pragma unroll
  for (int ii = 0; ii < 16; ++ii) acc[ii] = 0.0f;
  for (int q = 0; q < 32; ++q){
    float4 w = *(const float4*)(wr + 4*q);
#pragma unroll
    for (int ii = 0; ii < 16; ++ii){
      float4 v = *(const float4*)(f1 + ((size_t)b*NPp + i0 + ii)*128 + 4*q);
      acc[ii] = fma4(w, v, acc[ii]);
    }
  }
  for (int q = 0; q < 64; ++q){
    float4 w = *(const float4*)(wr + 128 + 4*q);
#pragma unroll
    for (int ii = 0; ii < 16; ++ii){
      float4 v = *(const float4*)(f2 + ((size_t)b*NPp + i0 + ii)*256 + 4*q);
      acc[ii] = fma4(w, v, acc[ii]);
    }
  }
  for (int q = 0; q < 128; ++q){
    float4 w = *(const float4*)(wr + 384 + 4*q);
#pragma unroll
    for (int ii = 0; ii < 16; ++ii){
      float4 v = *(const float4*)(f3 + ((size_t)b*NPp + i0 + ii)*512 + 4*q);
      acc[ii] = fma4(w, v, acc[ii]);
    }
  }
#pragma unroll
  for (int ii = 0; ii < 16; ++ii){
    float v = fmaxf(acc[ii], 0.0f);
    atomicMax((int*)(g128 + (size_t)b*128 + t), __float_as_int(v));
  }
}

// ---------------- classifier head ----------------
__global__ __launch_bounds__(256) void k_final(const float* __restrict__ g128,
    const float* __restrict__ W0, const float* __restrict__ W1,
    const float* __restrict__ Wc, const float* __restrict__ bc, float* __restrict__ out){
  __shared__ __align__(16) float g0[128];
  __shared__ __align__(16) float g5[512];
  __shared__ __align__(16) float g2[256];
  int b = blockIdx.x, t = threadIdx.x;
  if (t < 128) g0[t] = g128[(size_t)b*128 + t];
  __syncthreads();
#pragma unroll
  for (int cc = 0; cc < 2; ++cc){
    int c = t + cc*256;
    const float4* wr = (const float4*)(W0 + (size_t)c*128);
    const float4* gv = (const float4*)g0;
    float a = 0.0f;
#pragma unroll
    for (int qq = 0; qq < 32; ++qq) a = fma4(wr[qq], gv[qq], a);
    g5[c] = fmaxf(a, 0.0f);
  }
  __syncthreads();
  {
    const float4* wr = (const float4*)(W1 + (size_t)t*512);
    const float4* gv = (const float4*)g5;
    float a = 0.0f;
    for (int qq = 0; qq < 128; ++qq) a = fma4(wr[qq], gv[qq], a);
    g2[t] = fmaxf(a, 0.0f);
  }
  __syncthreads();
  if (t < 40){
    const float4* wr = (const float4*)(Wc + (size_t)t*256);
    const float4* gv = (const float4*)g2;
    float a = 0.0f;
#pragma unroll
    for (int qq = 0; qq < 64; ++qq) a = fma4(wr[qq], gv[qq], a);
    out[(size_t)b*40 + t] = a + bc[t];
  }
}

extern "C" void kernel_launch(void* const* d_in, const int* in_sizes, int n_in,
                              void* d_out, int out_size, void* d_ws, size_t ws_size,
                              hipStream_t stream){
  (void)in_sizes; (void)n_in; (void)out_size; (void)ws_size;
  const float* points     = (const float*)d_in[0];
  const float* sa_w0      = (const float*)d_in[1];
  const float* sa_w1      = (const float*)d_in[2];
  const float* sa_w2      = (const float*)d_in[3];
  const float* t_ec_w0    = (const float*)d_in[4];
  const float* t_ec_w1    = (const float*)d_in[5];
  const float* t_local_w  = (const float*)d_in[6];
  const float* t_g_w0     = (const float*)d_in[7];
  const float* t_g_w1     = (const float*)d_in[8];
  const float* t_lin_w    = (const float*)d_in[9];
  const float* t_lin_b    = (const float*)d_in[10];
  const float* dg_ec_w0   = (const float*)d_in[11];
  const float* dg_ec_w1   = (const float*)d_in[12];
  const float* dg_ec_w2   = (const float*)d_in[13];
  const float* dg_local_w = (const float*)d_in[14];
  const float* dg_g_w0    = (const float*)d_in[15];
  const float* dg_g_w1    = (const float*)d_in[16];
  const float* cls_w      = (const float*)d_in[17];
  const float* cls_b      = (const float*)d_in[18];
  float* out = (float*)d_out;

  float* ws     = (float*)d_ws;
  float* xyz    = ws;                    // 393216
  float* xnrm   = xyz    + 393216;       // 131072
  float* nxyz   = xnrm   + 131072;       // 24576
  float* feat   = nxyz   + 24576;        // 1048576
  float* x131   = feat   + 1048576;      // 1081344
  float* nrm    = x131   + 1081344;      // 8192
  int*   idx    = (int*)(nrm + 8192);    // 163840
  float* ht     = (float*)(idx + 163840);// 1048576 (reused as f1)
  float* g1024v = ht     + 1048576;      // 32768
  float* f2     = g1024v + 32768;        // 2097152
  float* f3     = f2     + 2097152;      // 4194304
  float* g128v  = f3     + 4194304;      // 4096
  float* wt_t1  = g128v  + 4096;         // 8192   (64x128)
  float* waT0   = wt_t1  + 8192;         // 8384   (131x64)
  float* wbT0   = waT0   + 8384;         // 8384
  float* waD0   = wbT0   + 8384;         // 16768  (131x128)
  float* wbD0   = waD0   + 16768;        // 16768
  float* waD1   = wbD0   + 16768;        // 32768  (128x256)
  float* wbD1   = waD1   + 32768;        // 32768
  float* waD2   = wbD1   + 32768;        // 131072 (256x512)
  float* wbD2   = waD2   + 131072;       // 131072
  float* Ab     = wbD2   + 131072;       // 4194304
  float* Bb     = Ab     + 4194304;      // 4194304
  float* f1 = ht;
  float* xT = f3;                        // alias: xT lives in f3 until k_emax<512> writes f3

  k_prep<<<512, 256, 0, stream>>>(points, xyz, xnrm);
  k_wprep<<<771, 256, 0, stream>>>(t_ec_w0, t_ec_w1, dg_ec_w0, dg_ec_w1, dg_ec_w2,
                                   waT0, wbT0, wt_t1, waD0, wbD0, waD1, wbD1, waD2, wbD2);
  k_fps<<<BB, 256, 0, stream>>>(xyz, nxyz);
  k_sa<<<BB*NPp/4, 256, 0, stream>>>(xyz, xnrm, nxyz, sa_w0, sa_w1, sa_w2, feat, x131);

  // T-Net branch (x = [feat, new_xyz])
  k_gab<131,64,256><<<512, 256, 0, stream>>>(x131, 132, waT0, wbT0, Ab, Bb, xT, nrm);
  k_knn3<131><<<1024, 512, 0, stream>>>(xT, nrm, idx);
  k_tedge3<<<BB*NPp, 128, 0, stream>>>(Ab, Bb, idx, wt_t1, ht);
  k_tpool<<<dim3(BB, 8, 8), 128, 0, stream>>>(ht, t_local_w, g1024v);
  k_trest<<<BB, 256, 0, stream>>>(g1024v, t_g_w0, t_g_w1, t_lin_w, t_lin_b, nxyz, x131);

  // DGCNN layer 1 (x = [feat, xyz_t], 131 dims)
  k_gab<131,128,512><<<512, 512, 0, stream>>>(x131, 132, waD0, wbD0, Ab, Bb, xT, nrm);
  k_knn3<131><<<1024, 512, 0, stream>>>(xT, nrm, idx);
  k_emax<128><<<1024, 256, 0, stream>>>(Ab, Bb, idx, f1);
  // layer 2
  k_gab<128,256,512><<<512, 512, 0, stream>>>(f1, 128, waD1, wbD1, Ab, Bb, xT, nrm);
  k_knn3<128><<<1024, 512, 0, stream>>>(xT, nrm, idx);
  k_emax<256><<<2048, 256, 0, stream>>>(Ab, Bb, idx, f2);
  // layer 3
  k_gab<256,512,512><<<512, 512, 0, stream>>>(f2, 256, waD2, wbD2, Ab, Bb, xT, nrm);
  k_knn3<256><<<1024, 512, 0, stream>>>(xT, nrm, idx);
  k_emax<512><<<4096, 256, 0, stream>>>(Ab, Bb, idx, f3);

  // local conv + global pool + head
  k_dgl<<<dim3(BB, 16), 128, 0, stream>>>(f1, f2, f3, dg_local_w, g128v);
  k_final<<<BB, 256, 0, stream>>>(g128v, dg_g_w0, dg_g_w1, cls_w, cls_b, out);
}

// Round 14
// 1359.287 us; speedup vs baseline: 1.3321x; 1.0121x over previous
//
#include <hip/hip_runtime.h>
#include <math.h>

#define BB 32
#define NN 4096
#define NPp 256
#define NSs 64
#define KC 20

typedef unsigned long long ull;

__device__ __forceinline__ float fma4(const float4 w, const float4 v, float a){
  a = fmaf(w.x, v.x, a); a = fmaf(w.y, v.y, a);
  a = fmaf(w.z, v.z, a); a = fmaf(w.w, v.w, a); return a;
}
__device__ __forceinline__ float4 fma4s(const float4 w, float s, float4 a){
  a.x = fmaf(w.x, s, a.x); a.y = fmaf(w.y, s, a.y);
  a.z = fmaf(w.z, s, a.z); a.w = fmaf(w.w, s, a.w); return a;
}
__device__ __forceinline__ float4 max4(float4 a, float4 b){
  a.x = fmaxf(a.x, b.x); a.y = fmaxf(a.y, b.y);
  a.z = fmaxf(a.z, b.z); a.w = fmaxf(a.w, b.w); return a;
}
__device__ __forceinline__ float4 add4(float4 a, float4 b){
  a.x += b.x; a.y += b.y; a.z += b.z; a.w += b.w; return a;
}

template<int C>
__device__ __forceinline__ int dpp_i(int x){
  return __builtin_amdgcn_update_dpp(x, x, C, 0xf, 0xf, false);
}

// ---------------- unified weight prep (all transposes/splits in one kernel) ----------------
__global__ void k_wprep(const float* __restrict__ t0, const float* __restrict__ t1,
                        const float* __restrict__ d0, const float* __restrict__ d1,
                        const float* __restrict__ d2, const float* __restrict__ saw1,
                        float* __restrict__ waT0, float* __restrict__ wbT0,
                        float* __restrict__ wt_t1,
                        float* __restrict__ waD0, float* __restrict__ wbD0,
                        float* __restrict__ waD1, float* __restrict__ wbD1,
                        float* __restrict__ waD2, float* __restrict__ wbD2,
                        float* __restrict__ w1T){
  int i = blockIdx.x*256 + threadIdx.x;
  if (i < 8384){                       // t_ec_w0: [64][262] -> A/B [131][64]
    int m = i >> 6;
    int c = i & 63;
    float bb = t0[(size_t)c*262 + m];
    float dd = t0[(size_t)c*262 + 131 + m];
    waT0[i] = __fsub_rn(bb, dd); wbT0[i] = dd;
    return;
  }
  i -= 8384;
  if (i < 8192){                       // t_ec_w1: [128][64] -> [64][128]
    int m = i >> 7, c = i & 127;
    wt_t1[i] = t1[(size_t)c*64 + m];
    return;
  }
  i -= 8192;
  if (i < 16768){                      // dg_ec_w0: [128][262] -> A/B [131][128]
    int m = i >> 7, c = i & 127;
    float bb = d0[(size_t)c*262 + m];
    float dd = d0[(size_t)c*262 + 131 + m];
    waD0[i] = __fsub_rn(bb, dd); wbD0[i] = dd;
    return;
  }
  i -= 16768;
  if (i < 32768){                      // dg_ec_w1: [256][256] -> A/B [128][256]
    int m = i >> 8, c = i & 255;
    float bb = d1[(size_t)c*256 + m];
    float dd = d1[(size_t)c*256 + 128 + m];
    waD1[i] = __fsub_rn(bb, dd); wbD1[i] = dd;
    return;
  }
  i -= 32768;
  if (i < 131072){                     // dg_ec_w2: [512][512] -> A/B [256][512]
    int m = i >> 9, c = i & 511;
    float bb = d2[(size_t)c*512 + m];
    float dd = d2[(size_t)c*512 + 256 + m];
    waD2[i] = __fsub_rn(bb, dd); wbD2[i] = dd;
    return;
  }
  i -= 131072;
  if (i < 4096){                       // sa_w1: [64][64] -> w1T[m][c]
    int m = i >> 6, c = i & 63;
    w1T[i] = saw1[(size_t)c*64 + m];
  }
}

// ---------------- transpose + point norms ----------------
__global__ void k_prep(const float* __restrict__ pts, float* __restrict__ xyz, float* __restrict__ xnrm){
  int i = blockIdx.x*256 + threadIdx.x;
  if (i >= BB*NN) return;
  int b = i >> 12, n = i & (NN-1);
  float X = pts[(b*3+0)*NN + n];
  float Y = pts[(b*3+1)*NN + n];
  float Z = pts[(b*3+2)*NN + n];
  xyz[i*3+0]=X; xyz[i*3+1]=Y; xyz[i*3+2]=Z;
  xnrm[i] = __fadd_rn(__fadd_rn(__fmul_rn(X,X), __fmul_rn(Y,Y)), __fmul_rn(Z,Z));
}

// ---------------- farthest point sampling: u64 keys, quad_perm combine ----------------
__global__ __launch_bounds__(256) void k_fps(const float* __restrict__ xyz, float* __restrict__ new_xyz){
  __shared__ __align__(16) float part[2][4][8];
  int b = blockIdx.x, t = threadIdx.x;
  int w = t >> 6, lane = t & 63;
  float px[16], py[16], pz[16], dist[16];
#pragma unroll
  for (int q = 0; q < 16; ++q){
    const float* p = xyz + ((size_t)b*NN + q*256 + t)*3;
    px[q] = p[0]; py[q] = p[1]; pz[q] = p[2];
    dist[q] = __builtin_inff();
  }
  const float* p0 = xyz + (size_t)b*NN*3;
  float Px = p0[0], Py = p0[1], Pz = p0[2];
  float sx = 0.f, sy = 0.f, sz = 0.f;
  for (int it = 0; it < NPp; ++it){
    if (t == it){ sx = Px; sy = Py; sz = Pz; }
    float bv = -1.0f, bx = 0.f, by = 0.f, bz = 0.f; int bj = 0;
#pragma unroll
    for (int q = 0; q < 16; ++q){
      float dx = __fsub_rn(px[q], Px);
      float dy = __fsub_rn(py[q], Py);
      float dz = __fsub_rn(pz[q], Pz);
      float dd = __fadd_rn(__fadd_rn(__fmul_rn(dx,dx), __fmul_rn(dy,dy)), __fmul_rn(dz,dz));
      float dm = fminf(dist[q], dd);
      dist[q] = dm;
      if (dm > bv){ bv = dm; bj = q*256 + t; bx = px[q]; by = py[q]; bz = pz[q]; }
    }
    ull key = ((ull)__float_as_uint(bv) << 32) | (unsigned)(4095 - bj);
#define FPS_STAGE(C) { \
    unsigned ol = (unsigned)dpp_i<C>((int)(unsigned)key); \
    unsigned oh = (unsigned)dpp_i<C>((int)(unsigned)(key >> 32)); \
    float ox = __int_as_float(dpp_i<C>(__float_as_int(bx))); \
    float oy = __int_as_float(dpp_i<C>(__float_as_int(by))); \
    float oz = __int_as_float(dpp_i<C>(__float_as_int(bz))); \
    ull ok = ((ull)oh << 32) | ol; \
    bool tk = ok > key; \
    key = tk ? ok : key; bx = tk ? ox : bx; by = tk ? oy : by; bz = tk ? oz : bz; }
    FPS_STAGE(0x111) FPS_STAGE(0x112) FPS_STAGE(0x114) FPS_STAGE(0x118)
    FPS_STAGE(0x142) FPS_STAGE(0x143)
#undef FPS_STAGE
    int par = it & 1;
    if (lane == 63){
      float4 v;
      v.x = __uint_as_float((unsigned)key);
      v.y = __uint_as_float((unsigned)(key >> 32));
      v.z = bx; v.w = by;
      *(float4*)&part[par][w][0] = v;
      part[par][w][4] = bz;
    }
    __syncthreads();
    {
      const float* pp = &part[par][lane & 3][0];
      float4 v = *(const float4*)pp;
      float vz = pp[4];
      ull k2 = ((ull)__float_as_uint(v.y) << 32) | __float_as_uint(v.x);
      float cx = v.z, cy = v.w, cz = vz;
#define FPS_Q(C) { \
      unsigned ol = (unsigned)dpp_i<C>((int)(unsigned)k2); \
      unsigned oh = (unsigned)dpp_i<C>((int)(unsigned)(k2 >> 32)); \
      float ox = __int_as_float(dpp_i<C>(__float_as_int(cx))); \
      float oy = __int_as_float(dpp_i<C>(__float_as_int(cy))); \
      float oz = __int_as_float(dpp_i<C>(__float_as_int(cz))); \
      ull ok = ((ull)oh << 32) | ol; \
      bool tk = ok > k2; \
      k2 = tk ? ok : k2; cx = tk ? ox : cx; cy = tk ? oy : cy; cz = tk ? oz : cz; }
      FPS_Q(0xB1) FPS_Q(0x4E)
#undef FPS_Q
      Px = cx; Py = cy; Pz = cz;
    }
  }
  {
    float* o = new_xyz + ((size_t)b*NPp + t)*3;
    o[0] = sx; o[1] = sy; o[2] = sz;
  }
}

// ---------------- ball query + SA convs + maxpool: rolled loops (I$-resident), regs only ----------------
__global__ __launch_bounds__(256) void k_sa(const float* __restrict__ xyz, const float* __restrict__ xnrm,
    const float* __restrict__ new_xyz, const float* __restrict__ w0, const float* __restrict__ w1T,
    const float* __restrict__ w2, float* __restrict__ feat, float* __restrict__ x131){
  __shared__ int gix[4][64];
  int t = threadIdx.x;
  int wv = t >> 6, lane = t & 63;
  int bi = blockIdx.x*4 + wv;
  int b = bi >> 8;
  int* gw = gix[wv];
  const float* q = new_xyz + (size_t)bi*3;
  float qx=q[0], qy=q[1], qz=q[2];
  float nq = __fadd_rn(__fadd_rn(__fmul_rn(qx,qx), __fmul_rn(qy,qy)), __fmul_rn(qz,qz));
  int cnt = 0;
  for (int base = 0; base < NN && cnt < NSs; base += 256){
#pragma unroll
    for (int u = 0; u < 4; ++u){
      int j = base + u*64 + lane;
      const float* p = xyz + ((size_t)b*NN + j)*3;
      float dot = __fadd_rn(__fadd_rn(__fmul_rn(qx,p[0]), __fmul_rn(qy,p[1])), __fmul_rn(qz,p[2]));
      float d2 = __fsub_rn(__fadd_rn(nq, xnrm[b*NN + j]), __fmul_rn(2.0f, dot));
      bool inb = d2 < 0.04f;
      unsigned long long m = __ballot(inb);
      int pos = cnt + (int)__popcll(m & ((1ull << lane) - 1ull));
      if (inb && pos < NSs) gw[pos] = j;
      cnt += (int)__popcll(m);
    }
  }
  int g0 = gw[0];
  if (lane >= cnt) gw[lane] = g0;
  // lane = sample; mid conv rolled over m (h1 channel index constant-unrolled -> stays in VGPRs)
  float h1[64];
  {
    int gj = gw[lane];
    const float* p = xyz + ((size_t)b*NN + gj)*3;
    float px = p[0]-qx, py = p[1]-qy, pz = p[2]-qz;
#pragma unroll
    for (int c = 0; c < 64; ++c) h1[c] = 0.0f;
    for (int m = 0; m < 64; ++m){
      float a0 = fmaf(w0[m*3+2], pz, fmaf(w0[m*3+1], py, w0[m*3]*px));
      float h0m = fmaxf(a0, 0.0f);
      const float4* wr = (const float4*)(w1T + m*64);
#pragma unroll
      for (int q4 = 0; q4 < 16; ++q4){
        float4 w = wr[q4];
        h1[4*q4+0] = fmaf(w.x, h0m, h1[4*q4+0]);
        h1[4*q4+1] = fmaf(w.y, h0m, h1[4*q4+1]);
        h1[4*q4+2] = fmaf(w.z, h0m, h1[4*q4+2]);
        h1[4*q4+3] = fmaf(w.w, h0m, h1[4*q4+3]);
      }
    }
#pragma unroll
    for (int c = 0; c < 64; ++c) h1[c] = fmaxf(h1[c], 0.0f);
  }
  // third conv: rolled over c, wave max-reduce via DPP
  float m0 = 0.0f, m1 = 0.0f;
#pragma unroll 2
  for (int c = 0; c < 128; ++c){
    const float4* wr = (const float4*)(w2 + (size_t)c*64);
    float a = 0.0f;
#pragma unroll
    for (int qq = 0; qq < 16; ++qq){
      float4 w = wr[qq];
      a = fmaf(w.x, h1[4*qq+0], a);
      a = fmaf(w.y, h1[4*qq+1], a);
      a = fmaf(w.z, h1[4*qq+2], a);
      a = fmaf(w.w, h1[4*qq+3], a);
    }
    a = fmaxf(a, 0.0f);
#define SA_MAX(C) { float o = __int_as_float(dpp_i<C>(__float_as_int(a))); a = fmaxf(a, o); }
    SA_MAX(0x111) SA_MAX(0x112) SA_MAX(0x114) SA_MAX(0x118) SA_MAX(0x142) SA_MAX(0x143)
#undef SA_MAX
    float r = __int_as_float(__builtin_amdgcn_readlane(__float_as_int(a), 63));
    if (c < 64){ if (lane == c) m0 = r; }
    else       { if (lane == c - 64) m1 = r; }
  }
  feat[(size_t)bi*128 + lane]      = m0;
  feat[(size_t)bi*128 + 64 + lane] = m1;
  x131[(size_t)bi*132 + lane]      = m0;
  x131[(size_t)bi*132 + 64 + lane] = m1;
  if (lane < 3) x131[(size_t)bi*132 + 128 + lane] = (lane==0)?qx:((lane==1)?qy:qz);
}

// ---------------- kNN: distances in registers, u64-DPP selection, no selection LDS ----------------
template<int CIN>
__global__ __launch_bounds__(512) void k_knn3(const float* __restrict__ xT,
    const float* __restrict__ nrm, int* __restrict__ idxo){
  __shared__ __align__(16) float sch[16*256];
  int bi = blockIdx.x, t = threadIdx.x;
  int w = t >> 6, lane = t & 63;
  int b = bi >> 5;
  int coli = (bi & 31)*8 + w;
  const float* xb = xT + (size_t)b*CIN*256;
  float d0=0.f, d1=0.f, d2=0.f, d3=0.f;
  for (int m0 = 0; m0 < CIN; m0 += 16){
    int mc = (CIN - m0 < 16) ? (CIN - m0) : 16;
    for (int i = t; i < mc*64; i += 512){
      int mm = i >> 6, c4 = i & 63;
      *(float4*)(sch + mm*256 + c4*4) = *(const float4*)(xb + (size_t)(m0+mm)*256 + c4*4);
    }
    __syncthreads();
    for (int mm = 0; mm < mc; ++mm){
      float xm = sch[mm*256 + coli];
      float4 v = *(const float4*)(sch + mm*256 + 4*lane);
      d0 = fmaf(v.x, xm, d0); d1 = fmaf(v.y, xm, d1);
      d2 = fmaf(v.z, xm, d2); d3 = fmaf(v.w, xm, d3);
    }
    __syncthreads();
  }
  float ni = nrm[b*256 + coli];
  float4 dv;
  {
    int j0 = 4*lane;
    dv.x = __fsub_rn(__fadd_rn(ni, nrm[b*256 + j0+0]), __fmul_rn(2.0f, d0));
    dv.y = __fsub_rn(__fadd_rn(ni, nrm[b*256 + j0+1]), __fmul_rn(2.0f, d1));
    dv.z = __fsub_rn(__fadd_rn(ni, nrm[b*256 + j0+2]), __fmul_rn(2.0f, d2));
    dv.w = __fsub_rn(__fadd_rn(ni, nrm[b*256 + j0+3]), __fmul_rn(2.0f, d3));
  }
  for (int r = 0; r < KC; ++r){
    float bv = 3.4e38f; int bj = NPp;
    if (dv.x < bv){ bv = dv.x; bj = 4*lane+0; }
    if (dv.y < bv){ bv = dv.y; bj = 4*lane+1; }
    if (dv.z < bv){ bv = dv.z; bj = 4*lane+2; }
    if (dv.w < bv){ bv = dv.w; bj = 4*lane+3; }
    unsigned xf = __float_as_uint(bv);
    xf = (xf & 0x80000000u) ? ~xf : (xf | 0x80000000u);
    ull key = ((ull)xf << 32) | (unsigned)bj;
#define KN_STAGE(C) { \
    unsigned ol = (unsigned)dpp_i<C>((int)(unsigned)key); \
    unsigned oh = (unsigned)dpp_i<C>((int)(unsigned)(key >> 32)); \
    ull ok = ((ull)oh << 32) | ol; \
    if (ok < key) key = ok; }
    KN_STAGE(0x111) KN_STAGE(0x112) KN_STAGE(0x114) KN_STAGE(0x118)
    KN_STAGE(0x142) KN_STAGE(0x143)
#undef KN_STAGE
    int bjw = __builtin_amdgcn_readlane((int)(unsigned)key, 63);
    if (lane == 0) idxo[((size_t)b*256 + coli)*KC + r] = bjw;
    if ((bjw >> 2) == lane){
      int e = bjw & 3;
      if      (e == 0) dv.x = 3.0e38f;
      else if (e == 1) dv.y = 3.0e38f;
      else if (e == 2) dv.z = 3.0e38f;
      else             dv.w = 3.0e38f;
    }
  }
}

// ---------------- per-point dual GEMM + fused xT transpose + fused norms ----------------
template<int CIN, int COUT, int T>
__global__ __launch_bounds__(T) void k_gab(const float* __restrict__ x, int xstride,
    const float* __restrict__ wA, const float* __restrict__ wB,
    float* __restrict__ A, float* __restrict__ B, float* __restrict__ xT,
    float* __restrict__ nrm){
  constexpr int PC  = CIN + 1;
  constexpr int G   = COUT/4;
  constexpr int RS  = T/G;
  constexpr int RPT = 16/RS;
  __shared__ float xsh[16*PC];
  int bi = blockIdx.x, t = threadIdx.x;
  int g = t % G, rs = t / G;
  int i0 = bi*16;
  for (int i = t; i < 16*CIN; i += T){
    int r = i / CIN, m = i - r*CIN;
    xsh[r*PC + m] = x[(size_t)(i0+r)*xstride + m];
  }
  __syncthreads();
  {
    int bb = i0 >> 8, col0 = i0 & 255;
    float* xTb = xT + (size_t)bb*CIN*256 + col0;
    for (int i = t; i < 16*CIN; i += T){
      int m = i >> 4, r = i & 15;
      xTb[m*256 + r] = xsh[r*PC + m];
    }
  }
  if (t < 16){
    const float* xr = xsh + t*PC;
    float a = 0.0f;
    for (int m = 0; m < CIN; ++m) a = __fadd_rn(a, __fmul_rn(xr[m], xr[m]));
    nrm[i0 + t] = a;
  }
  float4 accA[RPT], accB[RPT];
#pragma unroll
  for (int rr = 0; rr < RPT; ++rr){
    accA[rr] = make_float4(0.f,0.f,0.f,0.f);
    accB[rr] = make_float4(0.f,0.f,0.f,0.f);
  }
  for (int m = 0; m < CIN; ++m){
    float4 wa = *(const float4*)(wA + (size_t)m*COUT + 4*g);
    float4 wb = *(const float4*)(wB + (size_t)m*COUT + 4*g);
#pragma unroll
    for (int rr = 0; rr < RPT; ++rr){
      float xv = xsh[(rs + rr*RS)*PC + m];
      accA[rr] = fma4s(wa, xv, accA[rr]);
      accB[rr] = fma4s(wb, xv, accB[rr]);
    }
  }
#pragma unroll
  for (int rr = 0; rr < RPT; ++rr){
    int r = i0 + rs + rr*RS;
    *(float4*)(A + (size_t)r*COUT + 4*g) = accA[rr];
    *(float4*)(B + (size_t)r*COUT + 4*g) = accB[rr];
  }
}

// ---------------- edge epilogue: out[i][c] = max_k relu(A[i][c] + B[j_ik][c]) ----------------
template<int COUT>
__global__ __launch_bounds__(256) void k_emax(const float* __restrict__ A, const float* __restrict__ Bm,
    const int* __restrict__ idx, float* __restrict__ out){
  constexpr int GT = COUT/4;
  constexpr int NC = 256/GT;
  __shared__ int js[NC*KC];
  int bi = blockIdx.x, t = threadIdx.x;
  int li = t / GT, c4 = (t % GT)*4;
  int ci = bi*NC + li;
  int rb = (ci >> 8) << 8;
  if (t < NC*KC) js[t] = idx[(size_t)bi*NC*KC + t];
  __syncthreads();
  float4 a = *(const float4*)(A + (size_t)ci*COUT + c4);
  float4 p = make_float4(0.f,0.f,0.f,0.f);
#pragma unroll
  for (int k = 0; k < KC; ++k){
    int j = js[li*KC + k];
    float4 b = *(const float4*)(Bm + (size_t)(rb + j)*COUT + c4);
    p = max4(p, add4(a, b));
  }
  *(float4*)(out + (size_t)ci*COUT + c4) = p;
}

// ---------------- T-Net edge: h0 = relu(A0+B0) then 64->128 conv + k-maxpool ----------------
__global__ __launch_bounds__(128) void k_tedge3(const float* __restrict__ A0, const float* __restrict__ B0,
    const int* __restrict__ idx, const float* __restrict__ wt1, float* __restrict__ out){
  __shared__ __align__(16) float h0s[20*68];
  __shared__ __align__(16) float smax[4*128];
  __shared__ int js[KC];
  int bi = blockIdx.x, t = threadIdx.x;
  int cg = t & 31, kg = t >> 5, k0 = kg*5;
  int rb = (bi >> 8) << 8;
  if (t < KC) js[t] = idx[(size_t)bi*KC + t];
  __syncthreads();
  for (int i = t; i < 20*64; i += 128){
    int k = i >> 6, c = i & 63;
    float v = A0[(size_t)bi*64 + c] + B0[(size_t)(rb + js[k])*64 + c];
    h0s[k*68 + c] = fmaxf(v, 0.0f);
  }
  __syncthreads();
  float4 b2[5];
#pragma unroll
  for (int kk = 0; kk < 5; ++kk) b2[kk] = make_float4(0.f,0.f,0.f,0.f);
  for (int m4 = 0; m4 < 16; ++m4){
    float4 e[5];
#pragma unroll
    for (int kk = 0; kk < 5; ++kk) e[kk] = *(const float4*)(h0s + (k0+kk)*68 + 4*m4);
#pragma unroll
    for (int mm = 0; mm < 4; ++mm){
      float4 w = *(const float4*)(wt1 + (4*m4+mm)*128 + 4*cg);
#pragma unroll
      for (int kk = 0; kk < 5; ++kk){
        float ev = (mm==0)?e[kk].x:((mm==1)?e[kk].y:((mm==2)?e[kk].z:e[kk].w));
        b2[kk] = fma4s(w, ev, b2[kk]);
      }
    }
  }
  float4 p = make_float4(0.f,0.f,0.f,0.f);
#pragma unroll
  for (int kk = 0; kk < 5; ++kk) p = max4(p, b2[kk]);
  *(float4*)(smax + kg*128 + 4*cg) = p;
  __syncthreads();
  if (kg == 0){
    float4 r = *(const float4*)(smax + 4*cg);
#pragma unroll
    for (int g = 1; g < 4; ++g) r = max4(r, *(const float4*)(smax + g*128 + 4*cg));
    *(float4*)(out + (size_t)bi*128 + 4*cg) = r;
  }
}

// ---------------- T-Net 128->1024 + pool: 8 point-chunks, atomicMax combine ----------------
__global__ __launch_bounds__(128) void k_tpool(const float* __restrict__ h, const float* __restrict__ W,
    float* __restrict__ g1024){
  int b = blockIdx.x, t = threadIdx.x;
  int c = blockIdx.y*128 + t;
  int i0 = blockIdx.z*32;
  float4 w[32];
#pragma unroll
  for (int qq = 0; qq < 32; ++qq) w[qq] = *(const float4*)(W + (size_t)c*128 + 4*qq);
  const float* hb = h + (size_t)b*NPp*128;
  float mx = 0.0f;
  for (int i = i0; i < i0 + 32; ++i){
    const float4* hr = (const float4*)(hb + (size_t)i*128);
    float a = 0.0f;
#pragma unroll
    for (int qq = 0; qq < 32; ++qq) a = fma4(w[qq], hr[qq], a);
    mx = fmaxf(mx, a);
  }
  atomicMax((int*)(g1024 + (size_t)b*1024 + c), __float_as_int(mx));
}

// ---------------- T-Net MLP + 3x3 transform applied to new_xyz ----------------
__global__ __launch_bounds__(256) void k_trest(const float* __restrict__ g1024,
    const float* __restrict__ Wg0, const float* __restrict__ Wg1,
    const float* __restrict__ Wl, const float* __restrict__ bl,
    const float* __restrict__ new_xyz, float* __restrict__ x131){
  __shared__ __align__(16) float g1[1024];
  __shared__ __align__(16) float g5[512];
  __shared__ __align__(16) float g2[256];
  __shared__ float tm[12];
  int b = blockIdx.x, t = threadIdx.x;
  for (int m = t; m < 1024; m += 256) g1[m] = g1024[(size_t)b*1024 + m];
  __syncthreads();
#pragma unroll
  for (int cc = 0; cc < 2; ++cc){
    int c = t + cc*256;
    const float4* wr = (const float4*)(Wg0 + (size_t)c*1024);
    const float4* gv = (const float4*)g1;
    float a = 0.0f;
    for (int qq = 0; qq < 256; ++qq) a = fma4(wr[qq], gv[qq], a);
    g5[c] = fmaxf(a, 0.0f);
  }
  __syncthreads();
  {
    const float4* wr = (const float4*)(Wg1 + (size_t)t*512);
    const float4* gv = (const float4*)g5;
    float a = 0.0f;
    for (int qq = 0; qq < 128; ++qq) a = fma4(wr[qq], gv[qq], a);
    g2[t] = fmaxf(a, 0.0f);
  }
  __syncthreads();
  if (t < 9){
    const float4* wr = (const float4*)(Wl + (size_t)t*256);
    const float4* gv = (const float4*)g2;
    float a = 0.0f;
#pragma unroll
    for (int qq = 0; qq < 64; ++qq) a = fma4(wr[qq], gv[qq], a);
    a += bl[t];
    if (t == 0 || t == 4 || t == 8) a += 1.0f;
    tm[t] = a;
  }
  __syncthreads();
  {
    const float* nx = new_xyz + ((size_t)b*NPp + t)*3;
    float X = nx[0], Y = nx[1], Z = nx[2];
#pragma unroll
    for (int i = 0; i < 3; ++i){
      float v = __fadd_rn(__fadd_rn(__fmul_rn(tm[i*3+0], X), __fmul_rn(tm[i*3+1], Y)), __fmul_rn(tm[i*3+2], Z));
      x131[((size_t)b*NPp + t)*132 + 128 + i] = v;
    }
  }
}

// ---------------- 896->128 conv + global max pool (atomicMax; poison is negative int) ----------------
__global__ __launch_bounds__(128) void k_dgl(const float* __restrict__ f1, const float* __restrict__ f2,
    const float* __restrict__ f3, const float* __restrict__ W, float* __restrict__ g128){
  int b = blockIdx.x, t = threadIdx.x;
  int i0 = blockIdx.y * 16;
  const float* wr = W + (size_t)t*896;
  float acc[16];
#pragma unroll
  for (int ii = 0; ii < 16; ++ii) acc[ii] = 0.0f;
  for (int q = 0; q < 32; ++q){
    float4 w = *(const float4*)(wr + 4*q);
#pragma unroll
    for (int ii = 0; ii < 16; ++ii){
      float4 v = *(const float4*)(f1 + ((size_t)b*NPp + i0 + ii)*128 + 4*q);
      acc[ii] = fma4(w, v, acc[ii]);
    }
  }
  for (int q = 0; q < 64; ++q){
    float4 w = *(const float4*)(wr + 128 + 4*q);
#pragma unroll
    for (int ii = 0; ii < 16; ++ii){
      float4 v = *(const float4*)(f2 + ((size_t)b*NPp + i0 + ii)*256 + 4*q);
      acc[ii] = fma4(w, v, acc[ii]);
    }
  }
  for (int q = 0; q < 128; ++q){
    float4 w = *(const float4*)(wr + 384 + 4*q);
#pragma unroll
    for (int ii = 0; ii < 16; ++ii){
      float4 v = *(const float4*)(f3 + ((size_t)b*NPp + i0 + ii)*512 + 4*q);
      acc[ii] = fma4(w, v, acc[ii]);
    }
  }
#pragma unroll
  for (int ii = 0; ii < 16; ++ii){
    float v = fmaxf(acc[ii], 0.0f);
    atomicMax((int*)(g128 + (size_t)b*128 + t), __float_as_int(v));
  }
}

// ---------------- classifier head ----------------
__global__ __launch_bounds__(256) void k_final(const float* __restrict__ g128,
    const float* __restrict__ W0, const float* __restrict__ W1,
    const float* __restrict__ Wc, const float* __restrict__ bc, float* __restrict__ out){
  __shared__ __align__(16) float g0[128];
  __shared__ __align__(16) float g5[512];
  __shared__ __align__(16) float g2[256];
  int b = blockIdx.x, t = threadIdx.x;
  if (t < 128) g0[t] = g128[(size_t)b*128 + t];
  __syncthreads();
#pragma unroll
  for (int cc = 0; cc < 2; ++cc){
    int c = t + cc*256;
    const float4* wr = (const float4*)(W0 + (size_t)c*128);
    const float4* gv = (const float4*)g0;
    float a = 0.0f;
#pragma unroll
    for (int qq = 0; qq < 32; ++qq) a = fma4(wr[qq], gv[qq], a);
    g5[c] = fmaxf(a, 0.0f);
  }
  __syncthreads();
  {
    const float4* wr = (const float4*)(W1 + (size_t)t*512);
    const float4* gv = (const float4*)g5;
    float a = 0.0f;
    for (int qq = 0; qq < 128; ++qq) a = fma4(wr[qq], gv[qq], a);
    g2[t] = fmaxf(a, 0.0f);
  }
  __syncthreads();
  if (t < 40){
    const float4* wr = (const float4*)(Wc + (size_t)t*256);
    const float4* gv = (const float4*)g2;
    float a = 0.0f;
#pragma unroll
    for (int qq = 0; qq < 64; ++qq) a = fma4(wr[qq], gv[qq], a);
    out[(size_t)b*40 + t] = a + bc[t];
  }
}

extern "C" void kernel_launch(void* const* d_in, const int* in_sizes, int n_in,
                              void* d_out, int out_size, void* d_ws, size_t ws_size,
                              hipStream_t stream){
  (void)in_sizes; (void)n_in; (void)out_size; (void)ws_size;
  const float* points     = (const float*)d_in[0];
  const float* sa_w0      = (const float*)d_in[1];
  const float* sa_w1      = (const float*)d_in[2];
  const float* sa_w2      = (const float*)d_in[3];
  const float* t_ec_w0    = (const float*)d_in[4];
  const float* t_ec_w1    = (const float*)d_in[5];
  const float* t_local_w  = (const float*)d_in[6];
  const float* t_g_w0     = (const float*)d_in[7];
  const float* t_g_w1     = (const float*)d_in[8];
  const float* t_lin_w    = (const float*)d_in[9];
  const float* t_lin_b    = (const float*)d_in[10];
  const float* dg_ec_w0   = (const float*)d_in[11];
  const float* dg_ec_w1   = (const float*)d_in[12];
  const float* dg_ec_w2   = (const float*)d_in[13];
  const float* dg_local_w = (const float*)d_in[14];
  const float* dg_g_w0    = (const float*)d_in[15];
  const float* dg_g_w1    = (const float*)d_in[16];
  const float* cls_w      = (const float*)d_in[17];
  const float* cls_b      = (const float*)d_in[18];
  float* out = (float*)d_out;

  float* ws     = (float*)d_ws;
  float* xyz    = ws;                    // 393216
  float* xnrm   = xyz    + 393216;       // 131072
  float* nxyz   = xnrm   + 131072;       // 24576
  float* feat   = nxyz   + 24576;        // 1048576
  float* x131   = feat   + 1048576;      // 1081344
  float* nrm    = x131   + 1081344;      // 8192
  int*   idx    = (int*)(nrm + 8192);    // 163840
  float* ht     = (float*)(idx + 163840);// 1048576 (reused as f1)
  float* g1024v = ht     + 1048576;      // 32768
  float* f2     = g1024v + 32768;        // 2097152
  float* f3     = f2     + 2097152;      // 4194304
  float* g128v  = f3     + 4194304;      // 4096
  float* wt_t1  = g128v  + 4096;         // 8192   (64x128)
  float* waT0   = wt_t1  + 8192;         // 8384   (131x64)
  float* wbT0   = waT0   + 8384;         // 8384
  float* waD0   = wbT0   + 8384;         // 16768  (131x128)
  float* wbD0   = waD0   + 16768;        // 16768
  float* waD1   = wbD0   + 16768;        // 32768  (128x256)
  float* wbD1   = waD1   + 32768;        // 32768
  float* waD2   = wbD1   + 32768;        // 131072 (256x512)
  float* wbD2   = waD2   + 131072;       // 131072
  float* Ab     = wbD2   + 131072;       // 4194304
  float* Bb     = Ab     + 4194304;      // 4194304
  float* w1Tb   = Bb     + 4194304;      // 4096   (64x64 sa_w1 transposed)
  float* f1 = ht;
  float* xT = f3;                        // alias: xT lives in f3 until k_emax<512> writes f3

  k_prep<<<512, 256, 0, stream>>>(points, xyz, xnrm);
  k_wprep<<<787, 256, 0, stream>>>(t_ec_w0, t_ec_w1, dg_ec_w0, dg_ec_w1, dg_ec_w2, sa_w1,
                                   waT0, wbT0, wt_t1, waD0, wbD0, waD1, wbD1, waD2, wbD2, w1Tb);
  k_fps<<<BB, 256, 0, stream>>>(xyz, nxyz);
  k_sa<<<BB*NPp/4, 256, 0, stream>>>(xyz, xnrm, nxyz, sa_w0, w1Tb, sa_w2, feat, x131);

  // T-Net branch (x = [feat, new_xyz])
  k_gab<131,64,256><<<512, 256, 0, stream>>>(x131, 132, waT0, wbT0, Ab, Bb, xT, nrm);
  k_knn3<131><<<1024, 512, 0, stream>>>(xT, nrm, idx);
  k_tedge3<<<BB*NPp, 128, 0, stream>>>(Ab, Bb, idx, wt_t1, ht);
  k_tpool<<<dim3(BB, 8, 8), 128, 0, stream>>>(ht, t_local_w, g1024v);
  k_trest<<<BB, 256, 0, stream>>>(g1024v, t_g_w0, t_g_w1, t_lin_w, t_lin_b, nxyz, x131);

  // DGCNN layer 1 (x = [feat, xyz_t], 131 dims)
  k_gab<131,128,512><<<512, 512, 0, stream>>>(x131, 132, waD0, wbD0, Ab, Bb, xT, nrm);
  k_knn3<131><<<1024, 512, 0, stream>>>(xT, nrm, idx);
  k_emax<128><<<1024, 256, 0, stream>>>(Ab, Bb, idx, f1);
  // layer 2
  k_gab<128,256,512><<<512, 512, 0, stream>>>(f1, 128, waD1, wbD1, Ab, Bb, xT, nrm);
  k_knn3<128><<<1024, 512, 0, stream>>>(xT, nrm, idx);
  k_emax<256><<<2048, 256, 0, stream>>>(Ab, Bb, idx, f2);
  // layer 3
  k_gab<256,512,512><<<512, 512, 0, stream>>>(f2, 256, waD2, wbD2, Ab, Bb, xT, nrm);
  k_knn3<256><<<1024, 512, 0, stream>>>(xT, nrm, idx);
  k_emax<512><<<4096, 256, 0, stream>>>(Ab, Bb, idx, f3);

  // local conv + global pool + head
  k_dgl<<<dim3(BB, 16), 128, 0, stream>>>(f1, f2, f3, dg_local_w, g128v);
  k_final<<<BB, 256, 0, stream>>>(g128v, dg_g_w0, dg_g_w1, cls_w, cls_b, out);
}

// Round 15
// 1340.837 us; speedup vs baseline: 1.3504x; 1.0138x over previous
//
#include <hip/hip_runtime.h>
#include <math.h>

#define BB 32
#define NN 4096
#define NPp 256
#define NSs 64
#define KC 20

typedef unsigned long long ull;

__device__ __forceinline__ float fma4(const float4 w, const float4 v, float a){
  a = fmaf(w.x, v.x, a); a = fmaf(w.y, v.y, a);
  a = fmaf(w.z, v.z, a); a = fmaf(w.w, v.w, a); return a;
}
__device__ __forceinline__ float4 fma4s(const float4 w, float s, float4 a){
  a.x = fmaf(w.x, s, a.x); a.y = fmaf(w.y, s, a.y);
  a.z = fmaf(w.z, s, a.z); a.w = fmaf(w.w, s, a.w); return a;
}
__device__ __forceinline__ float4 max4(float4 a, float4 b){
  a.x = fmaxf(a.x, b.x); a.y = fmaxf(a.y, b.y);
  a.z = fmaxf(a.z, b.z); a.w = fmaxf(a.w, b.w); return a;
}
__device__ __forceinline__ float4 add4(float4 a, float4 b){
  a.x += b.x; a.y += b.y; a.z += b.z; a.w += b.w; return a;
}

template<int C>
__device__ __forceinline__ int dpp_i(int x){
  return __builtin_amdgcn_update_dpp(x, x, C, 0xf, 0xf, false);
}

// ---------------- unified weight prep (all transposes/splits in one kernel) ----------------
__global__ void k_wprep(const float* __restrict__ t0, const float* __restrict__ t1,
                        const float* __restrict__ d0, const float* __restrict__ d1,
                        const float* __restrict__ d2, const float* __restrict__ saw1,
                        float* __restrict__ waT0, float* __restrict__ wbT0,
                        float* __restrict__ wt_t1,
                        float* __restrict__ waD0, float* __restrict__ wbD0,
                        float* __restrict__ waD1, float* __restrict__ wbD1,
                        float* __restrict__ waD2, float* __restrict__ wbD2,
                        float* __restrict__ w1T){
  int i = blockIdx.x*256 + threadIdx.x;
  if (i < 8384){                       // t_ec_w0: [64][262] -> A/B [131][64]
    int m = i >> 6;
    int c = i & 63;
    float bb = t0[(size_t)c*262 + m];
    float dd = t0[(size_t)c*262 + 131 + m];
    waT0[i] = __fsub_rn(bb, dd); wbT0[i] = dd;
    return;
  }
  i -= 8384;
  if (i < 8192){                       // t_ec_w1: [128][64] -> [64][128]
    int m = i >> 7, c = i & 127;
    wt_t1[i] = t1[(size_t)c*64 + m];
    return;
  }
  i -= 8192;
  if (i < 16768){                      // dg_ec_w0: [128][262] -> A/B [131][128]
    int m = i >> 7, c = i & 127;
    float bb = d0[(size_t)c*262 + m];
    float dd = d0[(size_t)c*262 + 131 + m];
    waD0[i] = __fsub_rn(bb, dd); wbD0[i] = dd;
    return;
  }
  i -= 16768;
  if (i < 32768){                      // dg_ec_w1: [256][256] -> A/B [128][256]
    int m = i >> 8, c = i & 255;
    float bb = d1[(size_t)c*256 + m];
    float dd = d1[(size_t)c*256 + 128 + m];
    waD1[i] = __fsub_rn(bb, dd); wbD1[i] = dd;
    return;
  }
  i -= 32768;
  if (i < 131072){                     // dg_ec_w2: [512][512] -> A/B [256][512]
    int m = i >> 9, c = i & 511;
    float bb = d2[(size_t)c*512 + m];
    float dd = d2[(size_t)c*512 + 256 + m];
    waD2[i] = __fsub_rn(bb, dd); wbD2[i] = dd;
    return;
  }
  i -= 131072;
  if (i < 4096){                       // sa_w1: [64][64] -> w1T[m][c]
    int m = i >> 6, c = i & 63;
    w1T[i] = saw1[(size_t)c*64 + m];
  }
}

// ---------------- transpose + point norms ----------------
__global__ void k_prep(const float* __restrict__ pts, float* __restrict__ xyz, float* __restrict__ xnrm){
  int i = blockIdx.x*256 + threadIdx.x;
  if (i >= BB*NN) return;
  int b = i >> 12, n = i & (NN-1);
  float X = pts[(b*3+0)*NN + n];
  float Y = pts[(b*3+1)*NN + n];
  float Z = pts[(b*3+2)*NN + n];
  xyz[i*3+0]=X; xyz[i*3+1]=Y; xyz[i*3+2]=Z;
  xnrm[i] = __fadd_rn(__fadd_rn(__fmul_rn(X,X), __fmul_rn(Y,Y)), __fmul_rn(Z,Z));
}

// ---------------- farthest point sampling: u64 keys, quad_perm combine ----------------
__global__ __launch_bounds__(256) void k_fps(const float* __restrict__ xyz, float* __restrict__ new_xyz){
  __shared__ __align__(16) float part[2][4][8];
  int b = blockIdx.x, t = threadIdx.x;
  int w = t >> 6, lane = t & 63;
  float px[16], py[16], pz[16], dist[16];
#pragma unroll
  for (int q = 0; q < 16; ++q){
    const float* p = xyz + ((size_t)b*NN + q*256 + t)*3;
    px[q] = p[0]; py[q] = p[1]; pz[q] = p[2];
    dist[q] = __builtin_inff();
  }
  const float* p0 = xyz + (size_t)b*NN*3;
  float Px = p0[0], Py = p0[1], Pz = p0[2];
  float sx = 0.f, sy = 0.f, sz = 0.f;
  for (int it = 0; it < NPp; ++it){
    if (t == it){ sx = Px; sy = Py; sz = Pz; }
    float bv = -1.0f, bx = 0.f, by = 0.f, bz = 0.f; int bj = 0;
#pragma unroll
    for (int q = 0; q < 16; ++q){
      float dx = __fsub_rn(px[q], Px);
      float dy = __fsub_rn(py[q], Py);
      float dz = __fsub_rn(pz[q], Pz);
      float dd = __fadd_rn(__fadd_rn(__fmul_rn(dx,dx), __fmul_rn(dy,dy)), __fmul_rn(dz,dz));
      float dm = fminf(dist[q], dd);
      dist[q] = dm;
      if (dm > bv){ bv = dm; bj = q*256 + t; bx = px[q]; by = py[q]; bz = pz[q]; }
    }
    ull key = ((ull)__float_as_uint(bv) << 32) | (unsigned)(4095 - bj);
#define FPS_STAGE(C) { \
    unsigned ol = (unsigned)dpp_i<C>((int)(unsigned)key); \
    unsigned oh = (unsigned)dpp_i<C>((int)(unsigned)(key >> 32)); \
    float ox = __int_as_float(dpp_i<C>(__float_as_int(bx))); \
    float oy = __int_as_float(dpp_i<C>(__float_as_int(by))); \
    float oz = __int_as_float(dpp_i<C>(__float_as_int(bz))); \
    ull ok = ((ull)oh << 32) | ol; \
    bool tk = ok > key; \
    key = tk ? ok : key; bx = tk ? ox : bx; by = tk ? oy : by; bz = tk ? oz : bz; }
    FPS_STAGE(0x111) FPS_STAGE(0x112) FPS_STAGE(0x114) FPS_STAGE(0x118)
    FPS_STAGE(0x142) FPS_STAGE(0x143)
#undef FPS_STAGE
    int par = it & 1;
    if (lane == 63){
      float4 v;
      v.x = __uint_as_float((unsigned)key);
      v.y = __uint_as_float((unsigned)(key >> 32));
      v.z = bx; v.w = by;
      *(float4*)&part[par][w][0] = v;
      part[par][w][4] = bz;
    }
    __syncthreads();
    {
      const float* pp = &part[par][lane & 3][0];
      float4 v = *(const float4*)pp;
      float vz = pp[4];
      ull k2 = ((ull)__float_as_uint(v.y) << 32) | __float_as_uint(v.x);
      float cx = v.z, cy = v.w, cz = vz;
#define FPS_Q(C) { \
      unsigned ol = (unsigned)dpp_i<C>((int)(unsigned)k2); \
      unsigned oh = (unsigned)dpp_i<C>((int)(unsigned)(k2 >> 32)); \
      float ox = __int_as_float(dpp_i<C>(__float_as_int(cx))); \
      float oy = __int_as_float(dpp_i<C>(__float_as_int(cy))); \
      float oz = __int_as_float(dpp_i<C>(__float_as_int(cz))); \
      ull ok = ((ull)oh << 32) | ol; \
      bool tk = ok > k2; \
      k2 = tk ? ok : k2; cx = tk ? ox : cx; cy = tk ? oy : cy; cz = tk ? oz : cz; }
      FPS_Q(0xB1) FPS_Q(0x4E)
#undef FPS_Q
      Px = cx; Py = cy; Pz = cz;
    }
  }
  {
    float* o = new_xyz + ((size_t)b*NPp + t)*3;
    o[0] = sx; o[1] = sy; o[2] = sz;
  }
}

// ---------------- ball query + SA convs + maxpool: rolled loops, h1 in arch VGPRs ----------------
// launch_bounds(256,4): 128-reg/wave budget -> h1[64] fits in architectural VGPRs (no accvgpr moves)
__global__ __launch_bounds__(256, 4) void k_sa(const float* __restrict__ xyz, const float* __restrict__ xnrm,
    const float* __restrict__ new_xyz, const float* __restrict__ w0, const float* __restrict__ w1T,
    const float* __restrict__ w2, float* __restrict__ feat, float* __restrict__ x131){
  __shared__ int gix[4][64];
  int t = threadIdx.x;
  int wv = t >> 6, lane = t & 63;
  int bi = blockIdx.x*4 + wv;
  int b = bi >> 8;
  int* gw = gix[wv];
  const float* q = new_xyz + (size_t)bi*3;
  float qx=q[0], qy=q[1], qz=q[2];
  float nq = __fadd_rn(__fadd_rn(__fmul_rn(qx,qx), __fmul_rn(qy,qy)), __fmul_rn(qz,qz));
  int cnt = 0;
  for (int base = 0; base < NN && cnt < NSs; base += 256){
#pragma unroll
    for (int u = 0; u < 4; ++u){
      int j = base + u*64 + lane;
      const float* p = xyz + ((size_t)b*NN + j)*3;
      float dot = __fadd_rn(__fadd_rn(__fmul_rn(qx,p[0]), __fmul_rn(qy,p[1])), __fmul_rn(qz,p[2]));
      float d2 = __fsub_rn(__fadd_rn(nq, xnrm[b*NN + j]), __fmul_rn(2.0f, dot));
      bool inb = d2 < 0.04f;
      unsigned long long m = __ballot(inb);
      int pos = cnt + (int)__popcll(m & ((1ull << lane) - 1ull));
      if (inb && pos < NSs) gw[pos] = j;
      cnt += (int)__popcll(m);
    }
  }
  int g0 = gw[0];
  if (lane >= cnt) gw[lane] = g0;
  // lane = sample; mid conv rolled over m (h1 channel index constant-unrolled -> stays in VGPRs)
  float h1[64];
  {
    int gj = gw[lane];
    const float* p = xyz + ((size_t)b*NN + gj)*3;
    float px = p[0]-qx, py = p[1]-qy, pz = p[2]-qz;
#pragma unroll
    for (int c = 0; c < 64; ++c) h1[c] = 0.0f;
    for (int m = 0; m < 64; ++m){
      float a0 = fmaf(w0[m*3+2], pz, fmaf(w0[m*3+1], py, w0[m*3]*px));
      float h0m = fmaxf(a0, 0.0f);
      const float4* wr = (const float4*)(w1T + m*64);
#pragma unroll
      for (int q4 = 0; q4 < 16; ++q4){
        float4 w = wr[q4];
        h1[4*q4+0] = fmaf(w.x, h0m, h1[4*q4+0]);
        h1[4*q4+1] = fmaf(w.y, h0m, h1[4*q4+1]);
        h1[4*q4+2] = fmaf(w.z, h0m, h1[4*q4+2]);
        h1[4*q4+3] = fmaf(w.w, h0m, h1[4*q4+3]);
      }
    }
#pragma unroll
    for (int c = 0; c < 64; ++c) h1[c] = fmaxf(h1[c], 0.0f);
  }
  // third conv: rolled over c, wave max-reduce via DPP
  float m0 = 0.0f, m1 = 0.0f;
#pragma unroll 2
  for (int c = 0; c < 128; ++c){
    const float4* wr = (const float4*)(w2 + (size_t)c*64);
    float a = 0.0f;
#pragma unroll
    for (int qq = 0; qq < 16; ++qq){
      float4 w = wr[qq];
      a = fmaf(w.x, h1[4*qq+0], a);
      a = fmaf(w.y, h1[4*qq+1], a);
      a = fmaf(w.z, h1[4*qq+2], a);
      a = fmaf(w.w, h1[4*qq+3], a);
    }
    a = fmaxf(a, 0.0f);
#define SA_MAX(C) { float o = __int_as_float(dpp_i<C>(__float_as_int(a))); a = fmaxf(a, o); }
    SA_MAX(0x111) SA_MAX(0x112) SA_MAX(0x114) SA_MAX(0x118) SA_MAX(0x142) SA_MAX(0x143)
#undef SA_MAX
    float r = __int_as_float(__builtin_amdgcn_readlane(__float_as_int(a), 63));
    if (c < 64){ if (lane == c) m0 = r; }
    else       { if (lane == c - 64) m1 = r; }
  }
  feat[(size_t)bi*128 + lane]      = m0;
  feat[(size_t)bi*128 + 64 + lane] = m1;
  x131[(size_t)bi*132 + lane]      = m0;
  x131[(size_t)bi*132 + 64 + lane] = m1;
  if (lane < 3) x131[(size_t)bi*132 + 128 + lane] = (lane==0)?qx:((lane==1)?qy:qz);
}

// ---------------- kNN: distances in registers, u64-DPP selection, no selection LDS ----------------
template<int CIN>
__global__ __launch_bounds__(512) void k_knn3(const float* __restrict__ xT,
    const float* __restrict__ nrm, int* __restrict__ idxo){
  __shared__ __align__(16) float sch[16*256];
  int bi = blockIdx.x, t = threadIdx.x;
  int w = t >> 6, lane = t & 63;
  int b = bi >> 5;
  int coli = (bi & 31)*8 + w;
  const float* xb = xT + (size_t)b*CIN*256;
  float d0=0.f, d1=0.f, d2=0.f, d3=0.f;
  for (int m0 = 0; m0 < CIN; m0 += 16){
    int mc = (CIN - m0 < 16) ? (CIN - m0) : 16;
    for (int i = t; i < mc*64; i += 512){
      int mm = i >> 6, c4 = i & 63;
      *(float4*)(sch + mm*256 + c4*4) = *(const float4*)(xb + (size_t)(m0+mm)*256 + c4*4);
    }
    __syncthreads();
    for (int mm = 0; mm < mc; ++mm){
      float xm = sch[mm*256 + coli];
      float4 v = *(const float4*)(sch + mm*256 + 4*lane);
      d0 = fmaf(v.x, xm, d0); d1 = fmaf(v.y, xm, d1);
      d2 = fmaf(v.z, xm, d2); d3 = fmaf(v.w, xm, d3);
    }
    __syncthreads();
  }
  float ni = nrm[b*256 + coli];
  float4 dv;
  {
    int j0 = 4*lane;
    dv.x = __fsub_rn(__fadd_rn(ni, nrm[b*256 + j0+0]), __fmul_rn(2.0f, d0));
    dv.y = __fsub_rn(__fadd_rn(ni, nrm[b*256 + j0+1]), __fmul_rn(2.0f, d1));
    dv.z = __fsub_rn(__fadd_rn(ni, nrm[b*256 + j0+2]), __fmul_rn(2.0f, d2));
    dv.w = __fsub_rn(__fadd_rn(ni, nrm[b*256 + j0+3]), __fmul_rn(2.0f, d3));
  }
  for (int r = 0; r < KC; ++r){
    float bv = 3.4e38f; int bj = NPp;
    if (dv.x < bv){ bv = dv.x; bj = 4*lane+0; }
    if (dv.y < bv){ bv = dv.y; bj = 4*lane+1; }
    if (dv.z < bv){ bv = dv.z; bj = 4*lane+2; }
    if (dv.w < bv){ bv = dv.w; bj = 4*lane+3; }
    unsigned xf = __float_as_uint(bv);
    xf = (xf & 0x80000000u) ? ~xf : (xf | 0x80000000u);
    ull key = ((ull)xf << 32) | (unsigned)bj;
#define KN_STAGE(C) { \
    unsigned ol = (unsigned)dpp_i<C>((int)(unsigned)key); \
    unsigned oh = (unsigned)dpp_i<C>((int)(unsigned)(key >> 32)); \
    ull ok = ((ull)oh << 32) | ol; \
    if (ok < key) key = ok; }
    KN_STAGE(0x111) KN_STAGE(0x112) KN_STAGE(0x114) KN_STAGE(0x118)
    KN_STAGE(0x142) KN_STAGE(0x143)
#undef KN_STAGE
    int bjw = __builtin_amdgcn_readlane((int)(unsigned)key, 63);
    if (lane == 0) idxo[((size_t)b*256 + coli)*KC + r] = bjw;
    if ((bjw >> 2) == lane){
      int e = bjw & 3;
      if      (e == 0) dv.x = 3.0e38f;
      else if (e == 1) dv.y = 3.0e38f;
      else if (e == 2) dv.z = 3.0e38f;
      else             dv.w = 3.0e38f;
    }
  }
}

// ---------------- per-point dual GEMM + fused xT transpose + fused norms ----------------
template<int CIN, int COUT, int T>
__global__ __launch_bounds__(T) void k_gab(const float* __restrict__ x, int xstride,
    const float* __restrict__ wA, const float* __restrict__ wB,
    float* __restrict__ A, float* __restrict__ B, float* __restrict__ xT,
    float* __restrict__ nrm){
  constexpr int PC  = CIN + 1;
  constexpr int G   = COUT/4;
  constexpr int RS  = T/G;
  constexpr int RPT = 16/RS;
  __shared__ float xsh[16*PC];
  int bi = blockIdx.x, t = threadIdx.x;
  int g = t % G, rs = t / G;
  int i0 = bi*16;
  for (int i = t; i < 16*CIN; i += T){
    int r = i / CIN, m = i - r*CIN;
    xsh[r*PC + m] = x[(size_t)(i0+r)*xstride + m];
  }
  __syncthreads();
  {
    int bb = i0 >> 8, col0 = i0 & 255;
    float* xTb = xT + (size_t)bb*CIN*256 + col0;
    for (int i = t; i < 16*CIN; i += T){
      int m = i >> 4, r = i & 15;
      xTb[m*256 + r] = xsh[r*PC + m];
    }
  }
  if (t < 16){
    const float* xr = xsh + t*PC;
    float a = 0.0f;
    for (int m = 0; m < CIN; ++m) a = __fadd_rn(a, __fmul_rn(xr[m], xr[m]));
    nrm[i0 + t] = a;
  }
  float4 accA[RPT], accB[RPT];
#pragma unroll
  for (int rr = 0; rr < RPT; ++rr){
    accA[rr] = make_float4(0.f,0.f,0.f,0.f);
    accB[rr] = make_float4(0.f,0.f,0.f,0.f);
  }
  for (int m = 0; m < CIN; ++m){
    float4 wa = *(const float4*)(wA + (size_t)m*COUT + 4*g);
    float4 wb = *(const float4*)(wB + (size_t)m*COUT + 4*g);
#pragma unroll
    for (int rr = 0; rr < RPT; ++rr){
      float xv = xsh[(rs + rr*RS)*PC + m];
      accA[rr] = fma4s(wa, xv, accA[rr]);
      accB[rr] = fma4s(wb, xv, accB[rr]);
    }
  }
#pragma unroll
  for (int rr = 0; rr < RPT; ++rr){
    int r = i0 + rs + rr*RS;
    *(float4*)(A + (size_t)r*COUT + 4*g) = accA[rr];
    *(float4*)(B + (size_t)r*COUT + 4*g) = accB[rr];
  }
}

// ---------------- edge epilogue: out[i][c] = max_k relu(A[i][c] + B[j_ik][c]) ----------------
template<int COUT>
__global__ __launch_bounds__(256) void k_emax(const float* __restrict__ A, const float* __restrict__ Bm,
    const int* __restrict__ idx, float* __restrict__ out){
  constexpr int GT = COUT/4;
  constexpr int NC = 256/GT;
  __shared__ int js[NC*KC];
  int bi = blockIdx.x, t = threadIdx.x;
  int li = t / GT, c4 = (t % GT)*4;
  int ci = bi*NC + li;
  int rb = (ci >> 8) << 8;
  if (t < NC*KC) js[t] = idx[(size_t)bi*NC*KC + t];
  __syncthreads();
  float4 a = *(const float4*)(A + (size_t)ci*COUT + c4);
  float4 p = make_float4(0.f,0.f,0.f,0.f);
#pragma unroll
  for (int k = 0; k < KC; ++k){
    int j = js[li*KC + k];
    float4 b = *(const float4*)(Bm + (size_t)(rb + j)*COUT + c4);
    p = max4(p, add4(a, b));
  }
  *(float4*)(out + (size_t)ci*COUT + c4) = p;
}

// ---------------- T-Net edge: h0 = relu(A0+B0) then 64->128 conv + k-maxpool ----------------
__global__ __launch_bounds__(128) void k_tedge3(const float* __restrict__ A0, const float* __restrict__ B0,
    const int* __restrict__ idx, const float* __restrict__ wt1, float* __restrict__ out){
  __shared__ __align__(16) float h0s[20*68];
  __shared__ __align__(16) float smax[4*128];
  __shared__ int js[KC];
  int bi = blockIdx.x, t = threadIdx.x;
  int cg = t & 31, kg = t >> 5, k0 = kg*5;
  int rb = (bi >> 8) << 8;
  if (t < KC) js[t] = idx[(size_t)bi*KC + t];
  __syncthreads();
  for (int i = t; i < 20*64; i += 128){
    int k = i >> 6, c = i & 63;
    float v = A0[(size_t)bi*64 + c] + B0[(size_t)(rb + js[k])*64 + c];
    h0s[k*68 + c] = fmaxf(v, 0.0f);
  }
  __syncthreads();
  float4 b2[5];
#pragma unroll
  for (int kk = 0; kk < 5; ++kk) b2[kk] = make_float4(0.f,0.f,0.f,0.f);
  for (int m4 = 0; m4 < 16; ++m4){
    float4 e[5];
#pragma unroll
    for (int kk = 0; kk < 5; ++kk) e[kk] = *(const float4*)(h0s + (k0+kk)*68 + 4*m4);
#pragma unroll
    for (int mm = 0; mm < 4; ++mm){
      float4 w = *(const float4*)(wt1 + (4*m4+mm)*128 + 4*cg);
#pragma unroll
      for (int kk = 0; kk < 5; ++kk){
        float ev = (mm==0)?e[kk].x:((mm==1)?e[kk].y:((mm==2)?e[kk].z:e[kk].w));
        b2[kk] = fma4s(w, ev, b2[kk]);
      }
    }
  }
  float4 p = make_float4(0.f,0.f,0.f,0.f);
#pragma unroll
  for (int kk = 0; kk < 5; ++kk) p = max4(p, b2[kk]);
  *(float4*)(smax + kg*128 + 4*cg) = p;
  __syncthreads();
  if (kg == 0){
    float4 r = *(const float4*)(smax + 4*cg);
#pragma unroll
    for (int g = 1; g < 4; ++g) r = max4(r, *(const float4*)(smax + g*128 + 4*cg));
    *(float4*)(out + (size_t)bi*128 + 4*cg) = r;
  }
}

// ---------------- T-Net 128->1024 + pool: 8 point-chunks, atomicMax combine ----------------
__global__ __launch_bounds__(128) void k_tpool(const float* __restrict__ h, const float* __restrict__ W,
    float* __restrict__ g1024){
  int b = blockIdx.x, t = threadIdx.x;
  int c = blockIdx.y*128 + t;
  int i0 = blockIdx.z*32;
  float4 w[32];
#pragma unroll
  for (int qq = 0; qq < 32; ++qq) w[qq] = *(const float4*)(W + (size_t)c*128 + 4*qq);
  const float* hb = h + (size_t)b*NPp*128;
  float mx = 0.0f;
  for (int i = i0; i < i0 + 32; ++i){
    const float4* hr = (const float4*)(hb + (size_t)i*128);
    float a = 0.0f;
#pragma unroll
    for (int qq = 0; qq < 32; ++qq) a = fma4(w[qq], hr[qq], a);
    mx = fmaxf(mx, a);
  }
  atomicMax((int*)(g1024 + (size_t)b*1024 + c), __float_as_int(mx));
}

// ---------------- T-Net MLP + 3x3 transform applied to new_xyz ----------------
__global__ __launch_bounds__(256) void k_trest(const float* __restrict__ g1024,
    const float* __restrict__ Wg0, const float* __restrict__ Wg1,
    const float* __restrict__ Wl, const float* __restrict__ bl,
    const float* __restrict__ new_xyz, float* __restrict__ x131){
  __shared__ __align__(16) float g1[1024];
  __shared__ __align__(16) float g5[512];
  __shared__ __align__(16) float g2[256];
  __shared__ float tm[12];
  int b = blockIdx.x, t = threadIdx.x;
  for (int m = t; m < 1024; m += 256) g1[m] = g1024[(size_t)b*1024 + m];
  __syncthreads();
#pragma unroll
  for (int cc = 0; cc < 2; ++cc){
    int c = t + cc*256;
    const float4* wr = (const float4*)(Wg0 + (size_t)c*1024);
    const float4* gv = (const float4*)g1;
    float a = 0.0f;
    for (int qq = 0; qq < 256; ++qq) a = fma4(wr[qq], gv[qq], a);
    g5[c] = fmaxf(a, 0.0f);
  }
  __syncthreads();
  {
    const float4* wr = (const float4*)(Wg1 + (size_t)t*512);
    const float4* gv = (const float4*)g5;
    float a = 0.0f;
    for (int qq = 0; qq < 128; ++qq) a = fma4(wr[qq], gv[qq], a);
    g2[t] = fmaxf(a, 0.0f);
  }
  __syncthreads();
  if (t < 9){
    const float4* wr = (const float4*)(Wl + (size_t)t*256);
    const float4* gv = (const float4*)g2;
    float a = 0.0f;
#pragma unroll
    for (int qq = 0; qq < 64; ++qq) a = fma4(wr[qq], gv[qq], a);
    a += bl[t];
    if (t == 0 || t == 4 || t == 8) a += 1.0f;
    tm[t] = a;
  }
  __syncthreads();
  {
    const float* nx = new_xyz + ((size_t)b*NPp + t)*3;
    float X = nx[0], Y = nx[1], Z = nx[2];
#pragma unroll
    for (int i = 0; i < 3; ++i){
      float v = __fadd_rn(__fadd_rn(__fmul_rn(tm[i*3+0], X), __fmul_rn(tm[i*3+1], Y)), __fmul_rn(tm[i*3+2], Z));
      x131[((size_t)b*NPp + t)*132 + 128 + i] = v;
    }
  }
}

// ---------------- 896->128 conv + global max pool (atomicMax; poison is negative int) ----------------
__global__ __launch_bounds__(128) void k_dgl(const float* __restrict__ f1, const float* __restrict__ f2,
    const float* __restrict__ f3, const float* __restrict__ W, float* __restrict__ g128){
  int b = blockIdx.x, t = threadIdx.x;
  int i0 = blockIdx.y * 16;
  const float* wr = W + (size_t)t*896;
  float acc[16];
#pragma unroll
  for (int ii = 0; ii < 16; ++ii) acc[ii] = 0.0f;
  for (int q = 0; q < 32; ++q){
    float4 w = *(const float4*)(wr + 4*q);
#pragma unroll
    for (int ii = 0; ii < 16; ++ii){
      float4 v = *(const float4*)(f1 + ((size_t)b*NPp + i0 + ii)*128 + 4*q);
      acc[ii] = fma4(w, v, acc[ii]);
    }
  }
  for (int q = 0; q < 64; ++q){
    float4 w = *(const float4*)(wr + 128 + 4*q);
#pragma unroll
    for (int ii = 0; ii < 16; ++ii){
      float4 v = *(const float4*)(f2 + ((size_t)b*NPp + i0 + ii)*256 + 4*q);
      acc[ii] = fma4(w, v, acc[ii]);
    }
  }
  for (int q = 0; q < 128; ++q){
    float4 w = *(const float4*)(wr + 384 + 4*q);
#pragma unroll
    for (int ii = 0; ii < 16; ++ii){
      float4 v = *(const float4*)(f3 + ((size_t)b*NPp + i0 + ii)*512 + 4*q);
      acc[ii] = fma4(w, v, acc[ii]);
    }
  }
#pragma unroll
  for (int ii = 0; ii < 16; ++ii){
    float v = fmaxf(acc[ii], 0.0f);
    atomicMax((int*)(g128 + (size_t)b*128 + t), __float_as_int(v));
  }
}

// ---------------- classifier head ----------------
__global__ __launch_bounds__(256) void k_final(const float* __restrict__ g128,
    const float* __restrict__ W0, const float* __restrict__ W1,
    const float* __restrict__ Wc, const float* __restrict__ bc, float* __restrict__ out){
  __shared__ __align__(16) float g0[128];
  __shared__ __align__(16) float g5[512];
  __shared__ __align__(16) float g2[256];
  int b = blockIdx.x, t = threadIdx.x;
  if (t < 128) g0[t] = g128[(size_t)b*128 + t];
  __syncthreads();
#pragma unroll
  for (int cc = 0; cc < 2; ++cc){
    int c = t + cc*256;
    const float4* wr = (const float4*)(W0 + (size_t)c*128);
    const float4* gv = (const float4*)g0;
    float a = 0.0f;
#pragma unroll
    for (int qq = 0; qq < 32; ++qq) a = fma4(wr[qq], gv[qq], a);
    g5[c] = fmaxf(a, 0.0f);
  }
  __syncthreads();
  {
    const float4* wr = (const float4*)(W1 + (size_t)t*512);
    const float4* gv = (const float4*)g5;
    float a = 0.0f;
    for (int qq = 0; qq < 128; ++qq) a = fma4(wr[qq], gv[qq], a);
    g2[t] = fmaxf(a, 0.0f);
  }
  __syncthreads();
  if (t < 40){
    const float4* wr = (const float4*)(Wc + (size_t)t*256);
    const float4* gv = (const float4*)g2;
    float a = 0.0f;
#pragma unroll
    for (int qq = 0; qq < 64; ++qq) a = fma4(wr[qq], gv[qq], a);
    out[(size_t)b*40 + t] = a + bc[t];
  }
}

extern "C" void kernel_launch(void* const* d_in, const int* in_sizes, int n_in,
                              void* d_out, int out_size, void* d_ws, size_t ws_size,
                              hipStream_t stream){
  (void)in_sizes; (void)n_in; (void)out_size; (void)ws_size;
  const float* points     = (const float*)d_in[0];
  const float* sa_w0      = (const float*)d_in[1];
  const float* sa_w1      = (const float*)d_in[2];
  const float* sa_w2      = (const float*)d_in[3];
  const float* t_ec_w0    = (const float*)d_in[4];
  const float* t_ec_w1    = (const float*)d_in[5];
  const float* t_local_w  = (const float*)d_in[6];
  const float* t_g_w0     = (const float*)d_in[7];
  const float* t_g_w1     = (const float*)d_in[8];
  const float* t_lin_w    = (const float*)d_in[9];
  const float* t_lin_b    = (const float*)d_in[10];
  const float* dg_ec_w0   = (const float*)d_in[11];
  const float* dg_ec_w1   = (const float*)d_in[12];
  const float* dg_ec_w2   = (const float*)d_in[13];
  const float* dg_local_w = (const float*)d_in[14];
  const float* dg_g_w0    = (const float*)d_in[15];
  const float* dg_g_w1    = (const float*)d_in[16];
  const float* cls_w      = (const float*)d_in[17];
  const float* cls_b      = (const float*)d_in[18];
  float* out = (float*)d_out;

  float* ws     = (float*)d_ws;
  float* xyz    = ws;                    // 393216
  float* xnrm   = xyz    + 393216;       // 131072
  float* nxyz   = xnrm   + 131072;       // 24576
  float* feat   = nxyz   + 24576;        // 1048576
  float* x131   = feat   + 1048576;      // 1081344
  float* nrm    = x131   + 1081344;      // 8192
  int*   idx    = (int*)(nrm + 8192);    // 163840
  float* ht     = (float*)(idx + 163840);// 1048576 (reused as f1)
  float* g1024v = ht     + 1048576;      // 32768
  float* f2     = g1024v + 32768;        // 2097152
  float* f3     = f2     + 2097152;      // 4194304
  float* g128v  = f3     + 4194304;      // 4096
  float* wt_t1  = g128v  + 4096;         // 8192   (64x128)
  float* waT0   = wt_t1  + 8192;         // 8384   (131x64)
  float* wbT0   = waT0   + 8384;         // 8384
  float* waD0   = wbT0   + 8384;         // 16768  (131x128)
  float* wbD0   = waD0   + 16768;        // 16768
  float* waD1   = wbD0   + 16768;        // 32768  (128x256)
  float* wbD1   = waD1   + 32768;        // 32768
  float* waD2   = wbD1   + 32768;        // 131072 (256x512)
  float* wbD2   = waD2   + 131072;       // 131072
  float* Ab     = wbD2   + 131072;       // 4194304
  float* Bb     = Ab     + 4194304;      // 4194304
  float* w1Tb   = Bb     + 4194304;      // 4096   (64x64 sa_w1 transposed)
  float* f1 = ht;
  float* xT = f3;                        // alias: xT lives in f3 until k_emax<512> writes f3

  k_prep<<<512, 256, 0, stream>>>(points, xyz, xnrm);
  k_wprep<<<787, 256, 0, stream>>>(t_ec_w0, t_ec_w1, dg_ec_w0, dg_ec_w1, dg_ec_w2, sa_w1,
                                   waT0, wbT0, wt_t1, waD0, wbD0, waD1, wbD1, waD2, wbD2, w1Tb);
  k_fps<<<BB, 256, 0, stream>>>(xyz, nxyz);
  k_sa<<<BB*NPp/4, 256, 0, stream>>>(xyz, xnrm, nxyz, sa_w0, w1Tb, sa_w2, feat, x131);

  // T-Net branch (x = [feat, new_xyz])
  k_gab<131,64,256><<<512, 256, 0, stream>>>(x131, 132, waT0, wbT0, Ab, Bb, xT, nrm);
  k_knn3<131><<<1024, 512, 0, stream>>>(xT, nrm, idx);
  k_tedge3<<<BB*NPp, 128, 0, stream>>>(Ab, Bb, idx, wt_t1, ht);
  k_tpool<<<dim3(BB, 8, 8), 128, 0, stream>>>(ht, t_local_w, g1024v);
  k_trest<<<BB, 256, 0, stream>>>(g1024v, t_g_w0, t_g_w1, t_lin_w, t_lin_b, nxyz, x131);

  // DGCNN layer 1 (x = [feat, xyz_t], 131 dims)
  k_gab<131,128,512><<<512, 512, 0, stream>>>(x131, 132, waD0, wbD0, Ab, Bb, xT, nrm);
  k_knn3<131><<<1024, 512, 0, stream>>>(xT, nrm, idx);
  k_emax<128><<<1024, 256, 0, stream>>>(Ab, Bb, idx, f1);
  // layer 2
  k_gab<128,256,512><<<512, 512, 0, stream>>>(f1, 128, waD1, wbD1, Ab, Bb, xT, nrm);
  k_knn3<128><<<1024, 512, 0, stream>>>(xT, nrm, idx);
  k_emax<256><<<2048, 256, 0, stream>>>(Ab, Bb, idx, f2);
  // layer 3
  k_gab<256,512,512><<<512, 512, 0, stream>>>(f2, 256, waD2, wbD2, Ab, Bb, xT, nrm);
  k_knn3<256><<<1024, 512, 0, stream>>>(xT, nrm, idx);
  k_emax<512><<<4096, 256, 0, stream>>>(Ab, Bb, idx, f3);

  // local conv + global pool + head
  k_dgl<<<dim3(BB, 16), 128, 0, stream>>>(f1, f2, f3, dg_local_w, g128v);
  k_final<<<BB, 256, 0, stream>>>(g128v, dg_g_w0, dg_g_w1, cls_w, cls_b, out);
}